// Round 11
// baseline (1068.792 us; speedup 1.0000x reference)
//
#include <hip/hip_runtime.h>
#include <hip/hip_bf16.h>

typedef unsigned short u16;
typedef __attribute__((ext_vector_type(8))) short sh8;     // 8 x bf16 (4 VGPRs)
typedef __attribute__((ext_vector_type(4))) float f32x4;   // MFMA accum

#define NV 8192
#define NG 4096
#define NE 65536

__device__ __forceinline__ u16 f2bf(float f) {
  __hip_bfloat16 h = __float2bfloat16(f);
  return __builtin_bit_cast(u16, h);
}

// async global->LDS, 16B per lane; LDS dest = wave-uniform base + lane*16
__device__ __forceinline__ void gl_lds16(const void* g, void* l) {
  __builtin_amdgcn_global_load_lds(
      (const __attribute__((address_space(1))) void*)g,
      (__attribute__((address_space(3))) void*)l, 16, 0, 0);
}

// ---------------- setup fills ----------------
__global__ void k_fill4(float* __restrict__ deg_v, float* __restrict__ deg_g,
                        float* __restrict__ deg_e, int* __restrict__ cnt) {
  int i = blockIdx.x * 256 + threadIdx.x;
  if (i < NV) deg_v[i] = 1.f;
  int j = i - NV;
  if (j >= 0 && j < NG) deg_g[j] = 1.f;
  j -= NG;
  if (j >= 0 && j < NG) deg_e[j] = 1.f;
  j -= NG;
  if (j >= 0 && j < NG) cnt[j] = 0;
}

// ---------------- Wb build ----------------
__global__ __launch_bounds__(256) void k_wb_build(
    const float* __restrict__ vert, const float* __restrict__ gpos,
    u16* __restrict__ WbRow, u16* __restrict__ WbP, u16* __restrict__ WbTP,
    float* __restrict__ deg_v, float* __restrict__ deg_g) {
  __shared__ float lv[192], lg[192], colp[256];
  __shared__ float tile[64][65];
  int t = threadIdx.x;
  int v0 = blockIdx.x * 64, g0 = blockIdx.y * 64;
  if (t < 192) { lv[t] = vert[(size_t)v0 * 3 + t]; lg[t] = gpos[(size_t)g0 * 3 + t]; }
  __syncthreads();
  int w = t >> 6, lane = t & 63;
  float gx_ = lg[lane * 3], gy_ = lg[lane * 3 + 1], gz_ = lg[lane * 3 + 2];
  float csum = 0.f;
  #pragma unroll 4
  for (int s = 0; s < 16; s++) {
    int vl = w + 4 * s;
    float dx = lv[vl * 3] - gx_, dy = lv[vl * 3 + 1] - gy_, dz = lv[vl * 3 + 2] - gz_;
    float d = sqrtf(dx * dx + dy * dy + dz * dz);
    float W = (d < 8.0f) ? expf(d * -0.25f) : 0.f;
    if (WbRow != nullptr) WbRow[(size_t)(v0 + vl) * NG + g0 + lane] = f2bf(W);
    tile[vl][lane] = W;
    csum += W;
  }
  colp[t] = csum;
  __syncthreads();
  int r4 = t >> 2, q = t & 3;
  float rs = 0.f;
  #pragma unroll
  for (int j = 0; j < 16; j++) rs += tile[r4][q * 16 + j];
  rs += __shfl_xor(rs, 1);
  rs += __shfl_xor(rs, 2);
  if (q == 0) atomicAdd(&deg_v[v0 + r4], rs);
  if (w == 0) {
    float tot = colp[lane] + colp[64 + lane] + colp[128 + lane] + colp[192 + lane];
    atomicAdd(&deg_g[g0 + lane], tot);
  }
  if (WbP != nullptr) {
    size_t tb = ((size_t)(v0 >> 7) * 64 + (g0 >> 6)) * 8192;
    #pragma unroll
    for (int j = 0; j < 2; j++) {
      int idx = j * 256 + t;
      int vr = idx >> 3, k8 = (idx & 7) * 8;
      u16 pk[8];
      #pragma unroll
      for (int qq = 0; qq < 8; qq++) pk[qq] = f2bf(tile[vr][k8 + qq]);
      int r = (v0 & 64) + vr;
      *(uint4*)&WbP[tb + (size_t)r * 64 + (size_t)(((k8 >> 3) ^ (r & 7)) << 3)] = *(uint4*)pk;
    }
  }
  if (WbTP != nullptr) {
    size_t tb = ((size_t)(g0 >> 7) * 128 + (v0 >> 6)) * 8192;
    #pragma unroll
    for (int j = 0; j < 2; j++) {
      int idx = j * 256 + t;
      int gr = idx >> 3, v8 = (idx & 7) * 8;
      u16 pk[8];
      #pragma unroll
      for (int qq = 0; qq < 8; qq++) pk[qq] = f2bf(tile[v8 + qq][gr]);
      int r = (g0 & 64) + gr;
      *(uint4*)&WbTP[tb + (size_t)r * 64 + (size_t)(((v8 >> 3) ^ (r & 7)) << 3)] = *(uint4*)pk;
    }
  }
}

// all three recips in one launch
__global__ void k_recips(const float* __restrict__ deg_v, float* __restrict__ inv_v,
                         float* __restrict__ rs_v, const float* __restrict__ deg_g,
                         float* __restrict__ inv_g, float* __restrict__ rs_g,
                         const float* __restrict__ deg_e, float* __restrict__ inv_e,
                         float* __restrict__ rs_e) {
  int i = blockIdx.x * 256 + threadIdx.x;
  if (i < NV) { float d = deg_v[i]; inv_v[i] = 1.f / d; rs_v[i] = 1.f / sqrtf(d); }
  else if (i < NV + NG) {
    int j = i - NV; float d = deg_g[j]; inv_g[j] = 1.f / d; rs_g[j] = 1.f / sqrtf(d);
  } else if (i < NV + 2 * NG) {
    int j = i - NV - NG; float d = deg_e[j]; inv_e[j] = 1.f / d; rs_e[j] = 1.f / sqrtf(d);
  }
}

// ---------------- edge preprocessing (CSR) ----------------
__global__ void k_edge_prep(const int* __restrict__ eidx, const float* __restrict__ ew,
                            float* __restrict__ deg_e, int* __restrict__ cnt) {
  int e = blockIdx.x * 256 + threadIdx.x;
  if (e < NE) { int d = eidx[NE + e]; atomicAdd(&deg_e[d], ew[e]); atomicAdd(&cnt[d], 1); }
}

__global__ __launch_bounds__(1024) void k_scan(const int* __restrict__ cnt,
    int* __restrict__ row_ptr, int* __restrict__ cursor) {
  __shared__ int buf0[1024], buf1[1024];
  int t = threadIdx.x;
  int b = t * 4;
  int c0 = cnt[b], c1 = cnt[b + 1], c2 = cnt[b + 2], c3 = cnt[b + 3];
  int s = c0 + c1 + c2 + c3;
  buf0[t] = s;
  __syncthreads();
  int* src = buf0; int* dst = buf1;
  for (int off = 1; off < 1024; off <<= 1) {
    int v = src[t];
    if (t >= off) v += src[t - off];
    dst[t] = v;
    __syncthreads();
    int* tmp = src; src = dst; dst = tmp;
  }
  int excl = (t == 0) ? 0 : src[t - 1];
  int r0 = excl, r1 = excl + c0, r2 = excl + c0 + c1, r3 = excl + c0 + c1 + c2;
  row_ptr[b] = r0; row_ptr[b + 1] = r1; row_ptr[b + 2] = r2; row_ptr[b + 3] = r3;
  cursor[b] = r0; cursor[b + 1] = r1; cursor[b + 2] = r2; cursor[b + 3] = r3;
  if (t == 1023) row_ptr[4096] = src[1023];
}

__global__ void k_scatter(const int* __restrict__ eidx, const float* __restrict__ ew,
                          const float* __restrict__ dinv, int* __restrict__ cursor,
                          int* __restrict__ csrc, float* __restrict__ cnorm) {
  int e = blockIdx.x * 256 + threadIdx.x;
  if (e < NE) {
    int s = eidx[e], d = eidx[NE + e];
    int slot = atomicAdd(&cursor[d], 1);
    csrc[slot] = s;
    cnorm[slot] = dinv[s] * ew[e] * dinv[d];
  }
}

// ---------------- evecs -> bf16 transposed [128][NV] ----------------
__global__ __launch_bounds__(256) void k_evecsT(const float* __restrict__ ev, u16* __restrict__ evT) {
  __shared__ float tile[32][33];
  int t = threadIdx.x;
  int v0 = blockIdx.x * 32, k0 = blockIdx.y * 32;
  int r = t >> 3, c4 = (t & 7) * 4;
  float4 x = *(const float4*)(ev + (size_t)(v0 + r) * 128 + k0 + c4);
  tile[r][c4] = x.x; tile[r][c4 + 1] = x.y; tile[r][c4 + 2] = x.z; tile[r][c4 + 3] = x.w;
  __syncthreads();
  u16* dst = evT + (size_t)(k0 + r) * NV + v0 + c4;
  dst[0] = f2bf(tile[c4][r]); dst[1] = f2bf(tile[c4 + 1][r]);
  dst[2] = f2bf(tile[c4 + 2][r]); dst[3] = f2bf(tile[c4 + 3][r]);
}

// ---------------- mdxT[c][v] = bf16(mass[v] * dx[v][c]) ----------------
__global__ __launch_bounds__(256) void k_mdxT(const float* __restrict__ dx,
    const float* __restrict__ mass, u16* __restrict__ mdxT) {
  __shared__ float tile[64][65];
  __shared__ float lm[64];
  int t = threadIdx.x;
  int v0 = blockIdx.x * 64;
  if (t < 64) lm[t] = mass[v0 + t];
  #pragma unroll
  for (int i = 0; i < 16; i++) {
    int idx = i * 256 + t;
    int r = idx >> 6, c = idx & 63;
    tile[r][c] = dx[(size_t)(v0 + r) * 64 + c];
  }
  __syncthreads();
  int c = t >> 2;
  #pragma unroll
  for (int i = 0; i < 2; i++) {
    int vq = (t & 3) * 16 + i * 8;
    u16 pk[8];
    #pragma unroll
    for (int q = 0; q < 8; q++) pk[q] = f2bf(lm[vq + q] * tile[vq + q][c]);
    *(uint4*)&mdxT[(size_t)c * NV + v0 + vq] = *(uint4*)pk;
  }
}

// =============== setup GEMM: BM=256/BN=128/BK=32, double-buffered ===========
__global__ __launch_bounds__(256) void gemm_setup3(
    const float* __restrict__ gXm, const float* __restrict__ gYm,
    const u16* __restrict__ evT, float* __restrict__ parts,
    int z, int kchunk) {
  extern __shared__ __align__(16) char smem[];   // 2 x (A 32KB + B 8KB)
  const int t = threadIdx.x;
  const int lane = t & 63, wave = t >> 6;
  const int rl = lane & 15, hi = lane >> 4;
  int b = blockIdx.x;
  const int zi = b % z; b /= z;
  const int mb = b & 31;
  const int mat = b >> 5;
  const float* A = mat ? gYm : gXm;
  const int m0 = mb * 256;
  const int kbeg = zi * kchunk;
  const int nt = kchunk >> 5;
  const int wm = wave * 64;

  f32x4 acc[4][8];
  #pragma unroll
  for (int a = 0; a < 4; a++)
    #pragma unroll
    for (int bb = 0; bb < 8; bb++) acc[a][bb] = f32x4{0.f, 0.f, 0.f, 0.f};

  auto STAGE = [&](int buf, int k0) {   // exactly 10 gl_lds16 per wave
    char* aB = smem + buf * 40960;
    #pragma unroll
    for (int jj = 0; jj < 8; jj++) {
      int R0 = wave * 64 + jj * 8;
      int r = R0 + (lane >> 3);
      int s = lane & 7;
      gl_lds16(A + (size_t)(m0 + r) * NV + k0 + ((s ^ (r & 7)) << 2), aB + R0 * 128);
    }
    char* bB = smem + buf * 40960 + 32768;
    #pragma unroll
    for (int jj = 0; jj < 2; jj++) {
      int R0 = wave * 32 + jj * 16;
      int n = R0 + (lane >> 2);
      int s = lane & 3;
      gl_lds16(evT + (size_t)n * NV + k0 + ((s ^ ((n >> 1) & 3)) << 3), bB + R0 * 64);
    }
  };

  auto COMPUTE = [&](int buf) {
    const float* Af = (const float*)(smem + buf * 40960);
    const u16* Bf = (const u16*)(smem + buf * 40960 + 32768);
    sh8 av[4], bv[8];
    #pragma unroll
    for (int mf = 0; mf < 4; mf++) {
      int r = wm + mf * 16 + rl;
      f32x4 lo = *(const f32x4*)(Af + r * 32 + (((2 * hi) ^ (r & 7)) << 2));
      f32x4 h4 = *(const f32x4*)(Af + r * 32 + (((2 * hi + 1) ^ (r & 7)) << 2));
      sh8 v;
      v[0] = (short)f2bf(lo[0]); v[1] = (short)f2bf(lo[1]);
      v[2] = (short)f2bf(lo[2]); v[3] = (short)f2bf(lo[3]);
      v[4] = (short)f2bf(h4[0]); v[5] = (short)f2bf(h4[1]);
      v[6] = (short)f2bf(h4[2]); v[7] = (short)f2bf(h4[3]);
      av[mf] = v;
    }
    #pragma unroll
    for (int nf = 0; nf < 8; nf++) {
      int n = nf * 16 + rl;
      bv[nf] = *(const sh8*)(Bf + n * 32 + ((hi ^ ((n >> 1) & 3)) << 3));
    }
    #pragma unroll
    for (int mf = 0; mf < 4; mf++)
      #pragma unroll
      for (int nf = 0; nf < 8; nf++)
        acc[mf][nf] = __builtin_amdgcn_mfma_f32_16x16x32_bf16(av[mf], bv[nf], acc[mf][nf], 0, 0, 0);
  };

  STAGE(0, kbeg);
  if (nt > 1) STAGE(1, kbeg + 32);
  for (int ti = 0; ti < nt; ti++) {
    if (ti + 1 < nt) { asm volatile("s_waitcnt vmcnt(10)" ::: "memory"); }
    else             { asm volatile("s_waitcnt vmcnt(0)" ::: "memory"); }
    __builtin_amdgcn_sched_barrier(0);
    __builtin_amdgcn_s_barrier();
    COMPUTE(ti & 1);
    __builtin_amdgcn_sched_barrier(0);
    __builtin_amdgcn_s_barrier();
    if (ti + 2 < nt) STAGE(ti & 1, kbeg + (ti + 2) * 32);
  }

  float* C = parts + (size_t)(mat * z + zi) * (NV * 128);
  #pragma unroll
  for (int mf = 0; mf < 4; mf++)
    #pragma unroll
    for (int nf = 0; nf < 8; nf++) {
      int row = m0 + wm + mf * 16 + hi * 4;
      int col = nf * 16 + rl;
      #pragma unroll
      for (int q = 0; q < 4; q++)
        C[(size_t)(row + q) * 128 + col] = acc[mf][nf][q];
    }
}

// =============== merged panel GEMM: blocks [0,512) Wbp, [512,1024) WbTp ====
__global__ __launch_bounds__(256) void gemm_panel2(
    const u16* __restrict__ WbP, const u16* __restrict__ WbTP,
    const u16* __restrict__ xwgT, const u16* __restrict__ xw2vT,
    float* __restrict__ parts) {
  __shared__ __align__(16) char smem[49152];   // 2 x (A 16KB + B 8KB)
  const int t = threadIdx.x;
  const int lane = t & 63, wave = t >> 6;
  const int rl = lane & 15, hi = lane >> 4;
  int bid = blockIdx.x;
  const u16* Apan; const u16* BT; int KT, ldbt, mb, z;
  float* Cbase;
  if (bid < 512) {
    Apan = WbP; BT = xwgT; KT = 64; ldbt = NG;
    mb = bid >> 3; z = bid & 7;
    Cbase = parts + (size_t)z * NV * 64;
  } else {
    bid -= 512;
    Apan = WbTP; BT = xw2vT; KT = 128; ldbt = NV;
    mb = bid >> 4; z = bid & 15;
    Cbase = parts + (size_t)8 * NV * 64 + (size_t)z * NG * 64;
  }
  const int ktpz = 8;
  const int kt0 = z * ktpz;
  const int wm = wave * 32;

  f32x4 acc[2][4];
  #pragma unroll
  for (int a = 0; a < 2; a++)
    #pragma unroll
    for (int b = 0; b < 4; b++) acc[a][b] = f32x4{0.f, 0.f, 0.f, 0.f};

  auto STAGE = [&](int buf, int kt) {   // exactly 6 gl_lds16 per wave
    char* aB = smem + buf * 24576;
    const u16* tbase = Apan + ((size_t)mb * KT + kt) * 8192;
    #pragma unroll
    for (int jj = 0; jj < 4; jj++) {
      int j = wave * 4 + jj;
      gl_lds16(tbase + j * 512 + lane * 8, aB + j * 1024);
    }
    char* bB = aB + 16384;
    #pragma unroll
    for (int jj = 0; jj < 2; jj++) {
      int j = wave * 2 + jj;
      int n = 8 * j + (lane >> 3);
      const u16* srcb = BT + (size_t)n * ldbt + kt * 64 + (((lane & 7) ^ (n & 7)) << 3);
      gl_lds16(srcb, bB + j * 1024);
    }
  };

  auto COMPUTE = [&](int buf) {
    const u16* Af = (const u16*)(smem + buf * 24576);
    const u16* Bf = Af + 8192;
    #pragma unroll
    for (int step = 0; step < 2; step++) {
      sh8 av[2], bv[4];
      int s = step * 4 + hi;
      #pragma unroll
      for (int mf = 0; mf < 2; mf++) {
        int r = wm + mf * 16 + rl;
        av[mf] = *(const sh8*)(Af + r * 64 + ((s ^ (r & 7)) << 3));
      }
      #pragma unroll
      for (int nf = 0; nf < 4; nf++) {
        int n = nf * 16 + rl;
        bv[nf] = *(const sh8*)(Bf + n * 64 + ((s ^ (n & 7)) << 3));
      }
      #pragma unroll
      for (int mf = 0; mf < 2; mf++)
        #pragma unroll
        for (int nf = 0; nf < 4; nf++)
          acc[mf][nf] = __builtin_amdgcn_mfma_f32_16x16x32_bf16(av[mf], bv[nf], acc[mf][nf], 0, 0, 0);
    }
  };

  STAGE(0, kt0);
  STAGE(1, kt0 + 1);
  for (int ti = 0; ti < ktpz; ti++) {
    if (ti + 1 < ktpz) { asm volatile("s_waitcnt vmcnt(6)" ::: "memory"); }
    else               { asm volatile("s_waitcnt vmcnt(0)" ::: "memory"); }
    __builtin_amdgcn_sched_barrier(0);
    __builtin_amdgcn_s_barrier();
    COMPUTE(ti & 1);
    __builtin_amdgcn_sched_barrier(0);
    __builtin_amdgcn_s_barrier();
    if (ti + 2 < ktpz) STAGE(ti & 1, kt0 + ti + 2);
  }

  #pragma unroll
  for (int mf = 0; mf < 2; mf++)
    #pragma unroll
    for (int nf = 0; nf < 4; nf++) {
      int row = mb * 128 + wm + mf * 16 + hi * 4;
      int col = nf * 16 + rl;
      #pragma unroll
      for (int q = 0; q < 4; q++)
        Cbase[(size_t)(row + q) * 64 + col] = acc[mf][nf][q];
    }
}

// reduce both panel results: Wbp (8 slices) then WbTp (16 slices)
__global__ void k_reduce_both(const float* __restrict__ parts,
    float* __restrict__ Wbp, float* __restrict__ WbTp) {
  int i = (blockIdx.x * 256 + threadIdx.x) * 4;
  if (i < NV * 64) {
    float4 s = *(const float4*)(parts + i);
    for (int z = 1; z < 8; z++) {
      float4 v = *(const float4*)(parts + (size_t)z * NV * 64 + i);
      s.x += v.x; s.y += v.y; s.z += v.z; s.w += v.w;
    }
    *(float4*)(Wbp + i) = s;
  } else {
    int j = i - NV * 64;
    if (j < NG * 64) {
      const float* src = parts + (size_t)8 * NV * 64;
      float4 s = *(const float4*)(src + j);
      for (int z = 1; z < 16; z++) {
        float4 v = *(const float4*)(src + (size_t)z * NG * 64 + j);
        s.x += v.x; s.y += v.y; s.z += v.z; s.w += v.w;
      }
      *(float4*)(WbTp + j) = s;
    }
  }
}

// =============== generic bf16 GEMM (spec + row-tier Wb), BM=128, BN=64 ======
__global__ __launch_bounds__(256) void gemm_bf16(
    const u16* __restrict__ Ab, int lda, const u16* __restrict__ BT, int ldbt,
    float* __restrict__ parts, int M, int kchunk) {
  __shared__ __align__(16) char smem[49152];
  const int t = threadIdx.x;
  const int lane = t & 63, wave = t >> 6;
  const int m0 = blockIdx.x * 128;
  const int kbeg = blockIdx.z * kchunk;
  const int nt = kchunk >> 6;
  const int wm = (wave >> 1) * 64, wn = (wave & 1) * 32;
  const int arl = lane >> 3, asl = lane & 7;

  f32x4 acc[4][2];
  #pragma unroll
  for (int a = 0; a < 4; a++)
    #pragma unroll
    for (int b = 0; b < 2; b++) acc[a][b] = f32x4{0.f, 0.f, 0.f, 0.f};

  auto STAGE = [&](int buf, int k0) {
    char* base = smem + buf * 24576;
    #pragma unroll
    for (int j = 0; j < 4; j++) {
      int R0 = (wave * 4 + j) * 8;
      int r = R0 + arl;
      int gs = asl ^ (r & 7);
      gl_lds16(Ab + (size_t)(m0 + r) * lda + k0 + gs * 8, base + R0 * 128);
    }
    char* bb = base + 16384;
    #pragma unroll
    for (int j = 0; j < 2; j++) {
      int R0 = (wave * 2 + j) * 8;
      int r = R0 + arl;
      int gs = asl ^ (r & 7);
      gl_lds16(BT + (size_t)r * ldbt + k0 + gs * 8, bb + R0 * 128);
    }
  };

  auto COMPUTE = [&](int buf) {
    char* base = smem + buf * 24576;
    const u16* Af = (const u16*)base;
    const u16* Bf = (const u16*)(base + 16384);
    #pragma unroll
    for (int kk = 0; kk < 2; kk++) {
      sh8 av[4], bv[2];
      #pragma unroll
      for (int mf = 0; mf < 4; mf++) {
        int r = wm + mf * 16 + (lane & 15);
        int g = kk * 4 + (lane >> 4);
        av[mf] = *(const sh8*)(Af + r * 64 + (g ^ (r & 7)) * 8);
      }
      #pragma unroll
      for (int nf = 0; nf < 2; nf++) {
        int r = wn + nf * 16 + (lane & 15);
        int g = kk * 4 + (lane >> 4);
        bv[nf] = *(const sh8*)(Bf + r * 64 + (g ^ (r & 7)) * 8);
      }
      #pragma unroll
      for (int mf = 0; mf < 4; mf++)
        #pragma unroll
        for (int nf = 0; nf < 2; nf++)
          acc[mf][nf] = __builtin_amdgcn_mfma_f32_16x16x32_bf16(av[mf], bv[nf], acc[mf][nf], 0, 0, 0);
    }
  };

  STAGE(0, kbeg);
  if (nt > 1) STAGE(1, kbeg + 64);
  for (int ti = 0; ti < nt; ti++) {
    if (ti + 1 < nt) { asm volatile("s_waitcnt vmcnt(6)" ::: "memory"); }
    else             { asm volatile("s_waitcnt vmcnt(0)" ::: "memory"); }
    __builtin_amdgcn_sched_barrier(0);
    __builtin_amdgcn_s_barrier();
    COMPUTE(ti & 1);
    __builtin_amdgcn_sched_barrier(0);
    __builtin_amdgcn_s_barrier();
    if (ti + 2 < nt) STAGE(ti & 1, kbeg + (ti + 2) * 64);
  }

  float* C = parts + (size_t)blockIdx.z * M * 64;
  #pragma unroll
  for (int mf = 0; mf < 4; mf++)
    #pragma unroll
    for (int nf = 0; nf < 2; nf++) {
      int row = m0 + wm + mf * 16 + (lane >> 4) * 4;
      int col = wn + nf * 16 + (lane & 15);
      #pragma unroll
      for (int q = 0; q < 4; q++)
        C[(size_t)(row + q) * 64 + col] = acc[mf][nf][q];
    }
}

// ---------------- ATRANS fallback GEMM (low-ws WbT path) ----------------
template<int BN, bool AF32, bool ATRANS>
__global__ __launch_bounds__(256) void gemm_k(
    const void* __restrict__ Aptr, const void* __restrict__ A2, int zsplit2,
    const u16* __restrict__ BT, float* __restrict__ Cpart,
    int M, int N, int lda, int ldbt, int kchunk) {
  constexpr int NF = BN / 32;
  __shared__ u16 lA[128 * 40];
  __shared__ u16 lB[BN * 40];
  const int t = threadIdx.x;
  const int m0 = blockIdx.x * 128, n0 = blockIdx.y * BN;
  const void* Ause = Aptr;
  int kz = blockIdx.z;
  if (A2 != nullptr && kz >= zsplit2) { Ause = A2; kz -= zsplit2; }
  const int kbeg = kz * kchunk;
  const int lane = t & 63, wave = t >> 6;
  const int wm = (wave >> 1) * 64, wn = (wave & 1) * (BN / 2);
  f32x4 zero = {0.f, 0.f, 0.f, 0.f};
  f32x4 acc[4][NF];
  #pragma unroll
  for (int a = 0; a < 4; a++)
    #pragma unroll
    for (int b = 0; b < NF; b++) acc[a][b] = zero;

  for (int k0 = kbeg; k0 < kbeg + kchunk; k0 += 32) {
    if constexpr (!ATRANS) {
      const int r = t >> 1, cc = (t & 1) * 16;
      const u16* A = (const u16*)Ause + (size_t)(m0 + r) * lda + k0 + cc;
      *(uint4*)&lA[r * 40 + cc] = *(const uint4*)A;
      *(uint4*)&lA[r * 40 + cc + 8] = *(const uint4*)(A + 8);
    } else {
      const int kl = t >> 3, mb = (t & 7) * 16;
      const u16* A = (const u16*)Ause + (size_t)(k0 + kl) * lda + m0 + mb;
      u16 vals[16];
      *(uint4*)&vals[0] = *(const uint4*)A;
      *(uint4*)&vals[8] = *(const uint4*)(A + 8);
      #pragma unroll
      for (int j = 0; j < 16; j++) lA[(mb + j) * 40 + kl] = vals[j];
    }
    if constexpr (BN == 64) {
      const int r = t >> 2, cc = (t & 3) * 8;
      const u16* B = BT + (size_t)(n0 + r) * ldbt + k0 + cc;
      *(uint4*)&lB[r * 40 + cc] = *(const uint4*)B;
    } else {
      const int r = t >> 1, cc = (t & 1) * 16;
      const u16* B = BT + (size_t)(n0 + r) * ldbt + k0 + cc;
      *(uint4*)&lB[r * 40 + cc] = *(const uint4*)B;
      *(uint4*)&lB[r * 40 + cc + 8] = *(const uint4*)(B + 8);
    }
    __syncthreads();
    sh8 af[4], bfv[NF];
    #pragma unroll
    for (int mf = 0; mf < 4; mf++)
      af[mf] = *(const sh8*)&lA[(wm + mf * 16 + (lane & 15)) * 40 + (lane >> 4) * 8];
    #pragma unroll
    for (int nf = 0; nf < NF; nf++)
      bfv[nf] = *(const sh8*)&lB[(wn + nf * 16 + (lane & 15)) * 40 + (lane >> 4) * 8];
    #pragma unroll
    for (int mf = 0; mf < 4; mf++)
      #pragma unroll
      for (int nf = 0; nf < NF; nf++)
        acc[mf][nf] = __builtin_amdgcn_mfma_f32_16x16x32_bf16(af[mf], bfv[nf], acc[mf][nf], 0, 0, 0);
    __syncthreads();
  }
  float* C = Cpart + (size_t)blockIdx.z * M * N;
  #pragma unroll
  for (int mf = 0; mf < 4; mf++)
    #pragma unroll
    for (int nf = 0; nf < NF; nf++) {
      const int row = m0 + wm + mf * 16 + (lane >> 4) * 4;
      const int col = n0 + wn + nf * 16 + (lane & 15);
      #pragma unroll
      for (int q = 0; q < 4; q++)
        C[(size_t)(row + q) * N + col] = acc[mf][nf][q];
    }
}

__global__ void k_reduce(const float* __restrict__ parts, float* __restrict__ dst, int len, int nz) {
  int i = (blockIdx.x * 256 + threadIdx.x) * 4;
  if (i >= len) return;
  float4 s = *(const float4*)(parts + i);
  for (int z = 1; z < nz; z++) {
    float4 v = *(const float4*)(parts + (size_t)z * len + i);
    s.x += v.x; s.y += v.y; s.z += v.z; s.w += v.w;
  }
  *(float4*)(dst + i) = s;
}

// reduce 64 spec slices + apply exp(-evals*t): Es[k][c]
__global__ void k_reduce_es(const float* __restrict__ parts,
    const float* __restrict__ evals, const float* __restrict__ dt,
    float* __restrict__ Es) {
  int i = blockIdx.x * 256 + threadIdx.x;   // 8192 elems
  float s = 0.f;
  #pragma unroll 8
  for (int z = 0; z < 64; z++) s += parts[(size_t)z * 8192 + i];
  int k = i >> 6, c = i & 63;
  Es[i] = expf(-evals[k] * fmaxf(dt[c], 1e-8f)) * s;
}

// two matrices packed: dst[mat*len + j] = sum_z parts[(mat*nz+z)*len + j]
__global__ void k_reduce2(const float* __restrict__ parts, float* __restrict__ dst, int len, int nz) {
  int i = (blockIdx.x * 256 + threadIdx.x) * 4;
  if (i >= 2 * len) return;
  int mat = i / len, j = i - mat * len;
  const float* src = parts + (size_t)mat * nz * len + j;
  float4 s = *(const float4*)src;
  for (int z = 1; z < nz; z++) {
    float4 v = *(const float4*)(src + (size_t)z * len);
    s.x += v.x; s.y += v.y; s.z += v.z; s.w += v.w;
  }
  *(float4*)(dst + i) = s;
}

// ---------------- fused lin1/lin2 (C_IN=128 -> DW=64) ----------------
__global__ __launch_bounds__(256) void k_lin_both(const float* __restrict__ x_in,
    const float* __restrict__ graph_x, const float* __restrict__ W1,
    const float* __restrict__ b1, const float* __restrict__ W2,
    const float* __restrict__ b2, float* __restrict__ outV, float* __restrict__ outG) {
  __shared__ float lW[8192];
  __shared__ float lb[64];
  int bb = blockIdx.x;
  bool isV = bb < 2048;
  const float* W = isV ? W1 : W2;
  const float* bi = isV ? b1 : b2;
  const float* A = isV ? x_in : graph_x;
  float* out = isV ? outV : outG;
  int rb = isV ? bb : bb - 2048;
  int t = threadIdx.x;
  for (int i = t; i < 8192; i += 256) lW[i] = W[i];
  if (t < 64) lb[t] = bi[t];
  __syncthreads();
  int row = rb * 4 + (t >> 6), c = t & 63;
  const float* Ar = A + (size_t)row * 128;
  float acc = lb[c];
  #pragma unroll 8
  for (int k = 0; k < 128; k++) acc += Ar[k] * lW[k * 64 + c];
  out[(size_t)row * 64 + c] = acc;
}

// ====== fused xd/gradfeat/mlp0: h1 = relu([dx, xd, gf] @ W0 + b0) ==========
// xd, gf never materialized (LDS only). Dynamic LDS ~116KB.
__global__ __launch_bounds__(256) void k_xdgf_mlp0(const float* __restrict__ evecs,
    const float* __restrict__ GXE, const float* __restrict__ GYE,
    const float* __restrict__ Es, const float* __restrict__ Are,
    const float* __restrict__ Aim, const float* __restrict__ dx,
    const float* __restrict__ W0, const float* __restrict__ b0,
    float* __restrict__ h1) {
  extern __shared__ float dls[];
  float* lE  = dls;               // 8192
  float* lr  = lE + 8192;         // 4096
  float* li  = lr + 4096;         // 4096
  float* lW  = li + 4096;         // 12288
  float* lb0 = lW + 12288;        // 64
  float* lgx = lb0 + 64;          // 256
  float* lgy = lgx + 256;         // 256
  float* lxd = lgy + 256;         // 256
  float* lgf = lxd + 256;         // 256
  int t = threadIdx.x;
  for (int i = t; i < 8192; i += 256) lE[i] = Es[i];
  for (int i = t; i < 4096; i += 256) { lr[i] = Are[i]; li[i] = Aim[i]; }
  for (int i = t; i < 12288; i += 256) lW[i] = W0[i];
  if (t < 64) lb0[t] = b0[t];
  __syncthreads();
  int wr = t >> 6, c = t & 63;
  int row = blockIdx.x * 4 + wr;
  const float* er = evecs + (size_t)row * 128;
  const float* xr = GXE + (size_t)row * 128;
  const float* yr = GYE + (size_t)row * 128;
  float a0 = 0, a1 = 0, a2 = 0;
  #pragma unroll 8
  for (int k = 0; k < 128; k++) {
    float s = lE[k * 64 + c];
    a0 += er[k] * s; a1 += xr[k] * s; a2 += yr[k] * s;
  }
  lgx[wr * 64 + c] = a1;
  lgy[wr * 64 + c] = a2;
  __syncthreads();
  float br = 0.f, bi = 0.f;
  #pragma unroll 8
  for (int k = 0; k < 64; k++) {
    float gx = lgx[wr * 64 + k], gy = lgy[wr * 64 + k];
    float ar = lr[k * 64 + c], ai = li[k * 64 + c];
    br += gx * ar - gy * ai;
    bi += gy * ar + gx * ai;
  }
  lxd[wr * 64 + c] = a0;
  lgf[wr * 64 + c] = tanhf(a1 * br + a2 * bi);
  __syncthreads();
  const float* dr = dx + (size_t)row * 64;
  float acc = lb0[c];
  #pragma unroll 8
  for (int k = 0; k < 64; k++) acc += dr[k] * lW[k * 64 + c];
  #pragma unroll 8
  for (int k = 0; k < 64; k++) acc += lxd[wr * 64 + k] * lW[(64 + k) * 64 + c];
  #pragma unroll 8
  for (int k = 0; k < 64; k++) acc += lgf[wr * 64 + k] * lW[(128 + k) * 64 + c];
  h1[(size_t)row * 64 + c] = fmaxf(acc, 0.f);
}

// fused mlp1+mlp2+residual+dual projection (post-MLP diffx never stored)
__global__ __launch_bounds__(256) void k_mlp12_dual(const float* __restrict__ h1,
    const float* __restrict__ W1, const float* __restrict__ b1,
    const float* __restrict__ W2, const float* __restrict__ b2,
    const float* __restrict__ dx, const float* __restrict__ gsw,
    const float* __restrict__ sgw, float* __restrict__ xw_v,
    float* __restrict__ xw2_v, u16* __restrict__ xw2vT) {
  __shared__ float l1[4096], l2[4096], lg[4096], ls[4096];
  __shared__ float lb1[64], lb2[64], lrow[256], lrow2[256];
  int t = threadIdx.x;
  for (int i = t; i < 4096; i += 256) {
    l1[i] = W1[i]; l2[i] = W2[i]; lg[i] = gsw[i]; ls[i] = sgw[i];
  }
  if (t < 64) lb1[t] = b1[t];
  else if (t < 128) lb2[t - 64] = b2[t - 64];
  __syncthreads();
  int wr = t >> 6, c = t & 63;
  int row = blockIdx.x * 4 + wr;
  const float* hr = h1 + (size_t)row * 64;
  float h2 = lb1[c];
  #pragma unroll 8
  for (int k = 0; k < 64; k++) h2 += hr[k] * l1[k * 64 + c];
  h2 = fmaxf(h2, 0.f);
  lrow[wr * 64 + c] = h2;
  __syncthreads();
  float o = lb2[c] + dx[(size_t)row * 64 + c];
  #pragma unroll 8
  for (int k = 0; k < 64; k++) o += lrow[wr * 64 + k] * l2[k * 64 + c];
  lrow2[wr * 64 + c] = o;
  __syncthreads();
  float p = 0.f, q = 0.f;
  #pragma unroll 8
  for (int k = 0; k < 64; k++) {
    float a = lrow2[wr * 64 + k];
    p += a * lg[k * 64 + c];
    q += a * ls[k * 64 + c];
  }
  xw_v[(size_t)row * 64 + c] = p;
  xw2_v[(size_t)row * 64 + c] = q;
  xw2vT[(size_t)c * NV + row] = f2bf(q);
}

// ---------------- small fp32 matmul (64x64 weights) ----------------
template<bool BIAS, bool RELU, bool RES>
__global__ __launch_bounds__(256) void k_mm64(const float* __restrict__ A,
    const float* __restrict__ W, const float* __restrict__ b,
    const float* __restrict__ res, float* __restrict__ out) {
  __shared__ float lW[4096];
  __shared__ float lb[64];
  int t = threadIdx.x;
  for (int i = t; i < 4096; i += 256) lW[i] = W[i];
  if constexpr (BIAS) { if (t < 64) lb[t] = b[t]; }
  __syncthreads();
  int row = blockIdx.x * 4 + (t >> 6), c = t & 63;
  const float* Ar = A + (size_t)row * 64;
  float acc = 0.f;
  #pragma unroll 8
  for (int k = 0; k < 64; k++) acc += Ar[k] * lW[k * 64 + c];
  if constexpr (BIAS) acc += lb[c];
  if constexpr (RES) acc += res[(size_t)row * 64 + c];
  if constexpr (RELU) acc = fmaxf(acc, 0.f);
  out[(size_t)row * 64 + c] = acc;
}

// ---------------- GCN agg + next matmul fused ----------------
__global__ __launch_bounds__(64) void k_aggmm(const float* __restrict__ xw,
    const int* __restrict__ rp, const int* __restrict__ csrc,
    const float* __restrict__ cnorm, const float* __restrict__ invdeg,
    const float* __restrict__ b1, const float* __restrict__ W2, float* __restrict__ out) {
  __shared__ float lrow[64];
  int g = blockIdx.x, c = threadIdx.x;
  float acc = xw[(size_t)g * 64 + c] * invdeg[g] + b1[c];
  int j1 = rp[g + 1];
  for (int j = rp[g]; j < j1; j++) acc += cnorm[j] * xw[(size_t)csrc[j] * 64 + c];
  acc = fmaxf(acc, 0.f);
  lrow[c] = acc;
  __syncthreads();
  float o = 0.f;
  #pragma unroll 8
  for (int k = 0; k < 64; k++) o += lrow[k] * W2[k * 64 + c];
  out[(size_t)g * 64 + c] = o;
}

__global__ __launch_bounds__(64) void k_aggdual(const float* __restrict__ xw,
    const int* __restrict__ rp, const int* __restrict__ csrc,
    const float* __restrict__ cnorm, const float* __restrict__ invdeg,
    const float* __restrict__ b2, const float* __restrict__ gsw,
    const float* __restrict__ sgw, float* __restrict__ xw_g,
    float* __restrict__ xw2_g, u16* __restrict__ xwgT) {
  __shared__ float lrow[64];
  int g = blockIdx.x, c = threadIdx.x;
  float acc = xw[(size_t)g * 64 + c] * invdeg[g] + b2[c];
  int j1 = rp[g + 1];
  for (int j = rp[g]; j < j1; j++) acc += cnorm[j] * xw[(size_t)csrc[j] * 64 + c];
  lrow[c] = acc;
  __syncthreads();
  float p = 0.f, q = 0.f;
  #pragma unroll 8
  for (int k = 0; k < 64; k++) {
    float r = lrow[k];
    p += r * gsw[k * 64 + c];
    q += r * sgw[k * 64 + c];
  }
  xw_g[(size_t)g * 64 + c] = p;
  xw2_g[(size_t)g * 64 + c] = q;
  xwgT[(size_t)c * NG + g] = f2bf(p);
}

// ---------------- fused bipartite combine ----------------
__global__ void k_combine(const float* __restrict__ xw_v, const float* __restrict__ Wbp,
    const float* __restrict__ xw2_v, const float* __restrict__ xw_g,
    const float* __restrict__ WbTp, const float* __restrict__ xw2_g,
    const float* __restrict__ inv_deg_v, const float* __restrict__ rsv,
    const float* __restrict__ inv_deg_g, const float* __restrict__ rsg,
    const float* __restrict__ gsb, const float* __restrict__ sgb,
    float* __restrict__ dx, float* __restrict__ gx) {
  int idx = blockIdx.x * 256 + threadIdx.x;
  if (idx < NV * 64) {
    int v = idx >> 6, c = idx & 63;
    dx[idx] = 0.5f * (xw_v[idx] * inv_deg_v[v] + Wbp[idx] * rsv[v] + gsb[c] + xw2_v[idx] + sgb[c]);
  } else {
    int j = idx - NV * 64;
    int g = j >> 6, c = j & 63;
    gx[j] = 0.5f * (xw_g[j] + gsb[c] + xw2_g[j] * inv_deg_g[g] + WbTp[j] * rsg[g] + sgb[c]);
  }
}

// =================================================================
extern "C" void kernel_launch(void* const* d_in, const int* in_sizes, int n_in,
                              void* d_out, int out_size, void* d_ws, size_t ws_size,
                              hipStream_t stream) {
  const float* vertices  = (const float*)d_in[0];
  const float* graph_pos = (const float*)d_in[1];
  const float* x_in      = (const float*)d_in[2];
  const float* graph_x   = (const float*)d_in[3];
  const float* mass      = (const float*)d_in[4];
  const float* evals     = (const float*)d_in[5];
  const float* evecs     = (const float*)d_in[6];
  const float* gradX     = (const float*)d_in[7];
  const float* gradY     = (const float*)d_in[8];
  const int*   eidx      = (const int*)d_in[9];
  const float* ew        = (const float*)d_in[10];
  const float* lin1_w    = (const float*)d_in[11];
  const float* lin1_b    = (const float*)d_in[12];
  const float* lin2_w    = (const float*)d_in[13];
  const float* lin2_b    = (const float*)d_in[14];
  const float* diff_time = (const float*)d_in[15];
  const float* A_re      = (const float*)d_in[16];
  const float* A_im      = (const float*)d_in[17];
  const float* mlp_w0    = (const float*)d_in[18];
  const float* mlp_b0    = (const float*)d_in[19];
  const float* mlp_w1    = (const float*)d_in[20];
  const float* mlp_b1    = (const float*)d_in[21];
  const float* mlp_w2    = (const float*)d_in[22];
  const float* mlp_b2    = (const float*)d_in[23];
  const float* gcn1_w    = (const float*)d_in[24];
  const float* gcn1_b    = (const float*)d_in[25];
  const float* gcn2_w    = (const float*)d_in[26];
  const float* gcn2_b    = (const float*)d_in[27];
  const float* gs_w      = (const float*)d_in[28];
  const float* gs_b      = (const float*)d_in[29];
  const float* sg_w      = (const float*)d_in[30];
  const float* sg_b      = (const float*)d_in[31];

  char* base = (char*)d_ws;
  size_t off = 0;
  auto alloc = [&](size_t nbytes) -> void* {
    void* p = base + off;
    off += (nbytes + 255) & ~(size_t)255;
    return p;
  };
  const size_t MBy = 1024 * 1024;
  u16*   evecsT  = (u16*)alloc((size_t)128 * NV * 2);
  float* GXE2    = (float*)alloc((size_t)2 * NV * 128 * 4); // GXE | GYE contiguous
  float* GXE     = GXE2;
  float* GYE     = GXE2 + (size_t)NV * 128;
  u16*   mdxT    = (u16*)alloc((size_t)64 * NV * 2);
  float* Es      = (float*)alloc(8192 * 4);
  float* diffx   = (float*)alloc((size_t)NV * 64 * 4);
  float* gxb     = (float*)alloc((size_t)NG * 64 * 4);
  float* h1      = (float*)alloc((size_t)NV * 64 * 4);
  float* xw_v    = (float*)alloc((size_t)NV * 64 * 4);
  float* xw2_v   = (float*)alloc((size_t)NV * 64 * 4);
  float* xw_g    = (float*)alloc((size_t)NG * 64 * 4);
  float* xw2_g   = (float*)alloc((size_t)NG * 64 * 4);
  float* xw1     = (float*)alloc((size_t)NG * 64 * 4);
  float* xw2k    = (float*)alloc((size_t)NG * 64 * 4);
  u16*   xwgT    = (u16*)alloc((size_t)64 * NG * 2);
  u16*   xw2vT   = (u16*)alloc((size_t)64 * NV * 2);
  float* Wbp     = (float*)alloc((size_t)NV * 64 * 4);
  float* WbTp    = (float*)alloc((size_t)NG * 64 * 4);
  float* deg_v   = (float*)alloc(NV * 4);
  float* inv_deg_v = (float*)alloc(NV * 4);
  float* rsv     = (float*)alloc(NV * 4);
  float* deg_g   = (float*)alloc(NG * 4);
  float* inv_deg_g = (float*)alloc(NG * 4);
  float* rsg     = (float*)alloc(NG * 4);
  float* deg_e   = (float*)alloc(NG * 4);
  float* invdeg_e = (float*)alloc(NG * 4);
  float* dinv_e  = (float*)alloc(NG * 4);
  int*   cnt     = (int*)alloc(NG * 4);
  int*   row_ptr = (int*)alloc((NG + 1) * 4);
  int*   cursor  = (int*)alloc(NG * 4);
  int*   csr_src = (int*)alloc(NE * 4);
  float* csr_norm = (float*)alloc(NE * 4);

  size_t avail = ws_size > off ? ws_size - off : 0;
  u16 *WbP = nullptr, *WbTP = nullptr, *WbRow = nullptr;
  float* parts;
  int zsu;
  if (avail >= 162 * MBy) {
    WbP  = (u16*)alloc((size_t)NV * NG * 2);   // 64 MB panels
    WbTP = (u16*)alloc((size_t)NG * NV * 2);   // 64 MB panels
    parts = (float*)alloc(32 * MBy);
    zsu = 4;
  } else if (avail >= 97 * MBy) {
    WbRow = (u16*)alloc((size_t)NV * NG * 2);  // 64 MB row-major fallback
    parts = (float*)alloc(32 * MBy);
    zsu = 4;
  } else {
    WbRow = (u16*)alloc((size_t)NV * NG * 2);
    parts = (float*)alloc(16 * MBy);
    zsu = 2;
  }
  if (off > ws_size) return;  // insufficient workspace -> fail loudly

  dim3 B256(256);

  // ---------- setup ----------
  k_fill4<<<dim3(80), B256, 0, stream>>>(deg_v, deg_g, deg_e, cnt);
  k_wb_build<<<dim3(128, 64), B256, 0, stream>>>(vertices, graph_pos, WbRow, WbP, WbTP, deg_v, deg_g);
  k_edge_prep<<<dim3(256), B256, 0, stream>>>(eidx, ew, deg_e, cnt);
  k_recips<<<dim3(64), B256, 0, stream>>>(deg_v, inv_deg_v, rsv, deg_g, inv_deg_g, rsg,
                                          deg_e, invdeg_e, dinv_e);
  k_scan<<<dim3(1), dim3(1024), 0, stream>>>(cnt, row_ptr, cursor);
  k_scatter<<<dim3(256), B256, 0, stream>>>(eidx, ew, dinv_e, cursor, csr_src, csr_norm);
  k_evecsT<<<dim3(256, 4), B256, 0, stream>>>(evecs, evecsT);
  // GXE = gradX @ evecs, GYE = gradY @ evecs (round-8 proven config)
  gemm_setup3<<<dim3(2 * 32 * zsu), B256, 81920, stream>>>(
      gradX, gradY, evecsT, parts, zsu, 8192 / zsu);
  k_reduce2<<<dim3(2048), B256, 0, stream>>>(parts, GXE2, NV * 128, zsu);
  k_lin_both<<<dim3(3072), B256, 0, stream>>>(x_in, graph_x, lin1_w, lin1_b, lin2_w, lin2_b, diffx, gxb);

  // ---------- 4 blocks ----------
  for (int i = 0; i < 4; i++) {
    const float* dtrow = diff_time + i * 64;
    // spec = evecsT @ (mass*dx)^T via MFMA; fused reduce+exp
    k_mdxT<<<dim3(128), B256, 0, stream>>>(diffx, mass, mdxT);
    gemm_bf16<<<dim3(1, 1, 64), B256, 0, stream>>>(evecsT, NV, mdxT, NV, parts, 128, 128);
    k_reduce_es<<<dim3(32), B256, 0, stream>>>(parts, evals, dtrow, Es);
    // fused xd/gradfeat/mlp0 (xd, gf never materialized)
    k_xdgf_mlp0<<<dim3(2048), B256, 118880, stream>>>(evecs, GXE, GYE, Es,
        A_re + i * 4096, A_im + i * 4096, diffx, mlp_w0 + i * 12288, mlp_b0 + i * 64, h1);
    // fused mlp12 + vertex-side dual projection (no post-MLP diffx store)
    k_mlp12_dual<<<dim3(2048), B256, 0, stream>>>(h1, mlp_w1 + i * 4096, mlp_b1 + i * 64,
        mlp_w2 + i * 4096, mlp_b2 + i * 64, diffx, gs_w + i * 4096, sg_w + i * 4096,
        xw_v, xw2_v, xw2vT);
    // graph GCN (2 convs) + graph-side dual projection
    k_mm64<false, false, false><<<dim3(1024), B256, 0, stream>>>(gxb, gcn1_w + i * 4096, nullptr, nullptr, xw1);
    k_aggmm<<<dim3(NG), dim3(64), 0, stream>>>(xw1, row_ptr, csr_src, csr_norm, invdeg_e,
        gcn1_b + i * 64, gcn2_w + i * 4096, xw2k);
    k_aggdual<<<dim3(NG), dim3(64), 0, stream>>>(xw2k, row_ptr, csr_src, csr_norm, invdeg_e,
        gcn2_b + i * 64, gs_w + i * 4096, sg_w + i * 4096, xw_g, xw2_g, xwgT);
    if (WbP != nullptr) {
      // both Wb GEMMs in one launch (blocks 0-511: Wbp, 512-1023: WbTp)
      gemm_panel2<<<dim3(1024), B256, 0, stream>>>(WbP, WbTP, xwgT, xw2vT, parts);
      k_reduce_both<<<dim3(768), B256, 0, stream>>>(parts, Wbp, WbTp);
    } else {
      gemm_bf16<<<dim3(64, 1, 8), B256, 0, stream>>>(WbRow, NG, xwgT, NG, parts, NV, 512);
      k_reduce<<<dim3(512), B256, 0, stream>>>(parts, Wbp, NV * 64, 8);
      gemm_k<64, false, true><<<dim3(32, 1, 16), B256, 0, stream>>>(
          WbRow, nullptr, 1 << 30, xw2vT, parts, NG, 64, NG, NV, 512);
      k_reduce<<<dim3(256), B256, 0, stream>>>(parts, WbTp, NG * 64, 16);
    }
    // fused combine
    k_combine<<<dim3(3072), B256, 0, stream>>>(xw_v, Wbp, xw2_v, xw_g, WbTp, xw2_g,
        inv_deg_v, rsv, inv_deg_g, rsg, gs_b + i * 64, sg_b + i * 64, diffx, gxb);
  }

  hipMemcpyAsync(d_out, diffx, (size_t)NV * 64 * 4, hipMemcpyDeviceToDevice, stream);
}

// Round 12
// 951.251 us; speedup vs baseline: 1.1236x; 1.1236x over previous
//
#include <hip/hip_runtime.h>
#include <hip/hip_bf16.h>

typedef unsigned short u16;
typedef __attribute__((ext_vector_type(8))) short sh8;     // 8 x bf16 (4 VGPRs)
typedef __attribute__((ext_vector_type(4))) float f32x4;   // MFMA accum

#define NV 8192
#define NG 4096
#define NE 65536

__device__ __forceinline__ u16 f2bf(float f) {
  __hip_bfloat16 h = __float2bfloat16(f);
  return __builtin_bit_cast(u16, h);
}

// async global->LDS, 16B per lane; LDS dest = wave-uniform base + lane*16
__device__ __forceinline__ void gl_lds16(const void* g, void* l) {
  __builtin_amdgcn_global_load_lds(
      (const __attribute__((address_space(1))) void*)g,
      (__attribute__((address_space(3))) void*)l, 16, 0, 0);
}

// ---------------- setup fills ----------------
__global__ void k_fill4(float* __restrict__ deg_v, float* __restrict__ deg_g,
                        float* __restrict__ deg_e, int* __restrict__ cnt) {
  int i = blockIdx.x * 256 + threadIdx.x;
  if (i < NV) deg_v[i] = 1.f;
  int j = i - NV;
  if (j >= 0 && j < NG) deg_g[j] = 1.f;
  j -= NG;
  if (j >= 0 && j < NG) deg_e[j] = 1.f;
  j -= NG;
  if (j >= 0 && j < NG) cnt[j] = 0;
}

// ---------------- Wb build ----------------
__global__ __launch_bounds__(256) void k_wb_build(
    const float* __restrict__ vert, const float* __restrict__ gpos,
    u16* __restrict__ WbRow, u16* __restrict__ WbP, u16* __restrict__ WbTP,
    float* __restrict__ deg_v, float* __restrict__ deg_g) {
  __shared__ float lv[192], lg[192], colp[256];
  __shared__ float tile[64][65];
  int t = threadIdx.x;
  int v0 = blockIdx.x * 64, g0 = blockIdx.y * 64;
  if (t < 192) { lv[t] = vert[(size_t)v0 * 3 + t]; lg[t] = gpos[(size_t)g0 * 3 + t]; }
  __syncthreads();
  int w = t >> 6, lane = t & 63;
  float gx_ = lg[lane * 3], gy_ = lg[lane * 3 + 1], gz_ = lg[lane * 3 + 2];
  float csum = 0.f;
  #pragma unroll 4
  for (int s = 0; s < 16; s++) {
    int vl = w + 4 * s;
    float dx = lv[vl * 3] - gx_, dy = lv[vl * 3 + 1] - gy_, dz = lv[vl * 3 + 2] - gz_;
    float d = sqrtf(dx * dx + dy * dy + dz * dz);
    float W = (d < 8.0f) ? expf(d * -0.25f) : 0.f;
    if (WbRow != nullptr) WbRow[(size_t)(v0 + vl) * NG + g0 + lane] = f2bf(W);
    tile[vl][lane] = W;
    csum += W;
  }
  colp[t] = csum;
  __syncthreads();
  int r4 = t >> 2, q = t & 3;
  float rs = 0.f;
  #pragma unroll
  for (int j = 0; j < 16; j++) rs += tile[r4][q * 16 + j];
  rs += __shfl_xor(rs, 1);
  rs += __shfl_xor(rs, 2);
  if (q == 0) atomicAdd(&deg_v[v0 + r4], rs);
  if (w == 0) {
    float tot = colp[lane] + colp[64 + lane] + colp[128 + lane] + colp[192 + lane];
    atomicAdd(&deg_g[g0 + lane], tot);
  }
  if (WbP != nullptr) {
    size_t tb = ((size_t)(v0 >> 7) * 64 + (g0 >> 6)) * 8192;
    #pragma unroll
    for (int j = 0; j < 2; j++) {
      int idx = j * 256 + t;
      int vr = idx >> 3, k8 = (idx & 7) * 8;
      u16 pk[8];
      #pragma unroll
      for (int qq = 0; qq < 8; qq++) pk[qq] = f2bf(tile[vr][k8 + qq]);
      int r = (v0 & 64) + vr;
      *(uint4*)&WbP[tb + (size_t)r * 64 + (size_t)(((k8 >> 3) ^ (r & 7)) << 3)] = *(uint4*)pk;
    }
  }
  if (WbTP != nullptr) {
    size_t tb = ((size_t)(g0 >> 7) * 128 + (v0 >> 6)) * 8192;
    #pragma unroll
    for (int j = 0; j < 2; j++) {
      int idx = j * 256 + t;
      int gr = idx >> 3, v8 = (idx & 7) * 8;
      u16 pk[8];
      #pragma unroll
      for (int qq = 0; qq < 8; qq++) pk[qq] = f2bf(tile[v8 + qq][gr]);
      int r = (g0 & 64) + gr;
      *(uint4*)&WbTP[tb + (size_t)r * 64 + (size_t)(((v8 >> 3) ^ (r & 7)) << 3)] = *(uint4*)pk;
    }
  }
}

// all three recips in one launch
__global__ void k_recips(const float* __restrict__ deg_v, float* __restrict__ inv_v,
                         float* __restrict__ rs_v, const float* __restrict__ deg_g,
                         float* __restrict__ inv_g, float* __restrict__ rs_g,
                         const float* __restrict__ deg_e, float* __restrict__ inv_e,
                         float* __restrict__ rs_e) {
  int i = blockIdx.x * 256 + threadIdx.x;
  if (i < NV) { float d = deg_v[i]; inv_v[i] = 1.f / d; rs_v[i] = 1.f / sqrtf(d); }
  else if (i < NV + NG) {
    int j = i - NV; float d = deg_g[j]; inv_g[j] = 1.f / d; rs_g[j] = 1.f / sqrtf(d);
  } else if (i < NV + 2 * NG) {
    int j = i - NV - NG; float d = deg_e[j]; inv_e[j] = 1.f / d; rs_e[j] = 1.f / sqrtf(d);
  }
}

// ---------------- edge preprocessing (CSR) ----------------
__global__ void k_edge_prep(const int* __restrict__ eidx, const float* __restrict__ ew,
                            float* __restrict__ deg_e, int* __restrict__ cnt) {
  int e = blockIdx.x * 256 + threadIdx.x;
  if (e < NE) { int d = eidx[NE + e]; atomicAdd(&deg_e[d], ew[e]); atomicAdd(&cnt[d], 1); }
}

__global__ __launch_bounds__(1024) void k_scan(const int* __restrict__ cnt,
    int* __restrict__ row_ptr, int* __restrict__ cursor) {
  __shared__ int buf0[1024], buf1[1024];
  int t = threadIdx.x;
  int b = t * 4;
  int c0 = cnt[b], c1 = cnt[b + 1], c2 = cnt[b + 2], c3 = cnt[b + 3];
  int s = c0 + c1 + c2 + c3;
  buf0[t] = s;
  __syncthreads();
  int* src = buf0; int* dst = buf1;
  for (int off = 1; off < 1024; off <<= 1) {
    int v = src[t];
    if (t >= off) v += src[t - off];
    dst[t] = v;
    __syncthreads();
    int* tmp = src; src = dst; dst = tmp;
  }
  int excl = (t == 0) ? 0 : src[t - 1];
  int r0 = excl, r1 = excl + c0, r2 = excl + c0 + c1, r3 = excl + c0 + c1 + c2;
  row_ptr[b] = r0; row_ptr[b + 1] = r1; row_ptr[b + 2] = r2; row_ptr[b + 3] = r3;
  cursor[b] = r0; cursor[b + 1] = r1; cursor[b + 2] = r2; cursor[b + 3] = r3;
  if (t == 1023) row_ptr[4096] = src[1023];
}

__global__ void k_scatter(const int* __restrict__ eidx, const float* __restrict__ ew,
                          const float* __restrict__ dinv, int* __restrict__ cursor,
                          int* __restrict__ csrc, float* __restrict__ cnorm) {
  int e = blockIdx.x * 256 + threadIdx.x;
  if (e < NE) {
    int s = eidx[e], d = eidx[NE + e];
    int slot = atomicAdd(&cursor[d], 1);
    csrc[slot] = s;
    cnorm[slot] = dinv[s] * ew[e] * dinv[d];
  }
}

// ---------------- evecs -> bf16 transposed [128][NV] ----------------
__global__ __launch_bounds__(256) void k_evecsT(const float* __restrict__ ev, u16* __restrict__ evT) {
  __shared__ float tile[32][33];
  int t = threadIdx.x;
  int v0 = blockIdx.x * 32, k0 = blockIdx.y * 32;
  int r = t >> 3, c4 = (t & 7) * 4;
  float4 x = *(const float4*)(ev + (size_t)(v0 + r) * 128 + k0 + c4);
  tile[r][c4] = x.x; tile[r][c4 + 1] = x.y; tile[r][c4 + 2] = x.z; tile[r][c4 + 3] = x.w;
  __syncthreads();
  u16* dst = evT + (size_t)(k0 + r) * NV + v0 + c4;
  dst[0] = f2bf(tile[c4][r]); dst[1] = f2bf(tile[c4 + 1][r]);
  dst[2] = f2bf(tile[c4 + 2][r]); dst[3] = f2bf(tile[c4 + 3][r]);
}

// ---------------- mdxT[c][v] = bf16(mass[v] * dx[v][c]) ----------------
__global__ __launch_bounds__(256) void k_mdxT(const float* __restrict__ dx,
    const float* __restrict__ mass, u16* __restrict__ mdxT) {
  __shared__ float tile[64][65];
  __shared__ float lm[64];
  int t = threadIdx.x;
  int v0 = blockIdx.x * 64;
  if (t < 64) lm[t] = mass[v0 + t];
  #pragma unroll
  for (int i = 0; i < 16; i++) {
    int idx = i * 256 + t;
    int r = idx >> 6, c = idx & 63;
    tile[r][c] = dx[(size_t)(v0 + r) * 64 + c];
  }
  __syncthreads();
  int c = t >> 2;
  #pragma unroll
  for (int i = 0; i < 2; i++) {
    int vq = (t & 3) * 16 + i * 8;
    u16 pk[8];
    #pragma unroll
    for (int q = 0; q < 8; q++) pk[q] = f2bf(lm[vq + q] * tile[vq + q][c]);
    *(uint4*)&mdxT[(size_t)c * NV + v0 + vq] = *(uint4*)pk;
  }
}

// =============== setup GEMM: BM=256/BN=128/BK=32, double-buffered ===========
__global__ __launch_bounds__(256) void gemm_setup3(
    const float* __restrict__ gXm, const float* __restrict__ gYm,
    const u16* __restrict__ evT, float* __restrict__ parts,
    int z, int kchunk) {
  extern __shared__ __align__(16) char smem[];   // 2 x (A 32KB + B 8KB)
  const int t = threadIdx.x;
  const int lane = t & 63, wave = t >> 6;
  const int rl = lane & 15, hi = lane >> 4;
  int b = blockIdx.x;
  const int zi = b % z; b /= z;
  const int mb = b & 31;
  const int mat = b >> 5;
  const float* A = mat ? gYm : gXm;
  const int m0 = mb * 256;
  const int kbeg = zi * kchunk;
  const int nt = kchunk >> 5;
  const int wm = wave * 64;

  f32x4 acc[4][8];
  #pragma unroll
  for (int a = 0; a < 4; a++)
    #pragma unroll
    for (int bb = 0; bb < 8; bb++) acc[a][bb] = f32x4{0.f, 0.f, 0.f, 0.f};

  auto STAGE = [&](int buf, int k0) {   // exactly 10 gl_lds16 per wave
    char* aB = smem + buf * 40960;
    #pragma unroll
    for (int jj = 0; jj < 8; jj++) {
      int R0 = wave * 64 + jj * 8;
      int r = R0 + (lane >> 3);
      int s = lane & 7;
      gl_lds16(A + (size_t)(m0 + r) * NV + k0 + ((s ^ (r & 7)) << 2), aB + R0 * 128);
    }
    char* bB = smem + buf * 40960 + 32768;
    #pragma unroll
    for (int jj = 0; jj < 2; jj++) {
      int R0 = wave * 32 + jj * 16;
      int n = R0 + (lane >> 2);
      int s = lane & 3;
      gl_lds16(evT + (size_t)n * NV + k0 + ((s ^ ((n >> 1) & 3)) << 3), bB + R0 * 64);
    }
  };

  auto COMPUTE = [&](int buf) {
    const float* Af = (const float*)(smem + buf * 40960);
    const u16* Bf = (const u16*)(smem + buf * 40960 + 32768);
    sh8 av[4], bv[8];
    #pragma unroll
    for (int mf = 0; mf < 4; mf++) {
      int r = wm + mf * 16 + rl;
      f32x4 lo = *(const f32x4*)(Af + r * 32 + (((2 * hi) ^ (r & 7)) << 2));
      f32x4 h4 = *(const f32x4*)(Af + r * 32 + (((2 * hi + 1) ^ (r & 7)) << 2));
      sh8 v;
      v[0] = (short)f2bf(lo[0]); v[1] = (short)f2bf(lo[1]);
      v[2] = (short)f2bf(lo[2]); v[3] = (short)f2bf(lo[3]);
      v[4] = (short)f2bf(h4[0]); v[5] = (short)f2bf(h4[1]);
      v[6] = (short)f2bf(h4[2]); v[7] = (short)f2bf(h4[3]);
      av[mf] = v;
    }
    #pragma unroll
    for (int nf = 0; nf < 8; nf++) {
      int n = nf * 16 + rl;
      bv[nf] = *(const sh8*)(Bf + n * 32 + ((hi ^ ((n >> 1) & 3)) << 3));
    }
    #pragma unroll
    for (int mf = 0; mf < 4; mf++)
      #pragma unroll
      for (int nf = 0; nf < 8; nf++)
        acc[mf][nf] = __builtin_amdgcn_mfma_f32_16x16x32_bf16(av[mf], bv[nf], acc[mf][nf], 0, 0, 0);
  };

  STAGE(0, kbeg);
  if (nt > 1) STAGE(1, kbeg + 32);
  for (int ti = 0; ti < nt; ti++) {
    if (ti + 1 < nt) { asm volatile("s_waitcnt vmcnt(10)" ::: "memory"); }
    else             { asm volatile("s_waitcnt vmcnt(0)" ::: "memory"); }
    __builtin_amdgcn_sched_barrier(0);
    __builtin_amdgcn_s_barrier();
    COMPUTE(ti & 1);
    __builtin_amdgcn_sched_barrier(0);
    __builtin_amdgcn_s_barrier();
    if (ti + 2 < nt) STAGE(ti & 1, kbeg + (ti + 2) * 32);
  }

  float* C = parts + (size_t)(mat * z + zi) * (NV * 128);
  #pragma unroll
  for (int mf = 0; mf < 4; mf++)
    #pragma unroll
    for (int nf = 0; nf < 8; nf++) {
      int row = m0 + wm + mf * 16 + hi * 4;
      int col = nf * 16 + rl;
      #pragma unroll
      for (int q = 0; q < 4; q++)
        C[(size_t)(row + q) * 128 + col] = acc[mf][nf][q];
    }
}

// =============== merged panel GEMM: blocks [0,512) Wbp, [512,1024) WbTp ====
__global__ __launch_bounds__(256) void gemm_panel2(
    const u16* __restrict__ WbP, const u16* __restrict__ WbTP,
    const u16* __restrict__ xwgT, const u16* __restrict__ xw2vT,
    float* __restrict__ parts) {
  __shared__ __align__(16) char smem[49152];   // 2 x (A 16KB + B 8KB)
  const int t = threadIdx.x;
  const int lane = t & 63, wave = t >> 6;
  const int rl = lane & 15, hi = lane >> 4;
  int bid = blockIdx.x;
  const u16* Apan; const u16* BT; int KT, ldbt, mb, z;
  float* Cbase;
  if (bid < 512) {
    Apan = WbP; BT = xwgT; KT = 64; ldbt = NG;
    mb = bid >> 3; z = bid & 7;
    Cbase = parts + (size_t)z * NV * 64;
  } else {
    bid -= 512;
    Apan = WbTP; BT = xw2vT; KT = 128; ldbt = NV;
    mb = bid >> 4; z = bid & 15;
    Cbase = parts + (size_t)8 * NV * 64 + (size_t)z * NG * 64;
  }
  const int ktpz = 8;
  const int kt0 = z * ktpz;
  const int wm = wave * 32;

  f32x4 acc[2][4];
  #pragma unroll
  for (int a = 0; a < 2; a++)
    #pragma unroll
    for (int b = 0; b < 4; b++) acc[a][b] = f32x4{0.f, 0.f, 0.f, 0.f};

  auto STAGE = [&](int buf, int kt) {   // exactly 6 gl_lds16 per wave
    char* aB = smem + buf * 24576;
    const u16* tbase = Apan + ((size_t)mb * KT + kt) * 8192;
    #pragma unroll
    for (int jj = 0; jj < 4; jj++) {
      int j = wave * 4 + jj;
      gl_lds16(tbase + j * 512 + lane * 8, aB + j * 1024);
    }
    char* bB = aB + 16384;
    #pragma unroll
    for (int jj = 0; jj < 2; jj++) {
      int j = wave * 2 + jj;
      int n = 8 * j + (lane >> 3);
      const u16* srcb = BT + (size_t)n * ldbt + kt * 64 + (((lane & 7) ^ (n & 7)) << 3);
      gl_lds16(srcb, bB + j * 1024);
    }
  };

  auto COMPUTE = [&](int buf) {
    const u16* Af = (const u16*)(smem + buf * 24576);
    const u16* Bf = Af + 8192;
    #pragma unroll
    for (int step = 0; step < 2; step++) {
      sh8 av[2], bv[4];
      int s = step * 4 + hi;
      #pragma unroll
      for (int mf = 0; mf < 2; mf++) {
        int r = wm + mf * 16 + rl;
        av[mf] = *(const sh8*)(Af + r * 64 + ((s ^ (r & 7)) << 3));
      }
      #pragma unroll
      for (int nf = 0; nf < 4; nf++) {
        int n = nf * 16 + rl;
        bv[nf] = *(const sh8*)(Bf + n * 64 + ((s ^ (n & 7)) << 3));
      }
      #pragma unroll
      for (int mf = 0; mf < 2; mf++)
        #pragma unroll
        for (int nf = 0; nf < 4; nf++)
          acc[mf][nf] = __builtin_amdgcn_mfma_f32_16x16x32_bf16(av[mf], bv[nf], acc[mf][nf], 0, 0, 0);
    }
  };

  STAGE(0, kt0);
  STAGE(1, kt0 + 1);
  for (int ti = 0; ti < ktpz; ti++) {
    if (ti + 1 < ktpz) { asm volatile("s_waitcnt vmcnt(6)" ::: "memory"); }
    else               { asm volatile("s_waitcnt vmcnt(0)" ::: "memory"); }
    __builtin_amdgcn_sched_barrier(0);
    __builtin_amdgcn_s_barrier();
    COMPUTE(ti & 1);
    __builtin_amdgcn_sched_barrier(0);
    __builtin_amdgcn_s_barrier();
    if (ti + 2 < ktpz) STAGE(ti & 1, kt0 + ti + 2);
  }

  #pragma unroll
  for (int mf = 0; mf < 2; mf++)
    #pragma unroll
    for (int nf = 0; nf < 4; nf++) {
      int row = mb * 128 + wm + mf * 16 + hi * 4;
      int col = nf * 16 + rl;
      #pragma unroll
      for (int q = 0; q < 4; q++)
        Cbase[(size_t)(row + q) * 64 + col] = acc[mf][nf][q];
    }
}

// reduce both panel results: Wbp (8 slices) then WbTp (16 slices)
__global__ void k_reduce_both(const float* __restrict__ parts,
    float* __restrict__ Wbp, float* __restrict__ WbTp) {
  int i = (blockIdx.x * 256 + threadIdx.x) * 4;
  if (i < NV * 64) {
    float4 s = *(const float4*)(parts + i);
    for (int z = 1; z < 8; z++) {
      float4 v = *(const float4*)(parts + (size_t)z * NV * 64 + i);
      s.x += v.x; s.y += v.y; s.z += v.z; s.w += v.w;
    }
    *(float4*)(Wbp + i) = s;
  } else {
    int j = i - NV * 64;
    if (j < NG * 64) {
      const float* src = parts + (size_t)8 * NV * 64;
      float4 s = *(const float4*)(src + j);
      for (int z = 1; z < 16; z++) {
        float4 v = *(const float4*)(src + (size_t)z * NG * 64 + j);
        s.x += v.x; s.y += v.y; s.z += v.z; s.w += v.w;
      }
      *(float4*)(WbTp + j) = s;
    }
  }
}

// =============== generic bf16 GEMM (spec + row-tier Wb), BM=128, BN=64 ======
__global__ __launch_bounds__(256) void gemm_bf16(
    const u16* __restrict__ Ab, int lda, const u16* __restrict__ BT, int ldbt,
    float* __restrict__ parts, int M, int kchunk) {
  __shared__ __align__(16) char smem[49152];
  const int t = threadIdx.x;
  const int lane = t & 63, wave = t >> 6;
  const int m0 = blockIdx.x * 128;
  const int kbeg = blockIdx.z * kchunk;
  const int nt = kchunk >> 6;
  const int wm = (wave >> 1) * 64, wn = (wave & 1) * 32;
  const int arl = lane >> 3, asl = lane & 7;

  f32x4 acc[4][2];
  #pragma unroll
  for (int a = 0; a < 4; a++)
    #pragma unroll
    for (int b = 0; b < 2; b++) acc[a][b] = f32x4{0.f, 0.f, 0.f, 0.f};

  auto STAGE = [&](int buf, int k0) {
    char* base = smem + buf * 24576;
    #pragma unroll
    for (int j = 0; j < 4; j++) {
      int R0 = (wave * 4 + j) * 8;
      int r = R0 + arl;
      int gs = asl ^ (r & 7);
      gl_lds16(Ab + (size_t)(m0 + r) * lda + k0 + gs * 8, base + R0 * 128);
    }
    char* bb = base + 16384;
    #pragma unroll
    for (int j = 0; j < 2; j++) {
      int R0 = (wave * 2 + j) * 8;
      int r = R0 + arl;
      int gs = asl ^ (r & 7);
      gl_lds16(BT + (size_t)r * ldbt + k0 + gs * 8, bb + R0 * 128);
    }
  };

  auto COMPUTE = [&](int buf) {
    char* base = smem + buf * 24576;
    const u16* Af = (const u16*)base;
    const u16* Bf = (const u16*)(base + 16384);
    #pragma unroll
    for (int kk = 0; kk < 2; kk++) {
      sh8 av[4], bv[2];
      #pragma unroll
      for (int mf = 0; mf < 4; mf++) {
        int r = wm + mf * 16 + (lane & 15);
        int g = kk * 4 + (lane >> 4);
        av[mf] = *(const sh8*)(Af + r * 64 + (g ^ (r & 7)) * 8);
      }
      #pragma unroll
      for (int nf = 0; nf < 2; nf++) {
        int r = wn + nf * 16 + (lane & 15);
        int g = kk * 4 + (lane >> 4);
        bv[nf] = *(const sh8*)(Bf + r * 64 + (g ^ (r & 7)) * 8);
      }
      #pragma unroll
      for (int mf = 0; mf < 4; mf++)
        #pragma unroll
        for (int nf = 0; nf < 2; nf++)
          acc[mf][nf] = __builtin_amdgcn_mfma_f32_16x16x32_bf16(av[mf], bv[nf], acc[mf][nf], 0, 0, 0);
    }
  };

  STAGE(0, kbeg);
  if (nt > 1) STAGE(1, kbeg + 64);
  for (int ti = 0; ti < nt; ti++) {
    if (ti + 1 < nt) { asm volatile("s_waitcnt vmcnt(6)" ::: "memory"); }
    else             { asm volatile("s_waitcnt vmcnt(0)" ::: "memory"); }
    __builtin_amdgcn_sched_barrier(0);
    __builtin_amdgcn_s_barrier();
    COMPUTE(ti & 1);
    __builtin_amdgcn_sched_barrier(0);
    __builtin_amdgcn_s_barrier();
    if (ti + 2 < nt) STAGE(ti & 1, kbeg + (ti + 2) * 64);
  }

  float* C = parts + (size_t)blockIdx.z * M * 64;
  #pragma unroll
  for (int mf = 0; mf < 4; mf++)
    #pragma unroll
    for (int nf = 0; nf < 2; nf++) {
      int row = m0 + wm + mf * 16 + (lane >> 4) * 4;
      int col = wn + nf * 16 + (lane & 15);
      #pragma unroll
      for (int q = 0; q < 4; q++)
        C[(size_t)(row + q) * 64 + col] = acc[mf][nf][q];
    }
}

// ---------------- ATRANS fallback GEMM (low-ws WbT path) ----------------
template<int BN, bool AF32, bool ATRANS>
__global__ __launch_bounds__(256) void gemm_k(
    const void* __restrict__ Aptr, const void* __restrict__ A2, int zsplit2,
    const u16* __restrict__ BT, float* __restrict__ Cpart,
    int M, int N, int lda, int ldbt, int kchunk) {
  constexpr int NF = BN / 32;
  __shared__ u16 lA[128 * 40];
  __shared__ u16 lB[BN * 40];
  const int t = threadIdx.x;
  const int m0 = blockIdx.x * 128, n0 = blockIdx.y * BN;
  const void* Ause = Aptr;
  int kz = blockIdx.z;
  if (A2 != nullptr && kz >= zsplit2) { Ause = A2; kz -= zsplit2; }
  const int kbeg = kz * kchunk;
  const int lane = t & 63, wave = t >> 6;
  const int wm = (wave >> 1) * 64, wn = (wave & 1) * (BN / 2);
  f32x4 zero = {0.f, 0.f, 0.f, 0.f};
  f32x4 acc[4][NF];
  #pragma unroll
  for (int a = 0; a < 4; a++)
    #pragma unroll
    for (int b = 0; b < NF; b++) acc[a][b] = zero;

  for (int k0 = kbeg; k0 < kbeg + kchunk; k0 += 32) {
    if constexpr (!ATRANS) {
      const int r = t >> 1, cc = (t & 1) * 16;
      const u16* A = (const u16*)Ause + (size_t)(m0 + r) * lda + k0 + cc;
      *(uint4*)&lA[r * 40 + cc] = *(const uint4*)A;
      *(uint4*)&lA[r * 40 + cc + 8] = *(const uint4*)(A + 8);
    } else {
      const int kl = t >> 3, mb = (t & 7) * 16;
      const u16* A = (const u16*)Ause + (size_t)(k0 + kl) * lda + m0 + mb;
      u16 vals[16];
      *(uint4*)&vals[0] = *(const uint4*)A;
      *(uint4*)&vals[8] = *(const uint4*)(A + 8);
      #pragma unroll
      for (int j = 0; j < 16; j++) lA[(mb + j) * 40 + kl] = vals[j];
    }
    if constexpr (BN == 64) {
      const int r = t >> 2, cc = (t & 3) * 8;
      const u16* B = BT + (size_t)(n0 + r) * ldbt + k0 + cc;
      *(uint4*)&lB[r * 40 + cc] = *(const uint4*)B;
    } else {
      const int r = t >> 1, cc = (t & 1) * 16;
      const u16* B = BT + (size_t)(n0 + r) * ldbt + k0 + cc;
      *(uint4*)&lB[r * 40 + cc] = *(const uint4*)B;
      *(uint4*)&lB[r * 40 + cc + 8] = *(const uint4*)(B + 8);
    }
    __syncthreads();
    sh8 af[4], bfv[NF];
    #pragma unroll
    for (int mf = 0; mf < 4; mf++)
      af[mf] = *(const sh8*)&lA[(wm + mf * 16 + (lane & 15)) * 40 + (lane >> 4) * 8];
    #pragma unroll
    for (int nf = 0; nf < NF; nf++)
      bfv[nf] = *(const sh8*)&lB[(wn + nf * 16 + (lane & 15)) * 40 + (lane >> 4) * 8];
    #pragma unroll
    for (int mf = 0; mf < 4; mf++)
      #pragma unroll
      for (int nf = 0; nf < NF; nf++)
        acc[mf][nf] = __builtin_amdgcn_mfma_f32_16x16x32_bf16(af[mf], bfv[nf], acc[mf][nf], 0, 0, 0);
    __syncthreads();
  }
  float* C = Cpart + (size_t)blockIdx.z * M * N;
  #pragma unroll
  for (int mf = 0; mf < 4; mf++)
    #pragma unroll
    for (int nf = 0; nf < NF; nf++) {
      const int row = m0 + wm + mf * 16 + (lane >> 4) * 4;
      const int col = n0 + wn + nf * 16 + (lane & 15);
      #pragma unroll
      for (int q = 0; q < 4; q++)
        C[(size_t)(row + q) * N + col] = acc[mf][nf][q];
    }
}

__global__ void k_reduce(const float* __restrict__ parts, float* __restrict__ dst, int len, int nz) {
  int i = (blockIdx.x * 256 + threadIdx.x) * 4;
  if (i >= len) return;
  float4 s = *(const float4*)(parts + i);
  for (int z = 1; z < nz; z++) {
    float4 v = *(const float4*)(parts + (size_t)z * len + i);
    s.x += v.x; s.y += v.y; s.z += v.z; s.w += v.w;
  }
  *(float4*)(dst + i) = s;
}

// reduce 64 spec slices + apply exp(-evals*t): Es[k][c]
__global__ void k_reduce_es(const float* __restrict__ parts,
    const float* __restrict__ evals, const float* __restrict__ dt,
    float* __restrict__ Es) {
  int i = blockIdx.x * 256 + threadIdx.x;   // 8192 elems
  float s = 0.f;
  #pragma unroll 8
  for (int z = 0; z < 64; z++) s += parts[(size_t)z * 8192 + i];
  int k = i >> 6, c = i & 63;
  Es[i] = expf(-evals[k] * fmaxf(dt[c], 1e-8f)) * s;
}

// two matrices packed: dst[mat*len + j] = sum_z parts[(mat*nz+z)*len + j]
__global__ void k_reduce2(const float* __restrict__ parts, float* __restrict__ dst, int len, int nz) {
  int i = (blockIdx.x * 256 + threadIdx.x) * 4;
  if (i >= 2 * len) return;
  int mat = i / len, j = i - mat * len;
  const float* src = parts + (size_t)mat * nz * len + j;
  float4 s = *(const float4*)src;
  for (int z = 1; z < nz; z++) {
    float4 v = *(const float4*)(src + (size_t)z * len);
    s.x += v.x; s.y += v.y; s.z += v.z; s.w += v.w;
  }
  *(float4*)(dst + i) = s;
}

// ---------------- fused lin1/lin2 (C_IN=128 -> DW=64) ----------------
__global__ __launch_bounds__(256) void k_lin_both(const float* __restrict__ x_in,
    const float* __restrict__ graph_x, const float* __restrict__ W1,
    const float* __restrict__ b1, const float* __restrict__ W2,
    const float* __restrict__ b2, float* __restrict__ outV, float* __restrict__ outG) {
  __shared__ float lW[8192];
  __shared__ float lb[64];
  int bb = blockIdx.x;
  bool isV = bb < 2048;
  const float* W = isV ? W1 : W2;
  const float* bi = isV ? b1 : b2;
  const float* A = isV ? x_in : graph_x;
  float* out = isV ? outV : outG;
  int rb = isV ? bb : bb - 2048;
  int t = threadIdx.x;
  for (int i = t; i < 8192; i += 256) lW[i] = W[i];
  if (t < 64) lb[t] = bi[t];
  __syncthreads();
  int row = rb * 4 + (t >> 6), c = t & 63;
  const float* Ar = A + (size_t)row * 128;
  float acc = lb[c];
  #pragma unroll 8
  for (int k = 0; k < 128; k++) acc += Ar[k] * lW[k * 64 + c];
  out[(size_t)row * 64 + c] = acc;
}

// ---------------- fused xd + gradient features ----------------
__global__ __launch_bounds__(256) void k_xdgf(const float* __restrict__ evecs,
    const float* __restrict__ GXE, const float* __restrict__ GYE,
    const float* __restrict__ Es, const float* __restrict__ Are,
    const float* __restrict__ Aim, float* __restrict__ xd, float* __restrict__ gf) {
  __shared__ float lE[8192];
  __shared__ float lr[4096], li[4096];
  __shared__ float lgx[256], lgy[256];
  int t = threadIdx.x;
  for (int i = t; i < 8192; i += 256) lE[i] = Es[i];
  for (int i = t; i < 4096; i += 256) { lr[i] = Are[i]; li[i] = Aim[i]; }
  __syncthreads();
  int wr = t >> 6, c = t & 63;
  int row = blockIdx.x * 4 + wr;
  const float* er = evecs + (size_t)row * 128;
  const float* xr = GXE + (size_t)row * 128;
  const float* yr = GYE + (size_t)row * 128;
  float a0 = 0, a1 = 0, a2 = 0;
  #pragma unroll 8
  for (int k = 0; k < 128; k++) {
    float s = lE[k * 64 + c];
    a0 += er[k] * s; a1 += xr[k] * s; a2 += yr[k] * s;
  }
  lgx[wr * 64 + c] = a1;
  lgy[wr * 64 + c] = a2;
  __syncthreads();
  float br = 0.f, bi = 0.f;
  #pragma unroll 8
  for (int k = 0; k < 64; k++) {
    float gx = lgx[wr * 64 + k], gy = lgy[wr * 64 + k];
    float ar = lr[k * 64 + c], ai = li[k * 64 + c];
    br += gx * ar - gy * ai;
    bi += gy * ar + gx * ai;
  }
  xd[(size_t)row * 64 + c] = a0;
  gf[(size_t)row * 64 + c] = tanhf(a1 * br + a2 * bi);
}

__global__ __launch_bounds__(256) void k_mlp0(const float* __restrict__ dx,
    const float* __restrict__ xd, const float* __restrict__ gf,
    const float* __restrict__ W0, const float* __restrict__ b0, float* __restrict__ h1) {
  __shared__ float lW[12288];
  __shared__ float lb[64];
  int t = threadIdx.x;
  for (int i = t; i < 12288; i += 256) lW[i] = W0[i];
  if (t < 64) lb[t] = b0[t];
  __syncthreads();
  int row = blockIdx.x * 4 + (t >> 6), c = t & 63;
  const float* a0 = dx + (size_t)row * 64;
  const float* a1 = xd + (size_t)row * 64;
  const float* a2 = gf + (size_t)row * 64;
  float acc = lb[c];
  #pragma unroll 8
  for (int k = 0; k < 64; k++) acc += a0[k] * lW[k * 64 + c];
  #pragma unroll 8
  for (int k = 0; k < 64; k++) acc += a1[k] * lW[(64 + k) * 64 + c];
  #pragma unroll 8
  for (int k = 0; k < 64; k++) acc += a2[k] * lW[(128 + k) * 64 + c];
  h1[(size_t)row * 64 + c] = fmaxf(acc, 0.f);
}

// fused mlp1+mlp2+residual+dual projection (post-MLP diffx never stored)
__global__ __launch_bounds__(256) void k_mlp12_dual(const float* __restrict__ h1,
    const float* __restrict__ W1, const float* __restrict__ b1,
    const float* __restrict__ W2, const float* __restrict__ b2,
    const float* __restrict__ dx, const float* __restrict__ gsw,
    const float* __restrict__ sgw, float* __restrict__ xw_v,
    float* __restrict__ xw2_v, u16* __restrict__ xw2vT) {
  __shared__ float l1[4096], l2[4096], lg[4096], ls[4096];
  __shared__ float lb1[64], lb2[64], lrow[256], lrow2[256];
  int t = threadIdx.x;
  for (int i = t; i < 4096; i += 256) {
    l1[i] = W1[i]; l2[i] = W2[i]; lg[i] = gsw[i]; ls[i] = sgw[i];
  }
  if (t < 64) lb1[t] = b1[t];
  else if (t < 128) lb2[t - 64] = b2[t - 64];
  __syncthreads();
  int wr = t >> 6, c = t & 63;
  int row = blockIdx.x * 4 + wr;
  const float* hr = h1 + (size_t)row * 64;
  float h2 = lb1[c];
  #pragma unroll 8
  for (int k = 0; k < 64; k++) h2 += hr[k] * l1[k * 64 + c];
  h2 = fmaxf(h2, 0.f);
  lrow[wr * 64 + c] = h2;
  __syncthreads();
  float o = lb2[c] + dx[(size_t)row * 64 + c];
  #pragma unroll 8
  for (int k = 0; k < 64; k++) o += lrow[wr * 64 + k] * l2[k * 64 + c];
  lrow2[wr * 64 + c] = o;
  __syncthreads();
  float p = 0.f, q = 0.f;
  #pragma unroll 8
  for (int k = 0; k < 64; k++) {
    float a = lrow2[wr * 64 + k];
    p += a * lg[k * 64 + c];
    q += a * ls[k * 64 + c];
  }
  xw_v[(size_t)row * 64 + c] = p;
  xw2_v[(size_t)row * 64 + c] = q;
  xw2vT[(size_t)c * NV + row] = f2bf(q);
}

// ---------------- small fp32 matmul (64x64 weights) ----------------
template<bool BIAS, bool RELU, bool RES>
__global__ __launch_bounds__(256) void k_mm64(const float* __restrict__ A,
    const float* __restrict__ W, const float* __restrict__ b,
    const float* __restrict__ res, float* __restrict__ out) {
  __shared__ float lW[4096];
  __shared__ float lb[64];
  int t = threadIdx.x;
  for (int i = t; i < 4096; i += 256) lW[i] = W[i];
  if constexpr (BIAS) { if (t < 64) lb[t] = b[t]; }
  __syncthreads();
  int row = blockIdx.x * 4 + (t >> 6), c = t & 63;
  const float* Ar = A + (size_t)row * 64;
  float acc = 0.f;
  #pragma unroll 8
  for (int k = 0; k < 64; k++) acc += Ar[k] * lW[k * 64 + c];
  if constexpr (BIAS) acc += lb[c];
  if constexpr (RES) acc += res[(size_t)row * 64 + c];
  if constexpr (RELU) acc = fmaxf(acc, 0.f);
  out[(size_t)row * 64 + c] = acc;
}

// ---------------- GCN agg + next matmul fused ----------------
__global__ __launch_bounds__(64) void k_aggmm(const float* __restrict__ xw,
    const int* __restrict__ rp, const int* __restrict__ csrc,
    const float* __restrict__ cnorm, const float* __restrict__ invdeg,
    const float* __restrict__ b1, const float* __restrict__ W2, float* __restrict__ out) {
  __shared__ float lrow[64];
  int g = blockIdx.x, c = threadIdx.x;
  float acc = xw[(size_t)g * 64 + c] * invdeg[g] + b1[c];
  int j1 = rp[g + 1];
  for (int j = rp[g]; j < j1; j++) acc += cnorm[j] * xw[(size_t)csrc[j] * 64 + c];
  acc = fmaxf(acc, 0.f);
  lrow[c] = acc;
  __syncthreads();
  float o = 0.f;
  #pragma unroll 8
  for (int k = 0; k < 64; k++) o += lrow[k] * W2[k * 64 + c];
  out[(size_t)g * 64 + c] = o;
}

__global__ __launch_bounds__(64) void k_aggdual(const float* __restrict__ xw,
    const int* __restrict__ rp, const int* __restrict__ csrc,
    const float* __restrict__ cnorm, const float* __restrict__ invdeg,
    const float* __restrict__ b2, const float* __restrict__ gsw,
    const float* __restrict__ sgw, float* __restrict__ xw_g,
    float* __restrict__ xw2_g, u16* __restrict__ xwgT) {
  __shared__ float lrow[64];
  int g = blockIdx.x, c = threadIdx.x;
  float acc = xw[(size_t)g * 64 + c] * invdeg[g] + b2[c];
  int j1 = rp[g + 1];
  for (int j = rp[g]; j < j1; j++) acc += cnorm[j] * xw[(size_t)csrc[j] * 64 + c];
  lrow[c] = acc;
  __syncthreads();
  float p = 0.f, q = 0.f;
  #pragma unroll 8
  for (int k = 0; k < 64; k++) {
    float r = lrow[k];
    p += r * gsw[k * 64 + c];
    q += r * sgw[k * 64 + c];
  }
  xw_g[(size_t)g * 64 + c] = p;
  xw2_g[(size_t)g * 64 + c] = q;
  xwgT[(size_t)c * NG + g] = f2bf(p);
}

// ---------------- fused bipartite combine ----------------
__global__ void k_combine(const float* __restrict__ xw_v, const float* __restrict__ Wbp,
    const float* __restrict__ xw2_v, const float* __restrict__ xw_g,
    const float* __restrict__ WbTp, const float* __restrict__ xw2_g,
    const float* __restrict__ inv_deg_v, const float* __restrict__ rsv,
    const float* __restrict__ inv_deg_g, const float* __restrict__ rsg,
    const float* __restrict__ gsb, const float* __restrict__ sgb,
    float* __restrict__ dx, float* __restrict__ gx) {
  int idx = blockIdx.x * 256 + threadIdx.x;
  if (idx < NV * 64) {
    int v = idx >> 6, c = idx & 63;
    dx[idx] = 0.5f * (xw_v[idx] * inv_deg_v[v] + Wbp[idx] * rsv[v] + gsb[c] + xw2_v[idx] + sgb[c]);
  } else {
    int j = idx - NV * 64;
    int g = j >> 6, c = j & 63;
    gx[j] = 0.5f * (xw_g[j] + gsb[c] + xw2_g[j] * inv_deg_g[g] + WbTp[j] * rsg[g] + sgb[c]);
  }
}

// =================================================================
extern "C" void kernel_launch(void* const* d_in, const int* in_sizes, int n_in,
                              void* d_out, int out_size, void* d_ws, size_t ws_size,
                              hipStream_t stream) {
  const float* vertices  = (const float*)d_in[0];
  const float* graph_pos = (const float*)d_in[1];
  const float* x_in      = (const float*)d_in[2];
  const float* graph_x   = (const float*)d_in[3];
  const float* mass      = (const float*)d_in[4];
  const float* evals     = (const float*)d_in[5];
  const float* evecs     = (const float*)d_in[6];
  const float* gradX     = (const float*)d_in[7];
  const float* gradY     = (const float*)d_in[8];
  const int*   eidx      = (const int*)d_in[9];
  const float* ew        = (const float*)d_in[10];
  const float* lin1_w    = (const float*)d_in[11];
  const float* lin1_b    = (const float*)d_in[12];
  const float* lin2_w    = (const float*)d_in[13];
  const float* lin2_b    = (const float*)d_in[14];
  const float* diff_time = (const float*)d_in[15];
  const float* A_re      = (const float*)d_in[16];
  const float* A_im      = (const float*)d_in[17];
  const float* mlp_w0    = (const float*)d_in[18];
  const float* mlp_b0    = (const float*)d_in[19];
  const float* mlp_w1    = (const float*)d_in[20];
  const float* mlp_b1    = (const float*)d_in[21];
  const float* mlp_w2    = (const float*)d_in[22];
  const float* mlp_b2    = (const float*)d_in[23];
  const float* gcn1_w    = (const float*)d_in[24];
  const float* gcn1_b    = (const float*)d_in[25];
  const float* gcn2_w    = (const float*)d_in[26];
  const float* gcn2_b    = (const float*)d_in[27];
  const float* gs_w      = (const float*)d_in[28];
  const float* gs_b      = (const float*)d_in[29];
  const float* sg_w      = (const float*)d_in[30];
  const float* sg_b      = (const float*)d_in[31];

  char* base = (char*)d_ws;
  size_t off = 0;
  auto alloc = [&](size_t nbytes) -> void* {
    void* p = base + off;
    off += (nbytes + 255) & ~(size_t)255;
    return p;
  };
  const size_t MBy = 1024 * 1024;
  u16*   evecsT  = (u16*)alloc((size_t)128 * NV * 2);
  float* GXE2    = (float*)alloc((size_t)2 * NV * 128 * 4); // GXE | GYE contiguous
  float* GXE     = GXE2;
  float* GYE     = GXE2 + (size_t)NV * 128;
  u16*   mdxT    = (u16*)alloc((size_t)64 * NV * 2);
  float* Es      = (float*)alloc(8192 * 4);
  float* diffx   = (float*)alloc((size_t)NV * 64 * 4);
  float* gxb     = (float*)alloc((size_t)NG * 64 * 4);
  float* xd      = (float*)alloc((size_t)NV * 64 * 4);
  float* gf      = (float*)alloc((size_t)NV * 64 * 4);
  float* h1      = (float*)alloc((size_t)NV * 64 * 4);
  float* xw_v    = (float*)alloc((size_t)NV * 64 * 4);
  float* xw2_v   = (float*)alloc((size_t)NV * 64 * 4);
  float* xw_g    = (float*)alloc((size_t)NG * 64 * 4);
  float* xw2_g   = (float*)alloc((size_t)NG * 64 * 4);
  float* xw1     = (float*)alloc((size_t)NG * 64 * 4);
  float* xw2k    = (float*)alloc((size_t)NG * 64 * 4);
  u16*   xwgT    = (u16*)alloc((size_t)64 * NG * 2);
  u16*   xw2vT   = (u16*)alloc((size_t)64 * NV * 2);
  float* Wbp     = (float*)alloc((size_t)NV * 64 * 4);
  float* WbTp    = (float*)alloc((size_t)NG * 64 * 4);
  float* deg_v   = (float*)alloc(NV * 4);
  float* inv_deg_v = (float*)alloc(NV * 4);
  float* rsv     = (float*)alloc(NV * 4);
  float* deg_g   = (float*)alloc(NG * 4);
  float* inv_deg_g = (float*)alloc(NG * 4);
  float* rsg     = (float*)alloc(NG * 4);
  float* deg_e   = (float*)alloc(NG * 4);
  float* invdeg_e = (float*)alloc(NG * 4);
  float* dinv_e  = (float*)alloc(NG * 4);
  int*   cnt     = (int*)alloc(NG * 4);
  int*   row_ptr = (int*)alloc((NG + 1) * 4);
  int*   cursor  = (int*)alloc(NG * 4);
  int*   csr_src = (int*)alloc(NE * 4);
  float* csr_norm = (float*)alloc(NE * 4);

  size_t avail = ws_size > off ? ws_size - off : 0;
  u16 *WbP = nullptr, *WbTP = nullptr, *WbRow = nullptr;
  float* parts;
  int zsu;
  if (avail >= 162 * MBy) {
    WbP  = (u16*)alloc((size_t)NV * NG * 2);   // 64 MB panels
    WbTP = (u16*)alloc((size_t)NG * NV * 2);   // 64 MB panels
    parts = (float*)alloc(32 * MBy);
    zsu = 4;
  } else if (avail >= 97 * MBy) {
    WbRow = (u16*)alloc((size_t)NV * NG * 2);  // 64 MB row-major fallback
    parts = (float*)alloc(32 * MBy);
    zsu = 4;
  } else {
    WbRow = (u16*)alloc((size_t)NV * NG * 2);
    parts = (float*)alloc(16 * MBy);
    zsu = 2;
  }
  if (off > ws_size) return;  // insufficient workspace -> fail loudly

  dim3 B256(256);

  // ---------- setup ----------
  k_fill4<<<dim3(80), B256, 0, stream>>>(deg_v, deg_g, deg_e, cnt);
  k_wb_build<<<dim3(128, 64), B256, 0, stream>>>(vertices, graph_pos, WbRow, WbP, WbTP, deg_v, deg_g);
  k_edge_prep<<<dim3(256), B256, 0, stream>>>(eidx, ew, deg_e, cnt);
  k_recips<<<dim3(64), B256, 0, stream>>>(deg_v, inv_deg_v, rsv, deg_g, inv_deg_g, rsg,
                                          deg_e, invdeg_e, dinv_e);
  k_scan<<<dim3(1), dim3(1024), 0, stream>>>(cnt, row_ptr, cursor);
  k_scatter<<<dim3(256), B256, 0, stream>>>(eidx, ew, dinv_e, cursor, csr_src, csr_norm);
  k_evecsT<<<dim3(256, 4), B256, 0, stream>>>(evecs, evecsT);
  // GXE = gradX @ evecs, GYE = gradY @ evecs (round-8 proven config)
  gemm_setup3<<<dim3(2 * 32 * zsu), B256, 81920, stream>>>(
      gradX, gradY, evecsT, parts, zsu, 8192 / zsu);
  k_reduce2<<<dim3(2048), B256, 0, stream>>>(parts, GXE2, NV * 128, zsu);
  k_lin_both<<<dim3(3072), B256, 0, stream>>>(x_in, graph_x, lin1_w, lin1_b, lin2_w, lin2_b, diffx, gxb);

  // ---------- 4 blocks ----------
  for (int i = 0; i < 4; i++) {
    const float* dtrow = diff_time + i * 64;
    // spec = evecsT @ (mass*dx)^T via MFMA; fused reduce+exp
    k_mdxT<<<dim3(128), B256, 0, stream>>>(diffx, mass, mdxT);
    gemm_bf16<<<dim3(1, 1, 64), B256, 0, stream>>>(evecsT, NV, mdxT, NV, parts, 128, 128);
    k_reduce_es<<<dim3(32), B256, 0, stream>>>(parts, evals, dtrow, Es);
    // xd + gradient features, then mlp0 (separate: occupancy beats fusion here)
    k_xdgf<<<dim3(2048), B256, 0, stream>>>(evecs, GXE, GYE, Es, A_re + i * 4096, A_im + i * 4096, xd, gf);
    k_mlp0<<<dim3(2048), B256, 0, stream>>>(diffx, xd, gf, mlp_w0 + i * 12288, mlp_b0 + i * 64, h1);
    // fused mlp12 + vertex-side dual projection (no post-MLP diffx store)
    k_mlp12_dual<<<dim3(2048), B256, 0, stream>>>(h1, mlp_w1 + i * 4096, mlp_b1 + i * 64,
        mlp_w2 + i * 4096, mlp_b2 + i * 64, diffx, gs_w + i * 4096, sg_w + i * 4096,
        xw_v, xw2_v, xw2vT);
    // graph GCN (2 convs) + graph-side dual projection
    k_mm64<false, false, false><<<dim3(1024), B256, 0, stream>>>(gxb, gcn1_w + i * 4096, nullptr, nullptr, xw1);
    k_aggmm<<<dim3(NG), dim3(64), 0, stream>>>(xw1, row_ptr, csr_src, csr_norm, invdeg_e,
        gcn1_b + i * 64, gcn2_w + i * 4096, xw2k);
    k_aggdual<<<dim3(NG), dim3(64), 0, stream>>>(xw2k, row_ptr, csr_src, csr_norm, invdeg_e,
        gcn2_b + i * 64, gs_w + i * 4096, sg_w + i * 4096, xw_g, xw2_g, xwgT);
    if (WbP != nullptr) {
      // both Wb GEMMs in one launch (blocks 0-511: Wbp, 512-1023: WbTp)
      gemm_panel2<<<dim3(1024), B256, 0, stream>>>(WbP, WbTP, xwgT, xw2vT, parts);
      k_reduce_both<<<dim3(768), B256, 0, stream>>>(parts, Wbp, WbTp);
    } else {
      gemm_bf16<<<dim3(64, 1, 8), B256, 0, stream>>>(WbRow, NG, xwgT, NG, parts, NV, 512);
      k_reduce<<<dim3(512), B256, 0, stream>>>(parts, Wbp, NV * 64, 8);
      gemm_k<64, false, true><<<dim3(32, 1, 16), B256, 0, stream>>>(
          WbRow, nullptr, 1 << 30, xw2vT, parts, NG, 64, NG, NV, 512);
      k_reduce<<<dim3(256), B256, 0, stream>>>(parts, WbTp, NG * 64, 16);
    }
    // fused combine
    k_combine<<<dim3(3072), B256, 0, stream>>>(xw_v, Wbp, xw2_v, xw_g, WbTp, xw2_g,
        inv_deg_v, rsv, inv_deg_g, rsg, gs_b + i * 64, sg_b + i * 64, diffx, gxb);
  }

  hipMemcpyAsync(d_out, diffx, (size_t)NV * 64 * 4, hipMemcpyDeviceToDevice, stream);
}

// Round 13
// 943.390 us; speedup vs baseline: 1.1329x; 1.0083x over previous
//
#include <hip/hip_runtime.h>
#include <hip/hip_bf16.h>

typedef unsigned short u16;
typedef __attribute__((ext_vector_type(8))) short sh8;     // 8 x bf16 (4 VGPRs)
typedef __attribute__((ext_vector_type(4))) float f32x4;   // MFMA accum

#define NV 8192
#define NG 4096
#define NE 65536

__device__ __forceinline__ u16 f2bf(float f) {
  __hip_bfloat16 h = __float2bfloat16(f);
  return __builtin_bit_cast(u16, h);
}

// async global->LDS, 16B per lane; LDS dest = wave-uniform base + lane*16
__device__ __forceinline__ void gl_lds16(const void* g, void* l) {
  __builtin_amdgcn_global_load_lds(
      (const __attribute__((address_space(1))) void*)g,
      (__attribute__((address_space(3))) void*)l, 16, 0, 0);
}

// ---------------- setup fills ----------------
__global__ void k_fill4(float* __restrict__ deg_v, float* __restrict__ deg_g,
                        float* __restrict__ deg_e, int* __restrict__ cnt) {
  int i = blockIdx.x * 256 + threadIdx.x;
  if (i < NV) deg_v[i] = 1.f;
  int j = i - NV;
  if (j >= 0 && j < NG) deg_g[j] = 1.f;
  j -= NG;
  if (j >= 0 && j < NG) deg_e[j] = 1.f;
  j -= NG;
  if (j >= 0 && j < NG) cnt[j] = 0;
}

// ---------------- Wb build ----------------
__global__ __launch_bounds__(256) void k_wb_build(
    const float* __restrict__ vert, const float* __restrict__ gpos,
    u16* __restrict__ WbRow, u16* __restrict__ WbP, u16* __restrict__ WbTP,
    float* __restrict__ deg_v, float* __restrict__ deg_g) {
  __shared__ float lv[192], lg[192], colp[256];
  __shared__ float tile[64][65];
  int t = threadIdx.x;
  int v0 = blockIdx.x * 64, g0 = blockIdx.y * 64;
  if (t < 192) { lv[t] = vert[(size_t)v0 * 3 + t]; lg[t] = gpos[(size_t)g0 * 3 + t]; }
  __syncthreads();
  int w = t >> 6, lane = t & 63;
  float gx_ = lg[lane * 3], gy_ = lg[lane * 3 + 1], gz_ = lg[lane * 3 + 2];
  float csum = 0.f;
  #pragma unroll 4
  for (int s = 0; s < 16; s++) {
    int vl = w + 4 * s;
    float dx = lv[vl * 3] - gx_, dy = lv[vl * 3 + 1] - gy_, dz = lv[vl * 3 + 2] - gz_;
    float d = sqrtf(dx * dx + dy * dy + dz * dz);
    float W = (d < 8.0f) ? expf(d * -0.25f) : 0.f;
    if (WbRow != nullptr) WbRow[(size_t)(v0 + vl) * NG + g0 + lane] = f2bf(W);
    tile[vl][lane] = W;
    csum += W;
  }
  colp[t] = csum;
  __syncthreads();
  int r4 = t >> 2, q = t & 3;
  float rs = 0.f;
  #pragma unroll
  for (int j = 0; j < 16; j++) rs += tile[r4][q * 16 + j];
  rs += __shfl_xor(rs, 1);
  rs += __shfl_xor(rs, 2);
  if (q == 0) atomicAdd(&deg_v[v0 + r4], rs);
  if (w == 0) {
    float tot = colp[lane] + colp[64 + lane] + colp[128 + lane] + colp[192 + lane];
    atomicAdd(&deg_g[g0 + lane], tot);
  }
  if (WbP != nullptr) {
    size_t tb = ((size_t)(v0 >> 7) * 64 + (g0 >> 6)) * 8192;
    #pragma unroll
    for (int j = 0; j < 2; j++) {
      int idx = j * 256 + t;
      int vr = idx >> 3, k8 = (idx & 7) * 8;
      u16 pk[8];
      #pragma unroll
      for (int qq = 0; qq < 8; qq++) pk[qq] = f2bf(tile[vr][k8 + qq]);
      int r = (v0 & 64) + vr;
      *(uint4*)&WbP[tb + (size_t)r * 64 + (size_t)(((k8 >> 3) ^ (r & 7)) << 3)] = *(uint4*)pk;
    }
  }
  if (WbTP != nullptr) {
    size_t tb = ((size_t)(g0 >> 7) * 128 + (v0 >> 6)) * 8192;
    #pragma unroll
    for (int j = 0; j < 2; j++) {
      int idx = j * 256 + t;
      int gr = idx >> 3, v8 = (idx & 7) * 8;
      u16 pk[8];
      #pragma unroll
      for (int qq = 0; qq < 8; qq++) pk[qq] = f2bf(tile[v8 + qq][gr]);
      int r = (g0 & 64) + gr;
      *(uint4*)&WbTP[tb + (size_t)r * 64 + (size_t)(((v8 >> 3) ^ (r & 7)) << 3)] = *(uint4*)pk;
    }
  }
}

// all three recips in one launch
__global__ void k_recips(const float* __restrict__ deg_v, float* __restrict__ inv_v,
                         float* __restrict__ rs_v, const float* __restrict__ deg_g,
                         float* __restrict__ inv_g, float* __restrict__ rs_g,
                         const float* __restrict__ deg_e, float* __restrict__ inv_e,
                         float* __restrict__ rs_e) {
  int i = blockIdx.x * 256 + threadIdx.x;
  if (i < NV) { float d = deg_v[i]; inv_v[i] = 1.f / d; rs_v[i] = 1.f / sqrtf(d); }
  else if (i < NV + NG) {
    int j = i - NV; float d = deg_g[j]; inv_g[j] = 1.f / d; rs_g[j] = 1.f / sqrtf(d);
  } else if (i < NV + 2 * NG) {
    int j = i - NV - NG; float d = deg_e[j]; inv_e[j] = 1.f / d; rs_e[j] = 1.f / sqrtf(d);
  }
}

// ---------------- edge preprocessing (CSR) ----------------
__global__ void k_edge_prep(const int* __restrict__ eidx, const float* __restrict__ ew,
                            float* __restrict__ deg_e, int* __restrict__ cnt) {
  int e = blockIdx.x * 256 + threadIdx.x;
  if (e < NE) { int d = eidx[NE + e]; atomicAdd(&deg_e[d], ew[e]); atomicAdd(&cnt[d], 1); }
}

__global__ __launch_bounds__(1024) void k_scan(const int* __restrict__ cnt,
    int* __restrict__ row_ptr, int* __restrict__ cursor) {
  __shared__ int buf0[1024], buf1[1024];
  int t = threadIdx.x;
  int b = t * 4;
  int c0 = cnt[b], c1 = cnt[b + 1], c2 = cnt[b + 2], c3 = cnt[b + 3];
  int s = c0 + c1 + c2 + c3;
  buf0[t] = s;
  __syncthreads();
  int* src = buf0; int* dst = buf1;
  for (int off = 1; off < 1024; off <<= 1) {
    int v = src[t];
    if (t >= off) v += src[t - off];
    dst[t] = v;
    __syncthreads();
    int* tmp = src; src = dst; dst = tmp;
  }
  int excl = (t == 0) ? 0 : src[t - 1];
  int r0 = excl, r1 = excl + c0, r2 = excl + c0 + c1, r3 = excl + c0 + c1 + c2;
  row_ptr[b] = r0; row_ptr[b + 1] = r1; row_ptr[b + 2] = r2; row_ptr[b + 3] = r3;
  cursor[b] = r0; cursor[b + 1] = r1; cursor[b + 2] = r2; cursor[b + 3] = r3;
  if (t == 1023) row_ptr[4096] = src[1023];
}

__global__ void k_scatter(const int* __restrict__ eidx, const float* __restrict__ ew,
                          const float* __restrict__ dinv, int* __restrict__ cursor,
                          int* __restrict__ csrc, float* __restrict__ cnorm) {
  int e = blockIdx.x * 256 + threadIdx.x;
  if (e < NE) {
    int s = eidx[e], d = eidx[NE + e];
    int slot = atomicAdd(&cursor[d], 1);
    csrc[slot] = s;
    cnorm[slot] = dinv[s] * ew[e] * dinv[d];
  }
}

// ---------------- evecs -> bf16 transposed [128][NV] ----------------
__global__ __launch_bounds__(256) void k_evecsT(const float* __restrict__ ev, u16* __restrict__ evT) {
  __shared__ float tile[32][33];
  int t = threadIdx.x;
  int v0 = blockIdx.x * 32, k0 = blockIdx.y * 32;
  int r = t >> 3, c4 = (t & 7) * 4;
  float4 x = *(const float4*)(ev + (size_t)(v0 + r) * 128 + k0 + c4);
  tile[r][c4] = x.x; tile[r][c4 + 1] = x.y; tile[r][c4 + 2] = x.z; tile[r][c4 + 3] = x.w;
  __syncthreads();
  u16* dst = evT + (size_t)(k0 + r) * NV + v0 + c4;
  dst[0] = f2bf(tile[c4][r]); dst[1] = f2bf(tile[c4 + 1][r]);
  dst[2] = f2bf(tile[c4 + 2][r]); dst[3] = f2bf(tile[c4 + 3][r]);
}

// =============== setup GEMM: BM=256/BN=128/BK=32, double-buffered ===========
__global__ __launch_bounds__(256) void gemm_setup3(
    const float* __restrict__ gXm, const float* __restrict__ gYm,
    const u16* __restrict__ evT, float* __restrict__ parts,
    int z, int kchunk) {
  extern __shared__ __align__(16) char smem[];   // 2 x (A 32KB + B 8KB)
  const int t = threadIdx.x;
  const int lane = t & 63, wave = t >> 6;
  const int rl = lane & 15, hi = lane >> 4;
  int b = blockIdx.x;
  const int zi = b % z; b /= z;
  const int mb = b & 31;
  const int mat = b >> 5;
  const float* A = mat ? gYm : gXm;
  const int m0 = mb * 256;
  const int kbeg = zi * kchunk;
  const int nt = kchunk >> 5;
  const int wm = wave * 64;

  f32x4 acc[4][8];
  #pragma unroll
  for (int a = 0; a < 4; a++)
    #pragma unroll
    for (int bb = 0; bb < 8; bb++) acc[a][bb] = f32x4{0.f, 0.f, 0.f, 0.f};

  auto STAGE = [&](int buf, int k0) {   // exactly 10 gl_lds16 per wave
    char* aB = smem + buf * 40960;
    #pragma unroll
    for (int jj = 0; jj < 8; jj++) {
      int R0 = wave * 64 + jj * 8;
      int r = R0 + (lane >> 3);
      int s = lane & 7;
      gl_lds16(A + (size_t)(m0 + r) * NV + k0 + ((s ^ (r & 7)) << 2), aB + R0 * 128);
    }
    char* bB = smem + buf * 40960 + 32768;
    #pragma unroll
    for (int jj = 0; jj < 2; jj++) {
      int R0 = wave * 32 + jj * 16;
      int n = R0 + (lane >> 2);
      int s = lane & 3;
      gl_lds16(evT + (size_t)n * NV + k0 + ((s ^ ((n >> 1) & 3)) << 3), bB + R0 * 64);
    }
  };

  auto COMPUTE = [&](int buf) {
    const float* Af = (const float*)(smem + buf * 40960);
    const u16* Bf = (const u16*)(smem + buf * 40960 + 32768);
    sh8 av[4], bv[8];
    #pragma unroll
    for (int mf = 0; mf < 4; mf++) {
      int r = wm + mf * 16 + rl;
      f32x4 lo = *(const f32x4*)(Af + r * 32 + (((2 * hi) ^ (r & 7)) << 2));
      f32x4 h4 = *(const f32x4*)(Af + r * 32 + (((2 * hi + 1) ^ (r & 7)) << 2));
      sh8 v;
      v[0] = (short)f2bf(lo[0]); v[1] = (short)f2bf(lo[1]);
      v[2] = (short)f2bf(lo[2]); v[3] = (short)f2bf(lo[3]);
      v[4] = (short)f2bf(h4[0]); v[5] = (short)f2bf(h4[1]);
      v[6] = (short)f2bf(h4[2]); v[7] = (short)f2bf(h4[3]);
      av[mf] = v;
    }
    #pragma unroll
    for (int nf = 0; nf < 8; nf++) {
      int n = nf * 16 + rl;
      bv[nf] = *(const sh8*)(Bf + n * 32 + ((hi ^ ((n >> 1) & 3)) << 3));
    }
    #pragma unroll
    for (int mf = 0; mf < 4; mf++)
      #pragma unroll
      for (int nf = 0; nf < 8; nf++)
        acc[mf][nf] = __builtin_amdgcn_mfma_f32_16x16x32_bf16(av[mf], bv[nf], acc[mf][nf], 0, 0, 0);
  };

  STAGE(0, kbeg);
  if (nt > 1) STAGE(1, kbeg + 32);
  for (int ti = 0; ti < nt; ti++) {
    if (ti + 1 < nt) { asm volatile("s_waitcnt vmcnt(10)" ::: "memory"); }
    else             { asm volatile("s_waitcnt vmcnt(0)" ::: "memory"); }
    __builtin_amdgcn_sched_barrier(0);
    __builtin_amdgcn_s_barrier();
    COMPUTE(ti & 1);
    __builtin_amdgcn_sched_barrier(0);
    __builtin_amdgcn_s_barrier();
    if (ti + 2 < nt) STAGE(ti & 1, kbeg + (ti + 2) * 32);
  }

  float* C = parts + (size_t)(mat * z + zi) * (NV * 128);
  #pragma unroll
  for (int mf = 0; mf < 4; mf++)
    #pragma unroll
    for (int nf = 0; nf < 8; nf++) {
      int row = m0 + wm + mf * 16 + hi * 4;
      int col = nf * 16 + rl;
      #pragma unroll
      for (int q = 0; q < 4; q++)
        C[(size_t)(row + q) * 128 + col] = acc[mf][nf][q];
    }
}

// =============== merged panel GEMM: blocks [0,512) Wbp, [512,1024) WbTp ====
__global__ __launch_bounds__(256) void gemm_panel2(
    const u16* __restrict__ WbP, const u16* __restrict__ WbTP,
    const u16* __restrict__ xwgT, const u16* __restrict__ xw2vT,
    float* __restrict__ parts) {
  __shared__ __align__(16) char smem[49152];   // 2 x (A 16KB + B 8KB)
  const int t = threadIdx.x;
  const int lane = t & 63, wave = t >> 6;
  const int rl = lane & 15, hi = lane >> 4;
  int bid = blockIdx.x;
  const u16* Apan; const u16* BT; int KT, ldbt, mb, z;
  float* Cbase;
  if (bid < 512) {
    Apan = WbP; BT = xwgT; KT = 64; ldbt = NG;
    mb = bid >> 3; z = bid & 7;
    Cbase = parts + (size_t)z * NV * 64;
  } else {
    bid -= 512;
    Apan = WbTP; BT = xw2vT; KT = 128; ldbt = NV;
    mb = bid >> 4; z = bid & 15;
    Cbase = parts + (size_t)8 * NV * 64 + (size_t)z * NG * 64;
  }
  const int ktpz = 8;
  const int kt0 = z * ktpz;
  const int wm = wave * 32;

  f32x4 acc[2][4];
  #pragma unroll
  for (int a = 0; a < 2; a++)
    #pragma unroll
    for (int b = 0; b < 4; b++) acc[a][b] = f32x4{0.f, 0.f, 0.f, 0.f};

  auto STAGE = [&](int buf, int kt) {   // exactly 6 gl_lds16 per wave
    char* aB = smem + buf * 24576;
    const u16* tbase = Apan + ((size_t)mb * KT + kt) * 8192;
    #pragma unroll
    for (int jj = 0; jj < 4; jj++) {
      int j = wave * 4 + jj;
      gl_lds16(tbase + j * 512 + lane * 8, aB + j * 1024);
    }
    char* bB = aB + 16384;
    #pragma unroll
    for (int jj = 0; jj < 2; jj++) {
      int j = wave * 2 + jj;
      int n = 8 * j + (lane >> 3);
      const u16* srcb = BT + (size_t)n * ldbt + kt * 64 + (((lane & 7) ^ (n & 7)) << 3);
      gl_lds16(srcb, bB + j * 1024);
    }
  };

  auto COMPUTE = [&](int buf) {
    const u16* Af = (const u16*)(smem + buf * 24576);
    const u16* Bf = Af + 8192;
    #pragma unroll
    for (int step = 0; step < 2; step++) {
      sh8 av[2], bv[4];
      int s = step * 4 + hi;
      #pragma unroll
      for (int mf = 0; mf < 2; mf++) {
        int r = wm + mf * 16 + rl;
        av[mf] = *(const sh8*)(Af + r * 64 + ((s ^ (r & 7)) << 3));
      }
      #pragma unroll
      for (int nf = 0; nf < 4; nf++) {
        int n = nf * 16 + rl;
        bv[nf] = *(const sh8*)(Bf + n * 64 + ((s ^ (n & 7)) << 3));
      }
      #pragma unroll
      for (int mf = 0; mf < 2; mf++)
        #pragma unroll
        for (int nf = 0; nf < 4; nf++)
          acc[mf][nf] = __builtin_amdgcn_mfma_f32_16x16x32_bf16(av[mf], bv[nf], acc[mf][nf], 0, 0, 0);
    }
  };

  STAGE(0, kt0);
  STAGE(1, kt0 + 1);
  for (int ti = 0; ti < ktpz; ti++) {
    if (ti + 1 < ktpz) { asm volatile("s_waitcnt vmcnt(6)" ::: "memory"); }
    else               { asm volatile("s_waitcnt vmcnt(0)" ::: "memory"); }
    __builtin_amdgcn_sched_barrier(0);
    __builtin_amdgcn_s_barrier();
    COMPUTE(ti & 1);
    __builtin_amdgcn_sched_barrier(0);
    __builtin_amdgcn_s_barrier();
    if (ti + 2 < ktpz) STAGE(ti & 1, kt0 + ti + 2);
  }

  #pragma unroll
  for (int mf = 0; mf < 2; mf++)
    #pragma unroll
    for (int nf = 0; nf < 4; nf++) {
      int row = mb * 128 + wm + mf * 16 + hi * 4;
      int col = nf * 16 + rl;
      #pragma unroll
      for (int q = 0; q < 4; q++)
        Cbase[(size_t)(row + q) * 64 + col] = acc[mf][nf][q];
    }
}

// reduce both panel results: Wbp (8 slices) then WbTp (16 slices)
__global__ void k_reduce_both(const float* __restrict__ parts,
    float* __restrict__ Wbp, float* __restrict__ WbTp) {
  int i = (blockIdx.x * 256 + threadIdx.x) * 4;
  if (i < NV * 64) {
    float4 s = *(const float4*)(parts + i);
    for (int z = 1; z < 8; z++) {
      float4 v = *(const float4*)(parts + (size_t)z * NV * 64 + i);
      s.x += v.x; s.y += v.y; s.z += v.z; s.w += v.w;
    }
    *(float4*)(Wbp + i) = s;
  } else {
    int j = i - NV * 64;
    if (j < NG * 64) {
      const float* src = parts + (size_t)8 * NV * 64;
      float4 s = *(const float4*)(src + j);
      for (int z = 1; z < 16; z++) {
        float4 v = *(const float4*)(src + (size_t)z * NG * 64 + j);
        s.x += v.x; s.y += v.y; s.z += v.z; s.w += v.w;
      }
      *(float4*)(WbTp + j) = s;
    }
  }
}

// =============== generic bf16 GEMM (row-tier Wb fallback), BM=128, BN=64 ====
__global__ __launch_bounds__(256) void gemm_bf16(
    const u16* __restrict__ Ab, int lda, const u16* __restrict__ BT, int ldbt,
    float* __restrict__ parts, int M, int kchunk) {
  __shared__ __align__(16) char smem[49152];
  const int t = threadIdx.x;
  const int lane = t & 63, wave = t >> 6;
  const int m0 = blockIdx.x * 128;
  const int kbeg = blockIdx.z * kchunk;
  const int nt = kchunk >> 6;
  const int wm = (wave >> 1) * 64, wn = (wave & 1) * 32;
  const int arl = lane >> 3, asl = lane & 7;

  f32x4 acc[4][2];
  #pragma unroll
  for (int a = 0; a < 4; a++)
    #pragma unroll
    for (int b = 0; b < 2; b++) acc[a][b] = f32x4{0.f, 0.f, 0.f, 0.f};

  auto STAGE = [&](int buf, int k0) {
    char* base = smem + buf * 24576;
    #pragma unroll
    for (int j = 0; j < 4; j++) {
      int R0 = (wave * 4 + j) * 8;
      int r = R0 + arl;
      int gs = asl ^ (r & 7);
      gl_lds16(Ab + (size_t)(m0 + r) * lda + k0 + gs * 8, base + R0 * 128);
    }
    char* bb = base + 16384;
    #pragma unroll
    for (int j = 0; j < 2; j++) {
      int R0 = (wave * 2 + j) * 8;
      int r = R0 + arl;
      int gs = asl ^ (r & 7);
      gl_lds16(BT + (size_t)r * ldbt + k0 + gs * 8, bb + R0 * 128);
    }
  };

  auto COMPUTE = [&](int buf) {
    char* base = smem + buf * 24576;
    const u16* Af = (const u16*)base;
    const u16* Bf = (const u16*)(base + 16384);
    #pragma unroll
    for (int kk = 0; kk < 2; kk++) {
      sh8 av[4], bv[2];
      #pragma unroll
      for (int mf = 0; mf < 4; mf++) {
        int r = wm + mf * 16 + (lane & 15);
        int g = kk * 4 + (lane >> 4);
        av[mf] = *(const sh8*)(Af + r * 64 + (g ^ (r & 7)) * 8);
      }
      #pragma unroll
      for (int nf = 0; nf < 2; nf++) {
        int r = wn + nf * 16 + (lane & 15);
        int g = kk * 4 + (lane >> 4);
        bv[nf] = *(const sh8*)(Bf + r * 64 + (g ^ (r & 7)) * 8);
      }
      #pragma unroll
      for (int mf = 0; mf < 4; mf++)
        #pragma unroll
        for (int nf = 0; nf < 2; nf++)
          acc[mf][nf] = __builtin_amdgcn_mfma_f32_16x16x32_bf16(av[mf], bv[nf], acc[mf][nf], 0, 0, 0);
    }
  };

  STAGE(0, kbeg);
  if (nt > 1) STAGE(1, kbeg + 64);
  for (int ti = 0; ti < nt; ti++) {
    if (ti + 1 < nt) { asm volatile("s_waitcnt vmcnt(6)" ::: "memory"); }
    else             { asm volatile("s_waitcnt vmcnt(0)" ::: "memory"); }
    __builtin_amdgcn_sched_barrier(0);
    __builtin_amdgcn_s_barrier();
    COMPUTE(ti & 1);
    __builtin_amdgcn_sched_barrier(0);
    __builtin_amdgcn_s_barrier();
    if (ti + 2 < nt) STAGE(ti & 1, kbeg + (ti + 2) * 64);
  }

  float* C = parts + (size_t)blockIdx.z * M * 64;
  #pragma unroll
  for (int mf = 0; mf < 4; mf++)
    #pragma unroll
    for (int nf = 0; nf < 2; nf++) {
      int row = m0 + wm + mf * 16 + (lane >> 4) * 4;
      int col = wn + nf * 16 + (lane & 15);
      #pragma unroll
      for (int q = 0; q < 4; q++)
        C[(size_t)(row + q) * 64 + col] = acc[mf][nf][q];
    }
}

// ---------------- ATRANS fallback GEMM (low-ws WbT path) ----------------
template<int BN, bool AF32, bool ATRANS>
__global__ __launch_bounds__(256) void gemm_k(
    const void* __restrict__ Aptr, const void* __restrict__ A2, int zsplit2,
    const u16* __restrict__ BT, float* __restrict__ Cpart,
    int M, int N, int lda, int ldbt, int kchunk) {
  constexpr int NF = BN / 32;
  __shared__ u16 lA[128 * 40];
  __shared__ u16 lB[BN * 40];
  const int t = threadIdx.x;
  const int m0 = blockIdx.x * 128, n0 = blockIdx.y * BN;
  const void* Ause = Aptr;
  int kz = blockIdx.z;
  if (A2 != nullptr && kz >= zsplit2) { Ause = A2; kz -= zsplit2; }
  const int kbeg = kz * kchunk;
  const int lane = t & 63, wave = t >> 6;
  const int wm = (wave >> 1) * 64, wn = (wave & 1) * (BN / 2);
  f32x4 zero = {0.f, 0.f, 0.f, 0.f};
  f32x4 acc[4][NF];
  #pragma unroll
  for (int a = 0; a < 4; a++)
    #pragma unroll
    for (int b = 0; b < NF; b++) acc[a][b] = zero;

  for (int k0 = kbeg; k0 < kbeg + kchunk; k0 += 32) {
    if constexpr (!ATRANS) {
      const int r = t >> 1, cc = (t & 1) * 16;
      const u16* A = (const u16*)Ause + (size_t)(m0 + r) * lda + k0 + cc;
      *(uint4*)&lA[r * 40 + cc] = *(const uint4*)A;
      *(uint4*)&lA[r * 40 + cc + 8] = *(const uint4*)(A + 8);
    } else {
      const int kl = t >> 3, mb = (t & 7) * 16;
      const u16* A = (const u16*)Ause + (size_t)(k0 + kl) * lda + m0 + mb;
      u16 vals[16];
      *(uint4*)&vals[0] = *(const uint4*)A;
      *(uint4*)&vals[8] = *(const uint4*)(A + 8);
      #pragma unroll
      for (int j = 0; j < 16; j++) lA[(mb + j) * 40 + kl] = vals[j];
    }
    if constexpr (BN == 64) {
      const int r = t >> 2, cc = (t & 3) * 8;
      const u16* B = BT + (size_t)(n0 + r) * ldbt + k0 + cc;
      *(uint4*)&lB[r * 40 + cc] = *(const uint4*)B;
    } else {
      const int r = t >> 1, cc = (t & 1) * 16;
      const u16* B = BT + (size_t)(n0 + r) * ldbt + k0 + cc;
      *(uint4*)&lB[r * 40 + cc] = *(const uint4*)B;
      *(uint4*)&lB[r * 40 + cc + 8] = *(const uint4*)(B + 8);
    }
    __syncthreads();
    sh8 af[4], bfv[NF];
    #pragma unroll
    for (int mf = 0; mf < 4; mf++)
      af[mf] = *(const sh8*)&lA[(wm + mf * 16 + (lane & 15)) * 40 + (lane >> 4) * 8];
    #pragma unroll
    for (int nf = 0; nf < NF; nf++)
      bfv[nf] = *(const sh8*)&lB[(wn + nf * 16 + (lane & 15)) * 40 + (lane >> 4) * 8];
    #pragma unroll
    for (int mf = 0; mf < 4; mf++)
      #pragma unroll
      for (int nf = 0; nf < NF; nf++)
        acc[mf][nf] = __builtin_amdgcn_mfma_f32_16x16x32_bf16(af[mf], bfv[nf], acc[mf][nf], 0, 0, 0);
    __syncthreads();
  }
  float* C = Cpart + (size_t)blockIdx.z * M * N;
  #pragma unroll
  for (int mf = 0; mf < 4; mf++)
    #pragma unroll
    for (int nf = 0; nf < NF; nf++) {
      const int row = m0 + wm + mf * 16 + (lane >> 4) * 4;
      const int col = n0 + wn + nf * 16 + (lane & 15);
      #pragma unroll
      for (int q = 0; q < 4; q++)
        C[(size_t)(row + q) * N + col] = acc[mf][nf][q];
    }
}

__global__ void k_reduce(const float* __restrict__ parts, float* __restrict__ dst, int len, int nz) {
  int i = (blockIdx.x * 256 + threadIdx.x) * 4;
  if (i >= len) return;
  float4 s = *(const float4*)(parts + i);
  for (int z = 1; z < nz; z++) {
    float4 v = *(const float4*)(parts + (size_t)z * len + i);
    s.x += v.x; s.y += v.y; s.z += v.z; s.w += v.w;
  }
  *(float4*)(dst + i) = s;
}

// two matrices packed: dst[mat*len + j] = sum_z parts[(mat*nz+z)*len + j]
__global__ void k_reduce2(const float* __restrict__ parts, float* __restrict__ dst, int len, int nz) {
  int i = (blockIdx.x * 256 + threadIdx.x) * 4;
  if (i >= 2 * len) return;
  int mat = i / len, j = i - mat * len;
  const float* src = parts + (size_t)mat * nz * len + j;
  float4 s = *(const float4*)src;
  for (int z = 1; z < nz; z++) {
    float4 v = *(const float4*)(src + (size_t)z * len);
    s.x += v.x; s.y += v.y; s.z += v.z; s.w += v.w;
  }
  *(float4*)(dst + i) = s;
}

// ---------------- fused lin1/lin2 (C_IN=128 -> DW=64) ----------------
__global__ __launch_bounds__(256) void k_lin_both(const float* __restrict__ x_in,
    const float* __restrict__ graph_x, const float* __restrict__ W1,
    const float* __restrict__ b1, const float* __restrict__ W2,
    const float* __restrict__ b2, float* __restrict__ outV, float* __restrict__ outG) {
  __shared__ float lW[8192];
  __shared__ float lb[64];
  int bb = blockIdx.x;
  bool isV = bb < 2048;
  const float* W = isV ? W1 : W2;
  const float* bi = isV ? b1 : b2;
  const float* A = isV ? x_in : graph_x;
  float* out = isV ? outV : outG;
  int rb = isV ? bb : bb - 2048;
  int t = threadIdx.x;
  for (int i = t; i < 8192; i += 256) lW[i] = W[i];
  if (t < 64) lb[t] = bi[t];
  __syncthreads();
  int row = rb * 4 + (t >> 6), c = t & 63;
  const float* Ar = A + (size_t)row * 128;
  float acc = lb[c];
  #pragma unroll 8
  for (int k = 0; k < 128; k++) acc += Ar[k] * lW[k * 64 + c];
  out[(size_t)row * 64 + c] = acc;
}

// ====== merged launch 1: mdxT (blocks 0..127) | gcn1 matmul (128..1151) =====
__global__ __launch_bounds__(256) void k_front(
    const float* __restrict__ dx, const float* __restrict__ mass,
    u16* __restrict__ mdxT, const float* __restrict__ gxb,
    const float* __restrict__ W, float* __restrict__ xw1) {
  __shared__ __align__(16) char shm[16896];
  int t = threadIdx.x;
  int bid = blockIdx.x;
  if (bid < 128) {
    float (*tile)[65] = (float(*)[65])shm;
    float* lm = (float*)(shm + 16640);
    int v0 = bid * 64;
    if (t < 64) lm[t] = mass[v0 + t];
    #pragma unroll
    for (int i = 0; i < 16; i++) {
      int idx = i * 256 + t;
      int r = idx >> 6, c = idx & 63;
      tile[r][c] = dx[(size_t)(v0 + r) * 64 + c];
    }
    __syncthreads();
    int c = t >> 2;
    #pragma unroll
    for (int i = 0; i < 2; i++) {
      int vq = (t & 3) * 16 + i * 8;
      u16 pk[8];
      #pragma unroll
      for (int q = 0; q < 8; q++) pk[q] = f2bf(lm[vq + q] * tile[vq + q][c]);
      *(uint4*)&mdxT[(size_t)c * NV + v0 + vq] = *(uint4*)pk;
    }
  } else {
    float* lW = (float*)shm;
    int rb = bid - 128;
    for (int i = t; i < 4096; i += 256) lW[i] = W[i];
    __syncthreads();
    int row = rb * 4 + (t >> 6), c = t & 63;
    const float* Ar = gxb + (size_t)row * 64;
    float acc = 0.f;
    #pragma unroll 8
    for (int k = 0; k < 64; k++) acc += Ar[k] * lW[k * 64 + c];
    xw1[(size_t)row * 64 + c] = acc;
  }
}

// ====== merged launch 2: spec GEMM (blocks 0..63) | gcn1 agg+W2 (64..1087) ==
__global__ __launch_bounds__(256) void k_specagg(
    const u16* __restrict__ evT, const u16* __restrict__ mdxT,
    float* __restrict__ parts,
    const float* __restrict__ xw, const int* __restrict__ rp,
    const int* __restrict__ csrc, const float* __restrict__ cnorm,
    const float* __restrict__ invdeg, const float* __restrict__ b1,
    const float* __restrict__ W2, float* __restrict__ out) {
  __shared__ __align__(16) char smem[49152];
  const int t = threadIdx.x;
  if (blockIdx.x < 64) {
    // spec slice: parts[z] = evecsT(128 rows) @ mdxT^T over K-slice z*128
    const int lane = t & 63, wave = t >> 6;
    const int kbeg = blockIdx.x * 128;
    const int wm = (wave >> 1) * 64, wn = (wave & 1) * 32;
    const int arl = lane >> 3, asl = lane & 7;
    f32x4 acc[4][2];
    #pragma unroll
    for (int a = 0; a < 4; a++)
      #pragma unroll
      for (int b = 0; b < 2; b++) acc[a][b] = f32x4{0.f, 0.f, 0.f, 0.f};
    auto STAGE = [&](int buf, int k0) {
      char* base = smem + buf * 24576;
      #pragma unroll
      for (int j = 0; j < 4; j++) {
        int R0 = (wave * 4 + j) * 8;
        int r = R0 + arl;
        int gs = asl ^ (r & 7);
        gl_lds16(evT + (size_t)r * NV + k0 + gs * 8, base + R0 * 128);
      }
      char* bb = base + 16384;
      #pragma unroll
      for (int j = 0; j < 2; j++) {
        int R0 = (wave * 2 + j) * 8;
        int r = R0 + arl;
        int gs = asl ^ (r & 7);
        gl_lds16(mdxT + (size_t)r * NV + k0 + gs * 8, bb + R0 * 128);
      }
    };
    auto COMPUTE = [&](int buf) {
      char* base = smem + buf * 24576;
      const u16* Af = (const u16*)base;
      const u16* Bf = (const u16*)(base + 16384);
      #pragma unroll
      for (int kk = 0; kk < 2; kk++) {
        sh8 av[4], bv[2];
        #pragma unroll
        for (int mf = 0; mf < 4; mf++) {
          int r = wm + mf * 16 + (lane & 15);
          int g = kk * 4 + (lane >> 4);
          av[mf] = *(const sh8*)(Af + r * 64 + (g ^ (r & 7)) * 8);
        }
        #pragma unroll
        for (int nf = 0; nf < 2; nf++) {
          int r = wn + nf * 16 + (lane & 15);
          int g = kk * 4 + (lane >> 4);
          bv[nf] = *(const sh8*)(Bf + r * 64 + (g ^ (r & 7)) * 8);
        }
        #pragma unroll
        for (int mf = 0; mf < 4; mf++)
          #pragma unroll
          for (int nf = 0; nf < 2; nf++)
            acc[mf][nf] = __builtin_amdgcn_mfma_f32_16x16x32_bf16(av[mf], bv[nf], acc[mf][nf], 0, 0, 0);
      }
    };
    STAGE(0, kbeg);
    STAGE(1, kbeg + 64);
    for (int ti = 0; ti < 2; ti++) {
      if (ti == 0) { asm volatile("s_waitcnt vmcnt(6)" ::: "memory"); }
      else         { asm volatile("s_waitcnt vmcnt(0)" ::: "memory"); }
      __builtin_amdgcn_sched_barrier(0);
      __builtin_amdgcn_s_barrier();
      COMPUTE(ti);
      __builtin_amdgcn_sched_barrier(0);
      __builtin_amdgcn_s_barrier();
    }
    float* C = parts + (size_t)blockIdx.x * 8192;
    const int lane2 = t & 63;
    #pragma unroll
    for (int mf = 0; mf < 4; mf++)
      #pragma unroll
      for (int nf = 0; nf < 2; nf++) {
        int row = wm + mf * 16 + (lane2 >> 4) * 4;
        int col = wn + nf * 16 + (lane2 & 15);
        #pragma unroll
        for (int q = 0; q < 4; q++)
          C[(size_t)(row + q) * 64 + col] = acc[mf][nf][q];
      }
  } else {
    float* lrow = (float*)smem;
    int g = (blockIdx.x - 64) * 4 + (t >> 6), c = t & 63;
    float acc = xw[(size_t)g * 64 + c] * invdeg[g] + b1[c];
    int j1 = rp[g + 1];
    for (int j = rp[g]; j < j1; j++) acc += cnorm[j] * xw[(size_t)csrc[j] * 64 + c];
    acc = fmaxf(acc, 0.f);
    lrow[t] = acc;
    __syncthreads();
    int grp = t & 192;
    float o = 0.f;
    #pragma unroll 8
    for (int k = 0; k < 64; k++) o += lrow[grp + k] * W2[k * 64 + c];
    out[(size_t)g * 64 + c] = o;
  }
}

// ====== merged launch 3: reduce_es (blocks 0..31) | gcn2 agg+dual (32..1055)
__global__ __launch_bounds__(256) void k_redagg(
    const float* __restrict__ parts, const float* __restrict__ evals,
    const float* __restrict__ dt, float* __restrict__ Es,
    const float* __restrict__ xw, const int* __restrict__ rp,
    const int* __restrict__ csrc, const float* __restrict__ cnorm,
    const float* __restrict__ invdeg, const float* __restrict__ b2,
    const float* __restrict__ gsw, const float* __restrict__ sgw,
    float* __restrict__ xw_g, float* __restrict__ xw2_g, u16* __restrict__ xwgT) {
  __shared__ float lrow[256];
  int t = threadIdx.x;
  if (blockIdx.x < 32) {
    int i = blockIdx.x * 256 + t;
    float s = 0.f;
    #pragma unroll 8
    for (int z = 0; z < 64; z++) s += parts[(size_t)z * 8192 + i];
    int k = i >> 6, c = i & 63;
    Es[i] = expf(-evals[k] * fmaxf(dt[c], 1e-8f)) * s;
  } else {
    int g = (blockIdx.x - 32) * 4 + (t >> 6), c = t & 63;
    float acc = xw[(size_t)g * 64 + c] * invdeg[g] + b2[c];
    int j1 = rp[g + 1];
    for (int j = rp[g]; j < j1; j++) acc += cnorm[j] * xw[(size_t)csrc[j] * 64 + c];
    lrow[t] = acc;
    __syncthreads();
    int grp = t & 192;
    float p = 0.f, q = 0.f;
    #pragma unroll 8
    for (int k = 0; k < 64; k++) {
      float r = lrow[grp + k];
      p += r * gsw[k * 64 + c];
      q += r * sgw[k * 64 + c];
    }
    xw_g[(size_t)g * 64 + c] = p;
    xw2_g[(size_t)g * 64 + c] = q;
    xwgT[(size_t)c * NG + g] = f2bf(p);
  }
}

// ---------------- fused xd + gradient features ----------------
__global__ __launch_bounds__(256) void k_xdgf(const float* __restrict__ evecs,
    const float* __restrict__ GXE, const float* __restrict__ GYE,
    const float* __restrict__ Es, const float* __restrict__ Are,
    const float* __restrict__ Aim, float* __restrict__ xd, float* __restrict__ gf) {
  __shared__ float lE[8192];
  __shared__ float lr[4096], li[4096];
  __shared__ float lgx[256], lgy[256];
  int t = threadIdx.x;
  for (int i = t; i < 8192; i += 256) lE[i] = Es[i];
  for (int i = t; i < 4096; i += 256) { lr[i] = Are[i]; li[i] = Aim[i]; }
  __syncthreads();
  int wr = t >> 6, c = t & 63;
  int row = blockIdx.x * 4 + wr;
  const float* er = evecs + (size_t)row * 128;
  const float* xr = GXE + (size_t)row * 128;
  const float* yr = GYE + (size_t)row * 128;
  float a0 = 0, a1 = 0, a2 = 0;
  #pragma unroll 8
  for (int k = 0; k < 128; k++) {
    float s = lE[k * 64 + c];
    a0 += er[k] * s; a1 += xr[k] * s; a2 += yr[k] * s;
  }
  lgx[wr * 64 + c] = a1;
  lgy[wr * 64 + c] = a2;
  __syncthreads();
  float br = 0.f, bi = 0.f;
  #pragma unroll 8
  for (int k = 0; k < 64; k++) {
    float gx = lgx[wr * 64 + k], gy = lgy[wr * 64 + k];
    float ar = lr[k * 64 + c], ai = li[k * 64 + c];
    br += gx * ar - gy * ai;
    bi += gy * ar + gx * ai;
  }
  xd[(size_t)row * 64 + c] = a0;
  gf[(size_t)row * 64 + c] = tanhf(a1 * br + a2 * bi);
}

__global__ __launch_bounds__(256) void k_mlp0(const float* __restrict__ dx,
    const float* __restrict__ xd, const float* __restrict__ gf,
    const float* __restrict__ W0, const float* __restrict__ b0, float* __restrict__ h1) {
  __shared__ float lW[12288];
  __shared__ float lb[64];
  int t = threadIdx.x;
  for (int i = t; i < 12288; i += 256) lW[i] = W0[i];
  if (t < 64) lb[t] = b0[t];
  __syncthreads();
  int row = blockIdx.x * 4 + (t >> 6), c = t & 63;
  const float* a0 = dx + (size_t)row * 64;
  const float* a1 = xd + (size_t)row * 64;
  const float* a2 = gf + (size_t)row * 64;
  float acc = lb[c];
  #pragma unroll 8
  for (int k = 0; k < 64; k++) acc += a0[k] * lW[k * 64 + c];
  #pragma unroll 8
  for (int k = 0; k < 64; k++) acc += a1[k] * lW[(64 + k) * 64 + c];
  #pragma unroll 8
  for (int k = 0; k < 64; k++) acc += a2[k] * lW[(128 + k) * 64 + c];
  h1[(size_t)row * 64 + c] = fmaxf(acc, 0.f);
}

// fused mlp1+mlp2+residual+dual projection (post-MLP diffx never stored)
__global__ __launch_bounds__(256) void k_mlp12_dual(const float* __restrict__ h1,
    const float* __restrict__ W1, const float* __restrict__ b1,
    const float* __restrict__ W2, const float* __restrict__ b2,
    const float* __restrict__ dx, const float* __restrict__ gsw,
    const float* __restrict__ sgw, float* __restrict__ xw_v,
    float* __restrict__ xw2_v, u16* __restrict__ xw2vT) {
  __shared__ float l1[4096], l2[4096], lg[4096], ls[4096];
  __shared__ float lb1[64], lb2[64], lrow[256], lrow2[256];
  int t = threadIdx.x;
  for (int i = t; i < 4096; i += 256) {
    l1[i] = W1[i]; l2[i] = W2[i]; lg[i] = gsw[i]; ls[i] = sgw[i];
  }
  if (t < 64) lb1[t] = b1[t];
  else if (t < 128) lb2[t - 64] = b2[t - 64];
  __syncthreads();
  int wr = t >> 6, c = t & 63;
  int row = blockIdx.x * 4 + wr;
  const float* hr = h1 + (size_t)row * 64;
  float h2 = lb1[c];
  #pragma unroll 8
  for (int k = 0; k < 64; k++) h2 += hr[k] * l1[k * 64 + c];
  h2 = fmaxf(h2, 0.f);
  lrow[wr * 64 + c] = h2;
  __syncthreads();
  float o = lb2[c] + dx[(size_t)row * 64 + c];
  #pragma unroll 8
  for (int k = 0; k < 64; k++) o += lrow[wr * 64 + k] * l2[k * 64 + c];
  lrow2[wr * 64 + c] = o;
  __syncthreads();
  float p = 0.f, q = 0.f;
  #pragma unroll 8
  for (int k = 0; k < 64; k++) {
    float a = lrow2[wr * 64 + k];
    p += a * lg[k * 64 + c];
    q += a * ls[k * 64 + c];
  }
  xw_v[(size_t)row * 64 + c] = p;
  xw2_v[(size_t)row * 64 + c] = q;
  xw2vT[(size_t)c * NV + row] = f2bf(q);
}

// ---------------- fused bipartite combine ----------------
__global__ void k_combine(const float* __restrict__ xw_v, const float* __restrict__ Wbp,
    const float* __restrict__ xw2_v, const float* __restrict__ xw_g,
    const float* __restrict__ WbTp, const float* __restrict__ xw2_g,
    const float* __restrict__ inv_deg_v, const float* __restrict__ rsv,
    const float* __restrict__ inv_deg_g, const float* __restrict__ rsg,
    const float* __restrict__ gsb, const float* __restrict__ sgb,
    float* __restrict__ dx, float* __restrict__ gx) {
  int idx = blockIdx.x * 256 + threadIdx.x;
  if (idx < NV * 64) {
    int v = idx >> 6, c = idx & 63;
    dx[idx] = 0.5f * (xw_v[idx] * inv_deg_v[v] + Wbp[idx] * rsv[v] + gsb[c] + xw2_v[idx] + sgb[c]);
  } else {
    int j = idx - NV * 64;
    int g = j >> 6, c = j & 63;
    gx[j] = 0.5f * (xw_g[j] + gsb[c] + xw2_g[j] * inv_deg_g[g] + WbTp[j] * rsg[g] + sgb[c]);
  }
}

// =================================================================
extern "C" void kernel_launch(void* const* d_in, const int* in_sizes, int n_in,
                              void* d_out, int out_size, void* d_ws, size_t ws_size,
                              hipStream_t stream) {
  const float* vertices  = (const float*)d_in[0];
  const float* graph_pos = (const float*)d_in[1];
  const float* x_in      = (const float*)d_in[2];
  const float* graph_x   = (const float*)d_in[3];
  const float* mass      = (const float*)d_in[4];
  const float* evals     = (const float*)d_in[5];
  const float* evecs     = (const float*)d_in[6];
  const float* gradX     = (const float*)d_in[7];
  const float* gradY     = (const float*)d_in[8];
  const int*   eidx      = (const int*)d_in[9];
  const float* ew        = (const float*)d_in[10];
  const float* lin1_w    = (const float*)d_in[11];
  const float* lin1_b    = (const float*)d_in[12];
  const float* lin2_w    = (const float*)d_in[13];
  const float* lin2_b    = (const float*)d_in[14];
  const float* diff_time = (const float*)d_in[15];
  const float* A_re      = (const float*)d_in[16];
  const float* A_im      = (const float*)d_in[17];
  const float* mlp_w0    = (const float*)d_in[18];
  const float* mlp_b0    = (const float*)d_in[19];
  const float* mlp_w1    = (const float*)d_in[20];
  const float* mlp_b1    = (const float*)d_in[21];
  const float* mlp_w2    = (const float*)d_in[22];
  const float* mlp_b2    = (const float*)d_in[23];
  const float* gcn1_w    = (const float*)d_in[24];
  const float* gcn1_b    = (const float*)d_in[25];
  const float* gcn2_w    = (const float*)d_in[26];
  const float* gcn2_b    = (const float*)d_in[27];
  const float* gs_w      = (const float*)d_in[28];
  const float* gs_b      = (const float*)d_in[29];
  const float* sg_w      = (const float*)d_in[30];
  const float* sg_b      = (const float*)d_in[31];

  char* base = (char*)d_ws;
  size_t off = 0;
  auto alloc = [&](size_t nbytes) -> void* {
    void* p = base + off;
    off += (nbytes + 255) & ~(size_t)255;
    return p;
  };
  const size_t MBy = 1024 * 1024;
  u16*   evecsT  = (u16*)alloc((size_t)128 * NV * 2);
  float* GXE2    = (float*)alloc((size_t)2 * NV * 128 * 4); // GXE | GYE contiguous
  float* GXE     = GXE2;
  float* GYE     = GXE2 + (size_t)NV * 128;
  u16*   mdxT    = (u16*)alloc((size_t)64 * NV * 2);
  float* Es      = (float*)alloc(8192 * 4);
  float* diffx   = (float*)alloc((size_t)NV * 64 * 4);
  float* gxb     = (float*)alloc((size_t)NG * 64 * 4);
  float* xd      = (float*)alloc((size_t)NV * 64 * 4);
  float* gf      = (float*)alloc((size_t)NV * 64 * 4);
  float* h1      = (float*)alloc((size_t)NV * 64 * 4);
  float* xw_v    = (float*)alloc((size_t)NV * 64 * 4);
  float* xw2_v   = (float*)alloc((size_t)NV * 64 * 4);
  float* xw_g    = (float*)alloc((size_t)NG * 64 * 4);
  float* xw2_g   = (float*)alloc((size_t)NG * 64 * 4);
  float* xw1     = (float*)alloc((size_t)NG * 64 * 4);
  float* xw2k    = (float*)alloc((size_t)NG * 64 * 4);
  u16*   xwgT    = (u16*)alloc((size_t)64 * NG * 2);
  u16*   xw2vT   = (u16*)alloc((size_t)64 * NV * 2);
  float* Wbp     = (float*)alloc((size_t)NV * 64 * 4);
  float* WbTp    = (float*)alloc((size_t)NG * 64 * 4);
  float* deg_v   = (float*)alloc(NV * 4);
  float* inv_deg_v = (float*)alloc(NV * 4);
  float* rsv     = (float*)alloc(NV * 4);
  float* deg_g   = (float*)alloc(NG * 4);
  float* inv_deg_g = (float*)alloc(NG * 4);
  float* rsg     = (float*)alloc(NG * 4);
  float* deg_e   = (float*)alloc(NG * 4);
  float* invdeg_e = (float*)alloc(NG * 4);
  float* dinv_e  = (float*)alloc(NG * 4);
  int*   cnt     = (int*)alloc(NG * 4);
  int*   row_ptr = (int*)alloc((NG + 1) * 4);
  int*   cursor  = (int*)alloc(NG * 4);
  int*   csr_src = (int*)alloc(NE * 4);
  float* csr_norm = (float*)alloc(NE * 4);

  size_t avail = ws_size > off ? ws_size - off : 0;
  u16 *WbP = nullptr, *WbTP = nullptr, *WbRow = nullptr;
  float* parts;
  int zsu;
  if (avail >= 162 * MBy) {
    WbP  = (u16*)alloc((size_t)NV * NG * 2);   // 64 MB panels
    WbTP = (u16*)alloc((size_t)NG * NV * 2);   // 64 MB panels
    parts = (float*)alloc(32 * MBy);
    zsu = 4;
  } else if (avail >= 97 * MBy) {
    WbRow = (u16*)alloc((size_t)NV * NG * 2);  // 64 MB row-major fallback
    parts = (float*)alloc(32 * MBy);
    zsu = 4;
  } else {
    WbRow = (u16*)alloc((size_t)NV * NG * 2);
    parts = (float*)alloc(16 * MBy);
    zsu = 2;
  }
  if (off > ws_size) return;  // insufficient workspace -> fail loudly

  dim3 B256(256);

  // ---------- setup ----------
  k_fill4<<<dim3(80), B256, 0, stream>>>(deg_v, deg_g, deg_e, cnt);
  k_wb_build<<<dim3(128, 64), B256, 0, stream>>>(vertices, graph_pos, WbRow, WbP, WbTP, deg_v, deg_g);
  k_edge_prep<<<dim3(256), B256, 0, stream>>>(eidx, ew, deg_e, cnt);
  k_recips<<<dim3(64), B256, 0, stream>>>(deg_v, inv_deg_v, rsv, deg_g, inv_deg_g, rsg,
                                          deg_e, invdeg_e, dinv_e);
  k_scan<<<dim3(1), dim3(1024), 0, stream>>>(cnt, row_ptr, cursor);
  k_scatter<<<dim3(256), B256, 0, stream>>>(eidx, ew, dinv_e, cursor, csr_src, csr_norm);
  k_evecsT<<<dim3(256, 4), B256, 0, stream>>>(evecs, evecsT);
  // GXE = gradX @ evecs, GYE = gradY @ evecs (round-8 proven config)
  gemm_setup3<<<dim3(2 * 32 * zsu), B256, 81920, stream>>>(
      gradX, gradY, evecsT, parts, zsu, 8192 / zsu);
  k_reduce2<<<dim3(2048), B256, 0, stream>>>(parts, GXE2, NV * 128, zsu);
  k_lin_both<<<dim3(3072), B256, 0, stream>>>(x_in, graph_x, lin1_w, lin1_b, lin2_w, lin2_b, diffx, gxb);

  // ---------- 4 blocks ----------
  for (int i = 0; i < 4; i++) {
    const float* dtrow = diff_time + i * 64;
    // merged: mdxT | gcn1 matmul
    k_front<<<dim3(128 + 1024), B256, 0, stream>>>(diffx, mass, mdxT, gxb,
        gcn1_w + i * 4096, xw1);
    // merged: spec GEMM | gcn1 agg + gcn2 matmul
    k_specagg<<<dim3(64 + 1024), B256, 0, stream>>>(evecsT, mdxT, parts,
        xw1, row_ptr, csr_src, csr_norm, invdeg_e, gcn1_b + i * 64,
        gcn2_w + i * 4096, xw2k);
    // merged: reduce+exp | gcn2 agg + graph-side dual projection
    k_redagg<<<dim3(32 + 1024), B256, 0, stream>>>(parts, evals, dtrow, Es,
        xw2k, row_ptr, csr_src, csr_norm, invdeg_e, gcn2_b + i * 64,
        gs_w + i * 4096, sg_w + i * 4096, xw_g, xw2_g, xwgT);
    // xd + gradient features, then mlp0
    k_xdgf<<<dim3(2048), B256, 0, stream>>>(evecs, GXE, GYE, Es, A_re + i * 4096, A_im + i * 4096, xd, gf);
    k_mlp0<<<dim3(2048), B256, 0, stream>>>(diffx, xd, gf, mlp_w0 + i * 12288, mlp_b0 + i * 64, h1);
    // fused mlp12 + vertex-side dual projection (no post-MLP diffx store)
    k_mlp12_dual<<<dim3(2048), B256, 0, stream>>>(h1, mlp_w1 + i * 4096, mlp_b1 + i * 64,
        mlp_w2 + i * 4096, mlp_b2 + i * 64, diffx, gs_w + i * 4096, sg_w + i * 4096,
        xw_v, xw2_v, xw2vT);
    if (WbP != nullptr) {
      // both Wb GEMMs in one launch (blocks 0-511: Wbp, 512-1023: WbTp)
      gemm_panel2<<<dim3(1024), B256, 0, stream>>>(WbP, WbTP, xwgT, xw2vT, parts);
      k_reduce_both<<<dim3(768), B256, 0, stream>>>(parts, Wbp, WbTp);
    } else {
      gemm_bf16<<<dim3(64, 1, 8), B256, 0, stream>>>(WbRow, NG, xwgT, NG, parts, NV, 512);
      k_reduce<<<dim3(512), B256, 0, stream>>>(parts, Wbp, NV * 64, 8);
      gemm_k<64, false, true><<<dim3(32, 1, 16), B256, 0, stream>>>(
          WbRow, nullptr, 1 << 30, xw2vT, parts, NG, 64, NG, NV, 512);
      k_reduce<<<dim3(256), B256, 0, stream>>>(parts, WbTp, NG * 64, 16);
    }
    // fused combine
    k_combine<<<dim3(3072), B256, 0, stream>>>(xw_v, Wbp, xw2_v, xw_g, WbTp, xw2_g,
        inv_deg_v, rsv, inv_deg_g, rsg, gs_b + i * 64, sg_b + i * 64, diffx, gxb);
  }

  hipMemcpyAsync(d_out, diffx, (size_t)NV * 64 * 4, hipMemcpyDeviceToDevice, stream);
}

// Round 14
// 913.205 us; speedup vs baseline: 1.1704x; 1.0331x over previous
//
#include <hip/hip_runtime.h>
#include <hip/hip_bf16.h>

typedef unsigned short u16;
typedef __attribute__((ext_vector_type(8))) short sh8;     // 8 x bf16 (4 VGPRs)
typedef __attribute__((ext_vector_type(4))) float f32x4;   // MFMA accum

#define NV 8192
#define NG 4096
#define NE 65536

__device__ __forceinline__ u16 f2bf(float f) {
  __hip_bfloat16 h = __float2bfloat16(f);
  return __builtin_bit_cast(u16, h);
}

// async global->LDS, 16B per lane; LDS dest = wave-uniform base + lane*16
__device__ __forceinline__ void gl_lds16(const void* g, void* l) {
  __builtin_amdgcn_global_load_lds(
      (const __attribute__((address_space(1))) void*)g,
      (__attribute__((address_space(3))) void*)l, 16, 0, 0);
}

// ---------------- setup fills ----------------
__global__ void k_fill4(float* __restrict__ deg_v, float* __restrict__ deg_g,
                        float* __restrict__ deg_e, int* __restrict__ cnt) {
  int i = blockIdx.x * 256 + threadIdx.x;
  if (i < NV) deg_v[i] = 1.f;
  int j = i - NV;
  if (j >= 0 && j < NG) deg_g[j] = 1.f;
  j -= NG;
  if (j >= 0 && j < NG) deg_e[j] = 1.f;
  j -= NG;
  if (j >= 0 && j < NG) cnt[j] = 0;
}

// ---------------- Wb build ----------------
__global__ __launch_bounds__(256) void k_wb_build(
    const float* __restrict__ vert, const float* __restrict__ gpos,
    u16* __restrict__ WbRow, u16* __restrict__ WbP, u16* __restrict__ WbTP,
    float* __restrict__ deg_v, float* __restrict__ deg_g) {
  __shared__ float lv[192], lg[192], colp[256];
  __shared__ float tile[64][65];
  int t = threadIdx.x;
  int v0 = blockIdx.x * 64, g0 = blockIdx.y * 64;
  if (t < 192) { lv[t] = vert[(size_t)v0 * 3 + t]; lg[t] = gpos[(size_t)g0 * 3 + t]; }
  __syncthreads();
  int w = t >> 6, lane = t & 63;
  float gx_ = lg[lane * 3], gy_ = lg[lane * 3 + 1], gz_ = lg[lane * 3 + 2];
  float csum = 0.f;
  #pragma unroll 4
  for (int s = 0; s < 16; s++) {
    int vl = w + 4 * s;
    float dx = lv[vl * 3] - gx_, dy = lv[vl * 3 + 1] - gy_, dz = lv[vl * 3 + 2] - gz_;
    float d = sqrtf(dx * dx + dy * dy + dz * dz);
    float W = (d < 8.0f) ? expf(d * -0.25f) : 0.f;
    if (WbRow != nullptr) WbRow[(size_t)(v0 + vl) * NG + g0 + lane] = f2bf(W);
    tile[vl][lane] = W;
    csum += W;
  }
  colp[t] = csum;
  __syncthreads();
  int r4 = t >> 2, q = t & 3;
  float rs = 0.f;
  #pragma unroll
  for (int j = 0; j < 16; j++) rs += tile[r4][q * 16 + j];
  rs += __shfl_xor(rs, 1);
  rs += __shfl_xor(rs, 2);
  if (q == 0) atomicAdd(&deg_v[v0 + r4], rs);
  if (w == 0) {
    float tot = colp[lane] + colp[64 + lane] + colp[128 + lane] + colp[192 + lane];
    atomicAdd(&deg_g[g0 + lane], tot);
  }
  if (WbP != nullptr) {
    size_t tb = ((size_t)(v0 >> 7) * 64 + (g0 >> 6)) * 8192;
    #pragma unroll
    for (int j = 0; j < 2; j++) {
      int idx = j * 256 + t;
      int vr = idx >> 3, k8 = (idx & 7) * 8;
      u16 pk[8];
      #pragma unroll
      for (int qq = 0; qq < 8; qq++) pk[qq] = f2bf(tile[vr][k8 + qq]);
      int r = (v0 & 64) + vr;
      *(uint4*)&WbP[tb + (size_t)r * 64 + (size_t)(((k8 >> 3) ^ (r & 7)) << 3)] = *(uint4*)pk;
    }
  }
  if (WbTP != nullptr) {
    size_t tb = ((size_t)(g0 >> 7) * 128 + (v0 >> 6)) * 8192;
    #pragma unroll
    for (int j = 0; j < 2; j++) {
      int idx = j * 256 + t;
      int gr = idx >> 3, v8 = (idx & 7) * 8;
      u16 pk[8];
      #pragma unroll
      for (int qq = 0; qq < 8; qq++) pk[qq] = f2bf(tile[v8 + qq][gr]);
      int r = (g0 & 64) + gr;
      *(uint4*)&WbTP[tb + (size_t)r * 64 + (size_t)(((v8 >> 3) ^ (r & 7)) << 3)] = *(uint4*)pk;
    }
  }
}

// all three recips in one launch
__global__ void k_recips(const float* __restrict__ deg_v, float* __restrict__ inv_v,
                         float* __restrict__ rs_v, const float* __restrict__ deg_g,
                         float* __restrict__ inv_g, float* __restrict__ rs_g,
                         const float* __restrict__ deg_e, float* __restrict__ inv_e,
                         float* __restrict__ rs_e) {
  int i = blockIdx.x * 256 + threadIdx.x;
  if (i < NV) { float d = deg_v[i]; inv_v[i] = 1.f / d; rs_v[i] = 1.f / sqrtf(d); }
  else if (i < NV + NG) {
    int j = i - NV; float d = deg_g[j]; inv_g[j] = 1.f / d; rs_g[j] = 1.f / sqrtf(d);
  } else if (i < NV + 2 * NG) {
    int j = i - NV - NG; float d = deg_e[j]; inv_e[j] = 1.f / d; rs_e[j] = 1.f / sqrtf(d);
  }
}

// ---------------- edge preprocessing (CSR) ----------------
__global__ void k_edge_prep(const int* __restrict__ eidx, const float* __restrict__ ew,
                            float* __restrict__ deg_e, int* __restrict__ cnt) {
  int e = blockIdx.x * 256 + threadIdx.x;
  if (e < NE) { int d = eidx[NE + e]; atomicAdd(&deg_e[d], ew[e]); atomicAdd(&cnt[d], 1); }
}

__global__ __launch_bounds__(1024) void k_scan(const int* __restrict__ cnt,
    int* __restrict__ row_ptr, int* __restrict__ cursor) {
  __shared__ int buf0[1024], buf1[1024];
  int t = threadIdx.x;
  int b = t * 4;
  int c0 = cnt[b], c1 = cnt[b + 1], c2 = cnt[b + 2], c3 = cnt[b + 3];
  int s = c0 + c1 + c2 + c3;
  buf0[t] = s;
  __syncthreads();
  int* src = buf0; int* dst = buf1;
  for (int off = 1; off < 1024; off <<= 1) {
    int v = src[t];
    if (t >= off) v += src[t - off];
    dst[t] = v;
    __syncthreads();
    int* tmp = src; src = dst; dst = tmp;
  }
  int excl = (t == 0) ? 0 : src[t - 1];
  int r0 = excl, r1 = excl + c0, r2 = excl + c0 + c1, r3 = excl + c0 + c1 + c2;
  row_ptr[b] = r0; row_ptr[b + 1] = r1; row_ptr[b + 2] = r2; row_ptr[b + 3] = r3;
  cursor[b] = r0; cursor[b + 1] = r1; cursor[b + 2] = r2; cursor[b + 3] = r3;
  if (t == 1023) row_ptr[4096] = src[1023];
}

__global__ void k_scatter(const int* __restrict__ eidx, const float* __restrict__ ew,
                          const float* __restrict__ dinv, int* __restrict__ cursor,
                          int* __restrict__ csrc, float* __restrict__ cnorm) {
  int e = blockIdx.x * 256 + threadIdx.x;
  if (e < NE) {
    int s = eidx[e], d = eidx[NE + e];
    int slot = atomicAdd(&cursor[d], 1);
    csrc[slot] = s;
    cnorm[slot] = dinv[s] * ew[e] * dinv[d];
  }
}

// ---------------- evecs -> bf16 transposed [128][NV] ----------------
__global__ __launch_bounds__(256) void k_evecsT(const float* __restrict__ ev, u16* __restrict__ evT) {
  __shared__ float tile[32][33];
  int t = threadIdx.x;
  int v0 = blockIdx.x * 32, k0 = blockIdx.y * 32;
  int r = t >> 3, c4 = (t & 7) * 4;
  float4 x = *(const float4*)(ev + (size_t)(v0 + r) * 128 + k0 + c4);
  tile[r][c4] = x.x; tile[r][c4 + 1] = x.y; tile[r][c4 + 2] = x.z; tile[r][c4 + 3] = x.w;
  __syncthreads();
  u16* dst = evT + (size_t)(k0 + r) * NV + v0 + c4;
  dst[0] = f2bf(tile[c4][r]); dst[1] = f2bf(tile[c4 + 1][r]);
  dst[2] = f2bf(tile[c4 + 2][r]); dst[3] = f2bf(tile[c4 + 3][r]);
}

// =============== setup GEMM: BM=256/BN=128/BK=32, double-buffered ===========
__global__ __launch_bounds__(256) void gemm_setup3(
    const float* __restrict__ gXm, const float* __restrict__ gYm,
    const u16* __restrict__ evT, float* __restrict__ parts,
    int z, int kchunk) {
  extern __shared__ __align__(16) char smem[];   // 2 x (A 32KB + B 8KB)
  const int t = threadIdx.x;
  const int lane = t & 63, wave = t >> 6;
  const int rl = lane & 15, hi = lane >> 4;
  int b = blockIdx.x;
  const int zi = b % z; b /= z;
  const int mb = b & 31;
  const int mat = b >> 5;
  const float* A = mat ? gYm : gXm;
  const int m0 = mb * 256;
  const int kbeg = zi * kchunk;
  const int nt = kchunk >> 5;
  const int wm = wave * 64;

  f32x4 acc[4][8];
  #pragma unroll
  for (int a = 0; a < 4; a++)
    #pragma unroll
    for (int bb = 0; bb < 8; bb++) acc[a][bb] = f32x4{0.f, 0.f, 0.f, 0.f};

  auto STAGE = [&](int buf, int k0) {   // exactly 10 gl_lds16 per wave
    char* aB = smem + buf * 40960;
    #pragma unroll
    for (int jj = 0; jj < 8; jj++) {
      int R0 = wave * 64 + jj * 8;
      int r = R0 + (lane >> 3);
      int s = lane & 7;
      gl_lds16(A + (size_t)(m0 + r) * NV + k0 + ((s ^ (r & 7)) << 2), aB + R0 * 128);
    }
    char* bB = smem + buf * 40960 + 32768;
    #pragma unroll
    for (int jj = 0; jj < 2; jj++) {
      int R0 = wave * 32 + jj * 16;
      int n = R0 + (lane >> 2);
      int s = lane & 3;
      gl_lds16(evT + (size_t)n * NV + k0 + ((s ^ ((n >> 1) & 3)) << 3), bB + R0 * 64);
    }
  };

  auto COMPUTE = [&](int buf) {
    const float* Af = (const float*)(smem + buf * 40960);
    const u16* Bf = (const u16*)(smem + buf * 40960 + 32768);
    sh8 av[4], bv[8];
    #pragma unroll
    for (int mf = 0; mf < 4; mf++) {
      int r = wm + mf * 16 + rl;
      f32x4 lo = *(const f32x4*)(Af + r * 32 + (((2 * hi) ^ (r & 7)) << 2));
      f32x4 h4 = *(const f32x4*)(Af + r * 32 + (((2 * hi + 1) ^ (r & 7)) << 2));
      sh8 v;
      v[0] = (short)f2bf(lo[0]); v[1] = (short)f2bf(lo[1]);
      v[2] = (short)f2bf(lo[2]); v[3] = (short)f2bf(lo[3]);
      v[4] = (short)f2bf(h4[0]); v[5] = (short)f2bf(h4[1]);
      v[6] = (short)f2bf(h4[2]); v[7] = (short)f2bf(h4[3]);
      av[mf] = v;
    }
    #pragma unroll
    for (int nf = 0; nf < 8; nf++) {
      int n = nf * 16 + rl;
      bv[nf] = *(const sh8*)(Bf + n * 32 + ((hi ^ ((n >> 1) & 3)) << 3));
    }
    #pragma unroll
    for (int mf = 0; mf < 4; mf++)
      #pragma unroll
      for (int nf = 0; nf < 8; nf++)
        acc[mf][nf] = __builtin_amdgcn_mfma_f32_16x16x32_bf16(av[mf], bv[nf], acc[mf][nf], 0, 0, 0);
  };

  STAGE(0, kbeg);
  if (nt > 1) STAGE(1, kbeg + 32);
  for (int ti = 0; ti < nt; ti++) {
    if (ti + 1 < nt) { asm volatile("s_waitcnt vmcnt(10)" ::: "memory"); }
    else             { asm volatile("s_waitcnt vmcnt(0)" ::: "memory"); }
    __builtin_amdgcn_sched_barrier(0);
    __builtin_amdgcn_s_barrier();
    COMPUTE(ti & 1);
    __builtin_amdgcn_sched_barrier(0);
    __builtin_amdgcn_s_barrier();
    if (ti + 2 < nt) STAGE(ti & 1, kbeg + (ti + 2) * 32);
  }

  float* C = parts + (size_t)(mat * z + zi) * (NV * 128);
  #pragma unroll
  for (int mf = 0; mf < 4; mf++)
    #pragma unroll
    for (int nf = 0; nf < 8; nf++) {
      int row = m0 + wm + mf * 16 + hi * 4;
      int col = nf * 16 + rl;
      #pragma unroll
      for (int q = 0; q < 4; q++)
        C[(size_t)(row + q) * 128 + col] = acc[mf][nf][q];
    }
}

// =============== merged panel GEMM: blocks [0,512) Wbp, [512,1024) WbTp ====
__global__ __launch_bounds__(256) void gemm_panel2(
    const u16* __restrict__ WbP, const u16* __restrict__ WbTP,
    const u16* __restrict__ xwgT, const u16* __restrict__ xw2vT,
    float* __restrict__ parts) {
  __shared__ __align__(16) char smem[49152];   // 2 x (A 16KB + B 8KB)
  const int t = threadIdx.x;
  const int lane = t & 63, wave = t >> 6;
  const int rl = lane & 15, hi = lane >> 4;
  int bid = blockIdx.x;
  const u16* Apan; const u16* BT; int KT, ldbt, mb, z;
  float* Cbase;
  if (bid < 512) {
    Apan = WbP; BT = xwgT; KT = 64; ldbt = NG;
    mb = bid >> 3; z = bid & 7;
    Cbase = parts + (size_t)z * NV * 64;
  } else {
    bid -= 512;
    Apan = WbTP; BT = xw2vT; KT = 128; ldbt = NV;
    mb = bid >> 4; z = bid & 15;
    Cbase = parts + (size_t)8 * NV * 64 + (size_t)z * NG * 64;
  }
  const int ktpz = 8;
  const int kt0 = z * ktpz;
  const int wm = wave * 32;

  f32x4 acc[2][4];
  #pragma unroll
  for (int a = 0; a < 2; a++)
    #pragma unroll
    for (int b = 0; b < 4; b++) acc[a][b] = f32x4{0.f, 0.f, 0.f, 0.f};

  auto STAGE = [&](int buf, int kt) {   // exactly 6 gl_lds16 per wave
    char* aB = smem + buf * 24576;
    const u16* tbase = Apan + ((size_t)mb * KT + kt) * 8192;
    #pragma unroll
    for (int jj = 0; jj < 4; jj++) {
      int j = wave * 4 + jj;
      gl_lds16(tbase + j * 512 + lane * 8, aB + j * 1024);
    }
    char* bB = aB + 16384;
    #pragma unroll
    for (int jj = 0; jj < 2; jj++) {
      int j = wave * 2 + jj;
      int n = 8 * j + (lane >> 3);
      const u16* srcb = BT + (size_t)n * ldbt + kt * 64 + (((lane & 7) ^ (n & 7)) << 3);
      gl_lds16(srcb, bB + j * 1024);
    }
  };

  auto COMPUTE = [&](int buf) {
    const u16* Af = (const u16*)(smem + buf * 24576);
    const u16* Bf = Af + 8192;
    #pragma unroll
    for (int step = 0; step < 2; step++) {
      sh8 av[2], bv[4];
      int s = step * 4 + hi;
      #pragma unroll
      for (int mf = 0; mf < 2; mf++) {
        int r = wm + mf * 16 + rl;
        av[mf] = *(const sh8*)(Af + r * 64 + ((s ^ (r & 7)) << 3));
      }
      #pragma unroll
      for (int nf = 0; nf < 4; nf++) {
        int n = nf * 16 + rl;
        bv[nf] = *(const sh8*)(Bf + n * 64 + ((s ^ (n & 7)) << 3));
      }
      #pragma unroll
      for (int mf = 0; mf < 2; mf++)
        #pragma unroll
        for (int nf = 0; nf < 4; nf++)
          acc[mf][nf] = __builtin_amdgcn_mfma_f32_16x16x32_bf16(av[mf], bv[nf], acc[mf][nf], 0, 0, 0);
    }
  };

  STAGE(0, kt0);
  STAGE(1, kt0 + 1);
  for (int ti = 0; ti < ktpz; ti++) {
    if (ti + 1 < ktpz) { asm volatile("s_waitcnt vmcnt(6)" ::: "memory"); }
    else               { asm volatile("s_waitcnt vmcnt(0)" ::: "memory"); }
    __builtin_amdgcn_sched_barrier(0);
    __builtin_amdgcn_s_barrier();
    COMPUTE(ti & 1);
    __builtin_amdgcn_sched_barrier(0);
    __builtin_amdgcn_s_barrier();
    if (ti + 2 < ktpz) STAGE(ti & 1, kt0 + ti + 2);
  }

  #pragma unroll
  for (int mf = 0; mf < 2; mf++)
    #pragma unroll
    for (int nf = 0; nf < 4; nf++) {
      int row = mb * 128 + wm + mf * 16 + hi * 4;
      int col = nf * 16 + rl;
      #pragma unroll
      for (int q = 0; q < 4; q++)
        Cbase[(size_t)(row + q) * 64 + col] = acc[mf][nf][q];
    }
}

// fused: reduce panel slices + bipartite combine (Wbp/WbTp never materialized)
__global__ void k_reduce_combine(const float* __restrict__ parts,
    const float* __restrict__ xw_v, const float* __restrict__ xw2_v,
    const float* __restrict__ xw_g, const float* __restrict__ xw2_g,
    const float* __restrict__ inv_deg_v, const float* __restrict__ rsv,
    const float* __restrict__ inv_deg_g, const float* __restrict__ rsg,
    const float* __restrict__ gsb, const float* __restrict__ sgb,
    float* __restrict__ dx, float* __restrict__ gx) {
  int idx = blockIdx.x * 256 + threadIdx.x;
  if (idx < NV * 64) {
    float s = parts[idx];
    #pragma unroll
    for (int z = 1; z < 8; z++) s += parts[(size_t)z * NV * 64 + idx];
    int v = idx >> 6, c = idx & 63;
    dx[idx] = 0.5f * (xw_v[idx] * inv_deg_v[v] + s * rsv[v] + gsb[c] + xw2_v[idx] + sgb[c]);
  } else {
    int j = idx - NV * 64;
    const float* src = parts + (size_t)8 * NV * 64;
    float s = src[j];
    #pragma unroll
    for (int z = 1; z < 16; z++) s += src[(size_t)z * NG * 64 + j];
    int g = j >> 6, c = j & 63;
    gx[j] = 0.5f * (xw_g[j] + gsb[c] + xw2_g[j] * inv_deg_g[g] + s * rsg[g] + sgb[c]);
  }
}

// =============== generic bf16 GEMM (row-tier Wb fallback), BM=128, BN=64 ====
__global__ __launch_bounds__(256) void gemm_bf16(
    const u16* __restrict__ Ab, int lda, const u16* __restrict__ BT, int ldbt,
    float* __restrict__ parts, int M, int kchunk) {
  __shared__ __align__(16) char smem[49152];
  const int t = threadIdx.x;
  const int lane = t & 63, wave = t >> 6;
  const int m0 = blockIdx.x * 128;
  const int kbeg = blockIdx.z * kchunk;
  const int nt = kchunk >> 6;
  const int wm = (wave >> 1) * 64, wn = (wave & 1) * 32;
  const int arl = lane >> 3, asl = lane & 7;

  f32x4 acc[4][2];
  #pragma unroll
  for (int a = 0; a < 4; a++)
    #pragma unroll
    for (int b = 0; b < 2; b++) acc[a][b] = f32x4{0.f, 0.f, 0.f, 0.f};

  auto STAGE = [&](int buf, int k0) {
    char* base = smem + buf * 24576;
    #pragma unroll
    for (int j = 0; j < 4; j++) {
      int R0 = (wave * 4 + j) * 8;
      int r = R0 + arl;
      int gs = asl ^ (r & 7);
      gl_lds16(Ab + (size_t)(m0 + r) * lda + k0 + gs * 8, base + R0 * 128);
    }
    char* bb = base + 16384;
    #pragma unroll
    for (int j = 0; j < 2; j++) {
      int R0 = (wave * 2 + j) * 8;
      int r = R0 + arl;
      int gs = asl ^ (r & 7);
      gl_lds16(BT + (size_t)r * ldbt + k0 + gs * 8, bb + R0 * 128);
    }
  };

  auto COMPUTE = [&](int buf) {
    char* base = smem + buf * 24576;
    const u16* Af = (const u16*)base;
    const u16* Bf = (const u16*)(base + 16384);
    #pragma unroll
    for (int kk = 0; kk < 2; kk++) {
      sh8 av[4], bv[2];
      #pragma unroll
      for (int mf = 0; mf < 4; mf++) {
        int r = wm + mf * 16 + (lane & 15);
        int g = kk * 4 + (lane >> 4);
        av[mf] = *(const sh8*)(Af + r * 64 + (g ^ (r & 7)) * 8);
      }
      #pragma unroll
      for (int nf = 0; nf < 2; nf++) {
        int r = wn + nf * 16 + (lane & 15);
        int g = kk * 4 + (lane >> 4);
        bv[nf] = *(const sh8*)(Bf + r * 64 + (g ^ (r & 7)) * 8);
      }
      #pragma unroll
      for (int mf = 0; mf < 4; mf++)
        #pragma unroll
        for (int nf = 0; nf < 2; nf++)
          acc[mf][nf] = __builtin_amdgcn_mfma_f32_16x16x32_bf16(av[mf], bv[nf], acc[mf][nf], 0, 0, 0);
    }
  };

  STAGE(0, kbeg);
  if (nt > 1) STAGE(1, kbeg + 64);
  for (int ti = 0; ti < nt; ti++) {
    if (ti + 1 < nt) { asm volatile("s_waitcnt vmcnt(6)" ::: "memory"); }
    else             { asm volatile("s_waitcnt vmcnt(0)" ::: "memory"); }
    __builtin_amdgcn_sched_barrier(0);
    __builtin_amdgcn_s_barrier();
    COMPUTE(ti & 1);
    __builtin_amdgcn_sched_barrier(0);
    __builtin_amdgcn_s_barrier();
    if (ti + 2 < nt) STAGE(ti & 1, kbeg + (ti + 2) * 64);
  }

  float* C = parts + (size_t)blockIdx.z * M * 64;
  #pragma unroll
  for (int mf = 0; mf < 4; mf++)
    #pragma unroll
    for (int nf = 0; nf < 2; nf++) {
      int row = m0 + wm + mf * 16 + (lane >> 4) * 4;
      int col = wn + nf * 16 + (lane & 15);
      #pragma unroll
      for (int q = 0; q < 4; q++)
        C[(size_t)(row + q) * 64 + col] = acc[mf][nf][q];
    }
}

// ---------------- ATRANS fallback GEMM (low-ws WbT path) ----------------
template<int BN, bool AF32, bool ATRANS>
__global__ __launch_bounds__(256) void gemm_k(
    const void* __restrict__ Aptr, const void* __restrict__ A2, int zsplit2,
    const u16* __restrict__ BT, float* __restrict__ Cpart,
    int M, int N, int lda, int ldbt, int kchunk) {
  constexpr int NF = BN / 32;
  __shared__ u16 lA[128 * 40];
  __shared__ u16 lB[BN * 40];
  const int t = threadIdx.x;
  const int m0 = blockIdx.x * 128, n0 = blockIdx.y * BN;
  const void* Ause = Aptr;
  int kz = blockIdx.z;
  if (A2 != nullptr && kz >= zsplit2) { Ause = A2; kz -= zsplit2; }
  const int kbeg = kz * kchunk;
  const int lane = t & 63, wave = t >> 6;
  const int wm = (wave >> 1) * 64, wn = (wave & 1) * (BN / 2);
  f32x4 zero = {0.f, 0.f, 0.f, 0.f};
  f32x4 acc[4][NF];
  #pragma unroll
  for (int a = 0; a < 4; a++)
    #pragma unroll
    for (int b = 0; b < NF; b++) acc[a][b] = zero;

  for (int k0 = kbeg; k0 < kbeg + kchunk; k0 += 32) {
    if constexpr (!ATRANS) {
      const int r = t >> 1, cc = (t & 1) * 16;
      const u16* A = (const u16*)Ause + (size_t)(m0 + r) * lda + k0 + cc;
      *(uint4*)&lA[r * 40 + cc] = *(const uint4*)A;
      *(uint4*)&lA[r * 40 + cc + 8] = *(const uint4*)(A + 8);
    } else {
      const int kl = t >> 3, mb = (t & 7) * 16;
      const u16* A = (const u16*)Ause + (size_t)(k0 + kl) * lda + m0 + mb;
      u16 vals[16];
      *(uint4*)&vals[0] = *(const uint4*)A;
      *(uint4*)&vals[8] = *(const uint4*)(A + 8);
      #pragma unroll
      for (int j = 0; j < 16; j++) lA[(mb + j) * 40 + kl] = vals[j];
    }
    if constexpr (BN == 64) {
      const int r = t >> 2, cc = (t & 3) * 8;
      const u16* B = BT + (size_t)(n0 + r) * ldbt + k0 + cc;
      *(uint4*)&lB[r * 40 + cc] = *(const uint4*)B;
    } else {
      const int r = t >> 1, cc = (t & 1) * 16;
      const u16* B = BT + (size_t)(n0 + r) * ldbt + k0 + cc;
      *(uint4*)&lB[r * 40 + cc] = *(const uint4*)B;
      *(uint4*)&lB[r * 40 + cc + 8] = *(const uint4*)(B + 8);
    }
    __syncthreads();
    sh8 af[4], bfv[NF];
    #pragma unroll
    for (int mf = 0; mf < 4; mf++)
      af[mf] = *(const sh8*)&lA[(wm + mf * 16 + (lane & 15)) * 40 + (lane >> 4) * 8];
    #pragma unroll
    for (int nf = 0; nf < NF; nf++)
      bfv[nf] = *(const sh8*)&lB[(wn + nf * 16 + (lane & 15)) * 40 + (lane >> 4) * 8];
    #pragma unroll
    for (int mf = 0; mf < 4; mf++)
      #pragma unroll
      for (int nf = 0; nf < NF; nf++)
        acc[mf][nf] = __builtin_amdgcn_mfma_f32_16x16x32_bf16(af[mf], bfv[nf], acc[mf][nf], 0, 0, 0);
    __syncthreads();
  }
  float* C = Cpart + (size_t)blockIdx.z * M * N;
  #pragma unroll
  for (int mf = 0; mf < 4; mf++)
    #pragma unroll
    for (int nf = 0; nf < NF; nf++) {
      const int row = m0 + wm + mf * 16 + (lane >> 4) * 4;
      const int col = n0 + wn + nf * 16 + (lane & 15);
      #pragma unroll
      for (int q = 0; q < 4; q++)
        C[(size_t)(row + q) * N + col] = acc[mf][nf][q];
    }
}

__global__ void k_reduce(const float* __restrict__ parts, float* __restrict__ dst, int len, int nz) {
  int i = (blockIdx.x * 256 + threadIdx.x) * 4;
  if (i >= len) return;
  float4 s = *(const float4*)(parts + i);
  for (int z = 1; z < nz; z++) {
    float4 v = *(const float4*)(parts + (size_t)z * len + i);
    s.x += v.x; s.y += v.y; s.z += v.z; s.w += v.w;
  }
  *(float4*)(dst + i) = s;
}

// two matrices packed: dst[mat*len + j] = sum_z parts[(mat*nz+z)*len + j]
__global__ void k_reduce2(const float* __restrict__ parts, float* __restrict__ dst, int len, int nz) {
  int i = (blockIdx.x * 256 + threadIdx.x) * 4;
  if (i >= 2 * len) return;
  int mat = i / len, j = i - mat * len;
  const float* src = parts + (size_t)mat * nz * len + j;
  float4 s = *(const float4*)src;
  for (int z = 1; z < nz; z++) {
    float4 v = *(const float4*)(src + (size_t)z * len);
    s.x += v.x; s.y += v.y; s.z += v.z; s.w += v.w;
  }
  *(float4*)(dst + i) = s;
}

// ---------------- fused lin1/lin2 (C_IN=128 -> DW=64) ----------------
__global__ __launch_bounds__(256) void k_lin_both(const float* __restrict__ x_in,
    const float* __restrict__ graph_x, const float* __restrict__ W1,
    const float* __restrict__ b1, const float* __restrict__ W2,
    const float* __restrict__ b2, float* __restrict__ outV, float* __restrict__ outG) {
  __shared__ float lW[8192];
  __shared__ float lb[64];
  int bb = blockIdx.x;
  bool isV = bb < 2048;
  const float* W = isV ? W1 : W2;
  const float* bi = isV ? b1 : b2;
  const float* A = isV ? x_in : graph_x;
  float* out = isV ? outV : outG;
  int rb = isV ? bb : bb - 2048;
  int t = threadIdx.x;
  for (int i = t; i < 8192; i += 256) lW[i] = W[i];
  if (t < 64) lb[t] = bi[t];
  __syncthreads();
  int row = rb * 4 + (t >> 6), c = t & 63;
  const float* Ar = A + (size_t)row * 128;
  float acc = lb[c];
  #pragma unroll 8
  for (int k = 0; k < 128; k++) acc += Ar[k] * lW[k * 64 + c];
  out[(size_t)row * 64 + c] = acc;
}

// ====== merged launch 1: mdxT (blocks 0..127) | gcn1 matmul (128..1151) =====
__global__ __launch_bounds__(256) void k_front(
    const float* __restrict__ dx, const float* __restrict__ mass,
    u16* __restrict__ mdxT, const float* __restrict__ gxb,
    const float* __restrict__ W, float* __restrict__ xw1) {
  __shared__ __align__(16) char shm[16896];
  int t = threadIdx.x;
  int bid = blockIdx.x;
  if (bid < 128) {
    float (*tile)[65] = (float(*)[65])shm;
    float* lm = (float*)(shm + 16640);
    int v0 = bid * 64;
    if (t < 64) lm[t] = mass[v0 + t];
    #pragma unroll
    for (int i = 0; i < 16; i++) {
      int idx = i * 256 + t;
      int r = idx >> 6, c = idx & 63;
      tile[r][c] = dx[(size_t)(v0 + r) * 64 + c];
    }
    __syncthreads();
    int c = t >> 2;
    #pragma unroll
    for (int i = 0; i < 2; i++) {
      int vq = (t & 3) * 16 + i * 8;
      u16 pk[8];
      #pragma unroll
      for (int q = 0; q < 8; q++) pk[q] = f2bf(lm[vq + q] * tile[vq + q][c]);
      *(uint4*)&mdxT[(size_t)c * NV + v0 + vq] = *(uint4*)pk;
    }
  } else {
    float* lW = (float*)shm;
    int rb = bid - 128;
    for (int i = t; i < 4096; i += 256) lW[i] = W[i];
    __syncthreads();
    int row = rb * 4 + (t >> 6), c = t & 63;
    const float* Ar = gxb + (size_t)row * 64;
    float acc = 0.f;
    #pragma unroll 8
    for (int k = 0; k < 64; k++) acc += Ar[k] * lW[k * 64 + c];
    xw1[(size_t)row * 64 + c] = acc;
  }
}

// ====== merged launch 2: spec GEMM (blocks 0..63) | gcn1 agg+W2 (64..1087) ==
__global__ __launch_bounds__(256) void k_specagg(
    const u16* __restrict__ evT, const u16* __restrict__ mdxT,
    float* __restrict__ parts,
    const float* __restrict__ xw, const int* __restrict__ rp,
    const int* __restrict__ csrc, const float* __restrict__ cnorm,
    const float* __restrict__ invdeg, const float* __restrict__ b1,
    const float* __restrict__ W2, float* __restrict__ out) {
  __shared__ __align__(16) char smem[49152];
  const int t = threadIdx.x;
  if (blockIdx.x < 64) {
    const int lane = t & 63, wave = t >> 6;
    const int kbeg = blockIdx.x * 128;
    const int wm = (wave >> 1) * 64, wn = (wave & 1) * 32;
    const int arl = lane >> 3, asl = lane & 7;
    f32x4 acc[4][2];
    #pragma unroll
    for (int a = 0; a < 4; a++)
      #pragma unroll
      for (int b = 0; b < 2; b++) acc[a][b] = f32x4{0.f, 0.f, 0.f, 0.f};
    auto STAGE = [&](int buf, int k0) {
      char* base = smem + buf * 24576;
      #pragma unroll
      for (int j = 0; j < 4; j++) {
        int R0 = (wave * 4 + j) * 8;
        int r = R0 + arl;
        int gs = asl ^ (r & 7);
        gl_lds16(evT + (size_t)r * NV + k0 + gs * 8, base + R0 * 128);
      }
      char* bb = base + 16384;
      #pragma unroll
      for (int j = 0; j < 2; j++) {
        int R0 = (wave * 2 + j) * 8;
        int r = R0 + arl;
        int gs = asl ^ (r & 7);
        gl_lds16(mdxT + (size_t)r * NV + k0 + gs * 8, bb + R0 * 128);
      }
    };
    auto COMPUTE = [&](int buf) {
      char* base = smem + buf * 24576;
      const u16* Af = (const u16*)base;
      const u16* Bf = (const u16*)(base + 16384);
      #pragma unroll
      for (int kk = 0; kk < 2; kk++) {
        sh8 av[4], bv[2];
        #pragma unroll
        for (int mf = 0; mf < 4; mf++) {
          int r = wm + mf * 16 + (lane & 15);
          int g = kk * 4 + (lane >> 4);
          av[mf] = *(const sh8*)(Af + r * 64 + (g ^ (r & 7)) * 8);
        }
        #pragma unroll
        for (int nf = 0; nf < 2; nf++) {
          int r = wn + nf * 16 + (lane & 15);
          int g = kk * 4 + (lane >> 4);
          bv[nf] = *(const sh8*)(Bf + r * 64 + (g ^ (r & 7)) * 8);
        }
        #pragma unroll
        for (int mf = 0; mf < 4; mf++)
          #pragma unroll
          for (int nf = 0; nf < 2; nf++)
            acc[mf][nf] = __builtin_amdgcn_mfma_f32_16x16x32_bf16(av[mf], bv[nf], acc[mf][nf], 0, 0, 0);
      }
    };
    STAGE(0, kbeg);
    STAGE(1, kbeg + 64);
    for (int ti = 0; ti < 2; ti++) {
      if (ti == 0) { asm volatile("s_waitcnt vmcnt(6)" ::: "memory"); }
      else         { asm volatile("s_waitcnt vmcnt(0)" ::: "memory"); }
      __builtin_amdgcn_sched_barrier(0);
      __builtin_amdgcn_s_barrier();
      COMPUTE(ti);
      __builtin_amdgcn_sched_barrier(0);
      __builtin_amdgcn_s_barrier();
    }
    float* C = parts + (size_t)blockIdx.x * 8192;
    const int lane2 = t & 63;
    #pragma unroll
    for (int mf = 0; mf < 4; mf++)
      #pragma unroll
      for (int nf = 0; nf < 2; nf++) {
        int row = wm + mf * 16 + (lane2 >> 4) * 4;
        int col = wn + nf * 16 + (lane2 & 15);
        #pragma unroll
        for (int q = 0; q < 4; q++)
          C[(size_t)(row + q) * 64 + col] = acc[mf][nf][q];
      }
  } else {
    float* lrow = (float*)smem;
    int g = (blockIdx.x - 64) * 4 + (t >> 6), c = t & 63;
    float acc = xw[(size_t)g * 64 + c] * invdeg[g] + b1[c];
    int j1 = rp[g + 1];
    for (int j = rp[g]; j < j1; j++) acc += cnorm[j] * xw[(size_t)csrc[j] * 64 + c];
    acc = fmaxf(acc, 0.f);
    lrow[t] = acc;
    __syncthreads();
    int grp = t & 192;
    float o = 0.f;
    #pragma unroll 8
    for (int k = 0; k < 64; k++) o += lrow[grp + k] * W2[k * 64 + c];
    out[(size_t)g * 64 + c] = o;
  }
}

// ====== merged launch 3: reduce_es (blocks 0..31) | gcn2 agg+dual (32..1055)
__global__ __launch_bounds__(256) void k_redagg(
    const float* __restrict__ parts, const float* __restrict__ evals,
    const float* __restrict__ dt, float* __restrict__ Es,
    const float* __restrict__ xw, const int* __restrict__ rp,
    const int* __restrict__ csrc, const float* __restrict__ cnorm,
    const float* __restrict__ invdeg, const float* __restrict__ b2,
    const float* __restrict__ gsw, const float* __restrict__ sgw,
    float* __restrict__ xw_g, float* __restrict__ xw2_g, u16* __restrict__ xwgT) {
  __shared__ float lrow[256];
  int t = threadIdx.x;
  if (blockIdx.x < 32) {
    int i = blockIdx.x * 256 + t;
    float s = 0.f;
    #pragma unroll 8
    for (int z = 0; z < 64; z++) s += parts[(size_t)z * 8192 + i];
    int k = i >> 6, c = i & 63;
    Es[i] = expf(-evals[k] * fmaxf(dt[c], 1e-8f)) * s;
  } else {
    int g = (blockIdx.x - 32) * 4 + (t >> 6), c = t & 63;
    float acc = xw[(size_t)g * 64 + c] * invdeg[g] + b2[c];
    int j1 = rp[g + 1];
    for (int j = rp[g]; j < j1; j++) acc += cnorm[j] * xw[(size_t)csrc[j] * 64 + c];
    lrow[t] = acc;
    __syncthreads();
    int grp = t & 192;
    float p = 0.f, q = 0.f;
    #pragma unroll 8
    for (int k = 0; k < 64; k++) {
      float r = lrow[grp + k];
      p += r * gsw[k * 64 + c];
      q += r * sgw[k * 64 + c];
    }
    xw_g[(size_t)g * 64 + c] = p;
    xw2_g[(size_t)g * 64 + c] = q;
    xwgT[(size_t)c * NG + g] = f2bf(p);
  }
}

// ---------------- fused xd + gradient features (8 rows/block) ----------------
__global__ __launch_bounds__(256) void k_xdgf(const float* __restrict__ evecs,
    const float* __restrict__ GXE, const float* __restrict__ GYE,
    const float* __restrict__ Es, const float* __restrict__ Are,
    const float* __restrict__ Aim, float* __restrict__ xd, float* __restrict__ gf) {
  __shared__ float lE[8192];
  __shared__ float lr[4096], li[4096];
  __shared__ float lgx[256], lgy[256];
  int t = threadIdx.x;
  for (int i = t; i < 8192; i += 256) lE[i] = Es[i];
  for (int i = t; i < 4096; i += 256) { lr[i] = Are[i]; li[i] = Aim[i]; }
  __syncthreads();
  int wr = t >> 6, c = t & 63;
  #pragma unroll
  for (int rg = 0; rg < 2; rg++) {
    int row = blockIdx.x * 8 + rg * 4 + wr;
    const float* er = evecs + (size_t)row * 128;
    const float* xr = GXE + (size_t)row * 128;
    const float* yr = GYE + (size_t)row * 128;
    float a0 = 0, a1 = 0, a2 = 0;
    #pragma unroll 8
    for (int k = 0; k < 128; k++) {
      float s = lE[k * 64 + c];
      a0 += er[k] * s; a1 += xr[k] * s; a2 += yr[k] * s;
    }
    lgx[wr * 64 + c] = a1;
    lgy[wr * 64 + c] = a2;
    __syncthreads();
    float br = 0.f, bi = 0.f;
    #pragma unroll 8
    for (int k = 0; k < 64; k++) {
      float gx = lgx[wr * 64 + k], gy = lgy[wr * 64 + k];
      float ar = lr[k * 64 + c], ai = li[k * 64 + c];
      br += gx * ar - gy * ai;
      bi += gy * ar + gx * ai;
    }
    xd[(size_t)row * 64 + c] = a0;
    gf[(size_t)row * 64 + c] = tanhf(a1 * br + a2 * bi);
    __syncthreads();
  }
}

// ---------------- mlp0 (8 rows/block) ----------------
__global__ __launch_bounds__(256) void k_mlp0(const float* __restrict__ dx,
    const float* __restrict__ xd, const float* __restrict__ gf,
    const float* __restrict__ W0, const float* __restrict__ b0, float* __restrict__ h1) {
  __shared__ float lW[12288];
  __shared__ float lb[64];
  int t = threadIdx.x;
  for (int i = t; i < 12288; i += 256) lW[i] = W0[i];
  if (t < 64) lb[t] = b0[t];
  __syncthreads();
  int wr = t >> 6, c = t & 63;
  #pragma unroll
  for (int rg = 0; rg < 2; rg++) {
    int row = blockIdx.x * 8 + rg * 4 + wr;
    const float* a0 = dx + (size_t)row * 64;
    const float* a1 = xd + (size_t)row * 64;
    const float* a2 = gf + (size_t)row * 64;
    float acc = lb[c];
    #pragma unroll 8
    for (int k = 0; k < 64; k++) acc += a0[k] * lW[k * 64 + c];
    #pragma unroll 8
    for (int k = 0; k < 64; k++) acc += a1[k] * lW[(64 + k) * 64 + c];
    #pragma unroll 8
    for (int k = 0; k < 64; k++) acc += a2[k] * lW[(128 + k) * 64 + c];
    h1[(size_t)row * 64 + c] = fmaxf(acc, 0.f);
  }
}

// fused mlp1+mlp2+residual+dual projection (8 rows/block)
__global__ __launch_bounds__(256) void k_mlp12_dual(const float* __restrict__ h1,
    const float* __restrict__ W1, const float* __restrict__ b1,
    const float* __restrict__ W2, const float* __restrict__ b2,
    const float* __restrict__ dx, const float* __restrict__ gsw,
    const float* __restrict__ sgw, float* __restrict__ xw_v,
    float* __restrict__ xw2_v, u16* __restrict__ xw2vT) {
  __shared__ float l1[4096], l2[4096], lg[4096], ls[4096];
  __shared__ float lb1[64], lb2[64], lrow[256], lrow2[256];
  int t = threadIdx.x;
  for (int i = t; i < 4096; i += 256) {
    l1[i] = W1[i]; l2[i] = W2[i]; lg[i] = gsw[i]; ls[i] = sgw[i];
  }
  if (t < 64) lb1[t] = b1[t];
  else if (t < 128) lb2[t - 64] = b2[t - 64];
  __syncthreads();
  int wr = t >> 6, c = t & 63;
  #pragma unroll
  for (int rg = 0; rg < 2; rg++) {
    int row = blockIdx.x * 8 + rg * 4 + wr;
    const float* hr = h1 + (size_t)row * 64;
    float h2 = lb1[c];
    #pragma unroll 8
    for (int k = 0; k < 64; k++) h2 += hr[k] * l1[k * 64 + c];
    h2 = fmaxf(h2, 0.f);
    lrow[wr * 64 + c] = h2;
    __syncthreads();
    float o = lb2[c] + dx[(size_t)row * 64 + c];
    #pragma unroll 8
    for (int k = 0; k < 64; k++) o += lrow[wr * 64 + k] * l2[k * 64 + c];
    lrow2[wr * 64 + c] = o;
    __syncthreads();
    float p = 0.f, q = 0.f;
    #pragma unroll 8
    for (int k = 0; k < 64; k++) {
      float a = lrow2[wr * 64 + k];
      p += a * lg[k * 64 + c];
      q += a * ls[k * 64 + c];
    }
    xw_v[(size_t)row * 64 + c] = p;
    xw2_v[(size_t)row * 64 + c] = q;
    xw2vT[(size_t)c * NV + row] = f2bf(q);
    __syncthreads();
  }
}

// ---------------- fused bipartite combine (fallback tier) ----------------
__global__ void k_combine(const float* __restrict__ xw_v, const float* __restrict__ Wbp,
    const float* __restrict__ xw2_v, const float* __restrict__ xw_g,
    const float* __restrict__ WbTp, const float* __restrict__ xw2_g,
    const float* __restrict__ inv_deg_v, const float* __restrict__ rsv,
    const float* __restrict__ inv_deg_g, const float* __restrict__ rsg,
    const float* __restrict__ gsb, const float* __restrict__ sgb,
    float* __restrict__ dx, float* __restrict__ gx) {
  int idx = blockIdx.x * 256 + threadIdx.x;
  if (idx < NV * 64) {
    int v = idx >> 6, c = idx & 63;
    dx[idx] = 0.5f * (xw_v[idx] * inv_deg_v[v] + Wbp[idx] * rsv[v] + gsb[c] + xw2_v[idx] + sgb[c]);
  } else {
    int j = idx - NV * 64;
    int g = j >> 6, c = j & 63;
    gx[j] = 0.5f * (xw_g[j] + gsb[c] + xw2_g[j] * inv_deg_g[g] + WbTp[j] * rsg[g] + sgb[c]);
  }
}

// =================================================================
extern "C" void kernel_launch(void* const* d_in, const int* in_sizes, int n_in,
                              void* d_out, int out_size, void* d_ws, size_t ws_size,
                              hipStream_t stream) {
  const float* vertices  = (const float*)d_in[0];
  const float* graph_pos = (const float*)d_in[1];
  const float* x_in      = (const float*)d_in[2];
  const float* graph_x   = (const float*)d_in[3];
  const float* mass      = (const float*)d_in[4];
  const float* evals     = (const float*)d_in[5];
  const float* evecs     = (const float*)d_in[6];
  const float* gradX     = (const float*)d_in[7];
  const float* gradY     = (const float*)d_in[8];
  const int*   eidx      = (const int*)d_in[9];
  const float* ew        = (const float*)d_in[10];
  const float* lin1_w    = (const float*)d_in[11];
  const float* lin1_b    = (const float*)d_in[12];
  const float* lin2_w    = (const float*)d_in[13];
  const float* lin2_b    = (const float*)d_in[14];
  const float* diff_time = (const float*)d_in[15];
  const float* A_re      = (const float*)d_in[16];
  const float* A_im      = (const float*)d_in[17];
  const float* mlp_w0    = (const float*)d_in[18];
  const float* mlp_b0    = (const float*)d_in[19];
  const float* mlp_w1    = (const float*)d_in[20];
  const float* mlp_b1    = (const float*)d_in[21];
  const float* mlp_w2    = (const float*)d_in[22];
  const float* mlp_b2    = (const float*)d_in[23];
  const float* gcn1_w    = (const float*)d_in[24];
  const float* gcn1_b    = (const float*)d_in[25];
  const float* gcn2_w    = (const float*)d_in[26];
  const float* gcn2_b    = (const float*)d_in[27];
  const float* gs_w      = (const float*)d_in[28];
  const float* gs_b      = (const float*)d_in[29];
  const float* sg_w      = (const float*)d_in[30];
  const float* sg_b      = (const float*)d_in[31];

  char* base = (char*)d_ws;
  size_t off = 0;
  auto alloc = [&](size_t nbytes) -> void* {
    void* p = base + off;
    off += (nbytes + 255) & ~(size_t)255;
    return p;
  };
  const size_t MBy = 1024 * 1024;
  u16*   evecsT  = (u16*)alloc((size_t)128 * NV * 2);
  float* GXE2    = (float*)alloc((size_t)2 * NV * 128 * 4); // GXE | GYE contiguous
  float* GXE     = GXE2;
  float* GYE     = GXE2 + (size_t)NV * 128;
  u16*   mdxT    = (u16*)alloc((size_t)64 * NV * 2);
  float* Es      = (float*)alloc(8192 * 4);
  float* diffx   = (float*)alloc((size_t)NV * 64 * 4);
  float* gxb     = (float*)alloc((size_t)NG * 64 * 4);
  float* xd      = (float*)alloc((size_t)NV * 64 * 4);
  float* gf      = (float*)alloc((size_t)NV * 64 * 4);
  float* h1      = (float*)alloc((size_t)NV * 64 * 4);
  float* xw_v    = (float*)alloc((size_t)NV * 64 * 4);
  float* xw2_v   = (float*)alloc((size_t)NV * 64 * 4);
  float* xw_g    = (float*)alloc((size_t)NG * 64 * 4);
  float* xw2_g   = (float*)alloc((size_t)NG * 64 * 4);
  float* xw1     = (float*)alloc((size_t)NG * 64 * 4);
  float* xw2k    = (float*)alloc((size_t)NG * 64 * 4);
  u16*   xwgT    = (u16*)alloc((size_t)64 * NG * 2);
  u16*   xw2vT   = (u16*)alloc((size_t)64 * NV * 2);
  float* Wbp     = (float*)alloc((size_t)NV * 64 * 4);
  float* WbTp    = (float*)alloc((size_t)NG * 64 * 4);
  float* deg_v   = (float*)alloc(NV * 4);
  float* inv_deg_v = (float*)alloc(NV * 4);
  float* rsv     = (float*)alloc(NV * 4);
  float* deg_g   = (float*)alloc(NG * 4);
  float* inv_deg_g = (float*)alloc(NG * 4);
  float* rsg     = (float*)alloc(NG * 4);
  float* deg_e   = (float*)alloc(NG * 4);
  float* invdeg_e = (float*)alloc(NG * 4);
  float* dinv_e  = (float*)alloc(NG * 4);
  int*   cnt     = (int*)alloc(NG * 4);
  int*   row_ptr = (int*)alloc((NG + 1) * 4);
  int*   cursor  = (int*)alloc(NG * 4);
  int*   csr_src = (int*)alloc(NE * 4);
  float* csr_norm = (float*)alloc(NE * 4);

  size_t avail = ws_size > off ? ws_size - off : 0;
  u16 *WbP = nullptr, *WbTP = nullptr, *WbRow = nullptr;
  float* parts;
  int zsu;
  if (avail >= 162 * MBy) {
    WbP  = (u16*)alloc((size_t)NV * NG * 2);   // 64 MB panels
    WbTP = (u16*)alloc((size_t)NG * NV * 2);   // 64 MB panels
    parts = (float*)alloc(32 * MBy);
    zsu = 4;
  } else if (avail >= 97 * MBy) {
    WbRow = (u16*)alloc((size_t)NV * NG * 2);  // 64 MB row-major fallback
    parts = (float*)alloc(32 * MBy);
    zsu = 4;
  } else {
    WbRow = (u16*)alloc((size_t)NV * NG * 2);
    parts = (float*)alloc(16 * MBy);
    zsu = 2;
  }
  if (off > ws_size) return;  // insufficient workspace -> fail loudly

  dim3 B256(256);

  // ---------- setup ----------
  k_fill4<<<dim3(80), B256, 0, stream>>>(deg_v, deg_g, deg_e, cnt);
  k_wb_build<<<dim3(128, 64), B256, 0, stream>>>(vertices, graph_pos, WbRow, WbP, WbTP, deg_v, deg_g);
  k_edge_prep<<<dim3(256), B256, 0, stream>>>(eidx, ew, deg_e, cnt);
  k_recips<<<dim3(64), B256, 0, stream>>>(deg_v, inv_deg_v, rsv, deg_g, inv_deg_g, rsg,
                                          deg_e, invdeg_e, dinv_e);
  k_scan<<<dim3(1), dim3(1024), 0, stream>>>(cnt, row_ptr, cursor);
  k_scatter<<<dim3(256), B256, 0, stream>>>(eidx, ew, dinv_e, cursor, csr_src, csr_norm);
  k_evecsT<<<dim3(256, 4), B256, 0, stream>>>(evecs, evecsT);
  // GXE = gradX @ evecs, GYE = gradY @ evecs (round-8 proven config)
  gemm_setup3<<<dim3(2 * 32 * zsu), B256, 81920, stream>>>(
      gradX, gradY, evecsT, parts, zsu, 8192 / zsu);
  k_reduce2<<<dim3(2048), B256, 0, stream>>>(parts, GXE2, NV * 128, zsu);
  k_lin_both<<<dim3(3072), B256, 0, stream>>>(x_in, graph_x, lin1_w, lin1_b, lin2_w, lin2_b, diffx, gxb);

  // ---------- 4 blocks ----------
  for (int i = 0; i < 4; i++) {
    const float* dtrow = diff_time + i * 64;
    // merged: mdxT | gcn1 matmul
    k_front<<<dim3(128 + 1024), B256, 0, stream>>>(diffx, mass, mdxT, gxb,
        gcn1_w + i * 4096, xw1);
    // merged: spec GEMM | gcn1 agg + gcn2 matmul
    k_specagg<<<dim3(64 + 1024), B256, 0, stream>>>(evecsT, mdxT, parts,
        xw1, row_ptr, csr_src, csr_norm, invdeg_e, gcn1_b + i * 64,
        gcn2_w + i * 4096, xw2k);
    // merged: reduce+exp | gcn2 agg + graph-side dual projection
    k_redagg<<<dim3(32 + 1024), B256, 0, stream>>>(parts, evals, dtrow, Es,
        xw2k, row_ptr, csr_src, csr_norm, invdeg_e, gcn2_b + i * 64,
        gs_w + i * 4096, sg_w + i * 4096, xw_g, xw2_g, xwgT);
    // xd + gradient features, then mlp0 (8 rows/block)
    k_xdgf<<<dim3(1024), B256, 0, stream>>>(evecs, GXE, GYE, Es, A_re + i * 4096, A_im + i * 4096, xd, gf);
    k_mlp0<<<dim3(1024), B256, 0, stream>>>(diffx, xd, gf, mlp_w0 + i * 12288, mlp_b0 + i * 64, h1);
    // fused mlp12 + vertex-side dual projection (no post-MLP diffx store)
    k_mlp12_dual<<<dim3(1024), B256, 0, stream>>>(h1, mlp_w1 + i * 4096, mlp_b1 + i * 64,
        mlp_w2 + i * 4096, mlp_b2 + i * 64, diffx, gs_w + i * 4096, sg_w + i * 4096,
        xw_v, xw2_v, xw2vT);
    if (WbP != nullptr) {
      // both Wb GEMMs in one launch, then fused reduce+combine
      gemm_panel2<<<dim3(1024), B256, 0, stream>>>(WbP, WbTP, xwgT, xw2vT, parts);
      k_reduce_combine<<<dim3(3072), B256, 0, stream>>>(parts, xw_v, xw2_v, xw_g, xw2_g,
          inv_deg_v, rsv, inv_deg_g, rsg, gs_b + i * 64, sg_b + i * 64, diffx, gxb);
    } else {
      gemm_bf16<<<dim3(64, 1, 8), B256, 0, stream>>>(WbRow, NG, xwgT, NG, parts, NV, 512);
      k_reduce<<<dim3(512), B256, 0, stream>>>(parts, Wbp, NV * 64, 8);
      gemm_k<64, false, true><<<dim3(32, 1, 16), B256, 0, stream>>>(
          WbRow, nullptr, 1 << 30, xw2vT, parts, NG, 64, NG, NV, 512);
      k_reduce<<<dim3(256), B256, 0, stream>>>(parts, WbTp, NG * 64, 16);
      k_combine<<<dim3(3072), B256, 0, stream>>>(xw_v, Wbp, xw2_v, xw_g, WbTp, xw2_g,
          inv_deg_v, rsv, inv_deg_g, rsg, gs_b + i * 64, sg_b + i * 64, diffx, gxb);
    }
  }

  hipMemcpyAsync(d_out, diffx, (size_t)NV * 64 * 4, hipMemcpyDeviceToDevice, stream);
}